// Round 2
// baseline (1585.757 us; speedup 1.0000x reference)
//
#include <hip/hip_runtime.h>

#define N_NODES 200000
#define N_EDGES 6400000
#define N_GRAPHS 512
#define RLEN 20
#define EMBED 8
#define EPS 1e-5f

// ---------------- CSR build ----------------

__global__ void k_degree(const int* __restrict__ dst, int* __restrict__ ecnt) {
  int e = blockIdx.x * blockDim.x + threadIdx.x;
  if (e < N_EDGES) atomicAdd(&ecnt[dst[e]], 1);
}

// dinv = rsqrt(ecnt+1) (self loop). Row allocation: wave-level exclusive scan
// + one atomicAdd per wave on a global counter.
__global__ void k_dinv_alloc(const int* __restrict__ ecnt, float* __restrict__ dinv,
                             int* __restrict__ rowstart, int* __restrict__ cursor,
                             int* __restrict__ counter) {
  int n = blockIdx.x * blockDim.x + threadIdx.x;
  int lane = threadIdx.x & 63;
  int e = (n < N_NODES) ? ecnt[n] : 0;
  if (n < N_NODES) dinv[n] = rsqrtf((float)(e + 1));
  int incl = e;
  #pragma unroll
  for (int off = 1; off < 64; off <<= 1) {
    int t = __shfl_up(incl, off);
    if (lane >= off) incl += t;
  }
  int excl = incl - e;
  int total = __shfl(incl, 63);
  int base = 0;
  if (lane == 0) base = atomicAdd(counter, total);
  base = __shfl(base, 0);
  if (n < N_NODES) { rowstart[n] = base + excl; cursor[n] = base + excl; }
}

__global__ void k_fill(const int* __restrict__ src, const int* __restrict__ dst,
                       int* __restrict__ cursor, int* __restrict__ cols) {
  int e = blockIdx.x * blockDim.x + threadIdx.x;
  if (e < N_EDGES) {
    int d = dst[e];
    int pos = atomicAdd(&cursor[d], 1);
    cols[pos] = src[e];
  }
}

// ---------------- node feature pipeline ----------------

// h0[n,f] = dinv[n] * (x[n,:] @ W1)[f]
__global__ void k_xw1(const float* __restrict__ x, const float* __restrict__ W1,
                      const float* __restrict__ dinv, float* __restrict__ h0) {
  __shared__ float w1s[3 * 64];
  if (threadIdx.x < 192) w1s[threadIdx.x] = W1[threadIdx.x];
  __syncthreads();
  int lane = threadIdx.x & 63;
  int wid = threadIdx.x >> 6;
  for (int n = blockIdx.x * 4 + wid; n < N_NODES; n += gridDim.x * 4) {
    float x0 = x[n * 3 + 0], x1 = x[n * 3 + 1], x2 = x[n * 3 + 2];
    float v = x0 * w1s[lane] + x1 * w1s[64 + lane] + x2 * w1s[128 + lane];
    h0[n * 64 + lane] = v * dinv[n];
  }
}

// out[d,f] = dinv[d] * ( hin[d,f] + sum_{s in N(d)} hin[s,f] )   (hin pre-scaled by dinv[s])
__global__ void k_agg(const float* __restrict__ hin, float* __restrict__ hout,
                      const int* __restrict__ rowstart, const int* __restrict__ ecnt,
                      const int* __restrict__ cols, const float* __restrict__ dinv) {
  int node = blockIdx.x * 4 + (threadIdx.x >> 6);
  int lane = threadIdx.x & 63;
  if (node >= N_NODES) return;
  float acc = hin[node * 64 + lane];  // self loop
  int base = rowstart[node];
  int len = ecnt[node];
  for (int c0 = 0; c0 < len; c0 += 64) {
    int rem = len - c0;
    int m = rem < 64 ? rem : 64;
    int cidx = (lane < m) ? cols[base + c0 + lane] : 0;
    int j = 0;
    for (; j + 4 <= m; j += 4) {  // 4 loads in flight
      int s0 = __shfl(cidx, j), s1 = __shfl(cidx, j + 1);
      int s2 = __shfl(cidx, j + 2), s3 = __shfl(cidx, j + 3);
      float v0 = hin[s0 * 64 + lane], v1 = hin[s1 * 64 + lane];
      float v2 = hin[s2 * 64 + lane], v3 = hin[s3 * 64 + lane];
      acc += (v0 + v1) + (v2 + v3);
    }
    for (; j < m; ++j) {
      int s = __shfl(cidx, j);
      acc += hin[s * 64 + lane];
    }
  }
  hout[node * 64 + lane] = acc * dinv[node];
}

// per-feature sum and sumsq over all nodes -> stats[0:64], stats[64:128]
__global__ void k_bnstats(const float* __restrict__ h, float* __restrict__ stats) {
  __shared__ float ls[4][64], ls2[4][64];
  int lane = threadIdx.x & 63, wid = threadIdx.x >> 6;
  float s = 0.f, s2 = 0.f;
  for (int r = blockIdx.x * 4 + wid; r < N_NODES; r += gridDim.x * 4) {
    float v = h[r * 64 + lane];
    s += v;
    s2 += v * v;
  }
  ls[wid][lane] = s;
  ls2[wid][lane] = s2;
  __syncthreads();
  if (wid == 0) {
    float a = ls[0][lane] + ls[1][lane] + ls[2][lane] + ls[3][lane];
    float b = ls2[0][lane] + ls2[1][lane] + ls2[2][lane] + ls2[3][lane];
    atomicAdd(&stats[lane], a);
    atomicAdd(&stats[64 + lane], b);
  }
}

// hout[n,f] = dinv[n] * ( relu(bn1(h1[n,:])) @ W2 )[f]
__global__ void k_l2(const float* __restrict__ h1, float* __restrict__ hout,
                     const float* __restrict__ W2, const float* __restrict__ stats,
                     const float* __restrict__ gamma, const float* __restrict__ beta,
                     const float* __restrict__ dinv) {
  __shared__ float w2s[64 * 64];
  for (int i = threadIdx.x; i < 64 * 64; i += blockDim.x) w2s[i] = W2[i];
  __syncthreads();
  int lane = threadIdx.x & 63, wid = threadIdx.x >> 6;
  float mu = stats[lane] * (1.0f / N_NODES);
  float var = stats[64 + lane] * (1.0f / N_NODES) - mu * mu;
  float sc = rsqrtf(var + EPS) * gamma[lane];
  float sh = beta[lane] - mu * sc;
  for (int n = blockIdx.x * 4 + wid; n < N_NODES; n += gridDim.x * 4) {
    float a = h1[n * 64 + lane] * sc + sh;
    a = a > 0.f ? a : 0.f;
    float acc = 0.f;
    #pragma unroll
    for (int k = 0; k < 64; ++k) {
      acc = fmaf(__shfl(a, k), w2s[k * 64 + lane], acc);
    }
    hout[n * 64 + lane] = acc * dinv[n];
  }
}

// ---------------- pooling + head ----------------

__global__ void k_gstart(const int* __restrict__ batch, int* __restrict__ gstart) {
  int g = blockIdx.x * blockDim.x + threadIdx.x;
  if (g > N_GRAPHS) return;
  int lo = 0, hi = N_NODES;
  while (lo < hi) {
    int mid = (lo + hi) >> 1;
    if (batch[mid] < g) lo = mid + 1; else hi = mid;
  }
  gstart[g] = lo;
}

__global__ void k_pool(const float* __restrict__ h2, const float* __restrict__ stats2,
                       const float* __restrict__ gamma, const float* __restrict__ beta,
                       const int* __restrict__ gstart, float* __restrict__ hgraph) {
  __shared__ float ssum[4][64], smax[4][64];
  int g = blockIdx.x;
  int lane = threadIdx.x & 63, wid = threadIdx.x >> 6;
  int s0 = gstart[g], s1 = gstart[g + 1];
  float mu = stats2[lane] * (1.0f / N_NODES);
  float var = stats2[64 + lane] * (1.0f / N_NODES) - mu * mu;
  float sc = rsqrtf(var + EPS) * gamma[lane];
  float sh = beta[lane] - mu * sc;
  float sum = 0.f, mx = 0.f;  // relu output >= 0, so 0 is a valid max identity (matches empty-graph guard)
  for (int r = s0 + wid; r < s1; r += 4) {
    float v = h2[r * 64 + lane] * sc + sh;
    v = v > 0.f ? v : 0.f;
    sum += v;
    mx = v > mx ? v : mx;
  }
  ssum[wid][lane] = sum;
  smax[wid][lane] = mx;
  __syncthreads();
  if (wid == 0) {
    float s = ssum[0][lane] + ssum[1][lane] + ssum[2][lane] + ssum[3][lane];
    float m = fmaxf(fmaxf(smax[0][lane], smax[1][lane]), fmaxf(smax[2][lane], smax[3][lane]));
    int cnt = s1 - s0;
    float inv = 1.0f / (float)(cnt > 0 ? cnt : 1);
    hgraph[g * 128 + lane] = s * inv;
    hgraph[g * 128 + 64 + lane] = m;
  }
}

__global__ void k_head(const float* __restrict__ hgraph,
                       const float* __restrict__ emb, const int* __restrict__ recipe,
                       const float* __restrict__ conv_w, const float* __restrict__ conv_b,
                       const float* __restrict__ fc_w, const float* __restrict__ fc_b,
                       const float* __restrict__ m1_w, const float* __restrict__ m1_b,
                       const float* __restrict__ m2_w, const float* __restrict__ m2_b,
                       const float* __restrict__ m3_w, const float* __restrict__ m3_b,
                       float* __restrict__ out) {
  __shared__ float r_s[RLEN][EMBED];
  __shared__ float convout[16 * RLEN];
  __shared__ float cvec[192];
  __shared__ float y1[128];
  __shared__ float y2[64];
  __shared__ int rec_s[RLEN];
  __shared__ float emb_s[80];
  int g = blockIdx.x;
  int t = threadIdx.x;
  if (t < 80) emb_s[t] = emb[t];
  if (t < RLEN) rec_s[t] = recipe[g * RLEN + t];
  __syncthreads();
  // FIX (round 1): RLEN*EMBED = 160 > blockDim (128) -> loop, not single guard.
  for (int idx = t; idx < RLEN * EMBED; idx += blockDim.x) {
    int pos = idx >> 3, e = idx & 7;
    r_s[pos][e] = emb_s[rec_s[pos] * EMBED + e];
  }
  if (t < 128) cvec[t] = hgraph[g * 128 + t];
  __syncthreads();
  for (int idx = t; idx < 16 * RLEN; idx += blockDim.x) {
    int c = idx / RLEN, pos = idx % RLEN;
    float acc = conv_b[c];
    #pragma unroll
    for (int k = 0; k < 3; ++k) {
      int p = pos + k - 1;
      if (p >= 0 && p < RLEN) {
        #pragma unroll
        for (int e = 0; e < EMBED; ++e)
          acc = fmaf(r_s[p][e], conv_w[(c * EMBED + e) * 3 + k], acc);
      }
    }
    convout[c * RLEN + pos] = acc > 0.f ? acc : 0.f;  // channel-major flatten
  }
  __syncthreads();
  if (t < 64) {
    float acc = fc_b[t];
    for (int i = 0; i < 320; ++i) acc = fmaf(convout[i], fc_w[i * 64 + t], acc);
    cvec[128 + t] = acc > 0.f ? acc : 0.f;
  }
  __syncthreads();
  if (t < 128) {
    float acc = m1_b[t];
    for (int i = 0; i < 192; ++i) acc = fmaf(cvec[i], m1_w[i * 128 + t], acc);
    y1[t] = acc > 0.f ? acc : 0.f;
  }
  __syncthreads();
  if (t < 64) {
    float acc = m2_b[t];
    for (int i = 0; i < 128; ++i) acc = fmaf(y1[i], m2_w[i * 64 + t], acc);
    y2[t] = acc > 0.f ? acc : 0.f;
  }
  __syncthreads();
  if (t < 3) {
    float acc = m3_b[t];
    for (int i = 0; i < 64; ++i) acc = fmaf(y2[i], m3_w[i * 3 + t], acc);
    out[g * 3 + t] = acc;
  }
}

extern "C" void kernel_launch(void* const* d_in, const int* in_sizes, int n_in,
                              void* d_out, int out_size, void* d_ws, size_t ws_size,
                              hipStream_t stream) {
  const float* x      = (const float*)d_in[0];
  const float* W1     = (const float*)d_in[1];
  // b1 (d_in[2]) cancels under BN
  const float* gamma1 = (const float*)d_in[3];
  const float* beta1  = (const float*)d_in[4];
  const float* W2     = (const float*)d_in[5];
  // b2 (d_in[6]) cancels under BN
  const float* gamma2 = (const float*)d_in[7];
  const float* beta2  = (const float*)d_in[8];
  const float* emb    = (const float*)d_in[9];
  const float* conv_w = (const float*)d_in[10];
  const float* conv_b = (const float*)d_in[11];
  const float* fc_w   = (const float*)d_in[12];
  const float* fc_b   = (const float*)d_in[13];
  const float* m1_w   = (const float*)d_in[14];
  const float* m1_b   = (const float*)d_in[15];
  const float* m2_w   = (const float*)d_in[16];
  const float* m2_b   = (const float*)d_in[17];
  const float* m3_w   = (const float*)d_in[18];
  const float* m3_b   = (const float*)d_in[19];
  const int* ei       = (const int*)d_in[20];
  const int* batch    = (const int*)d_in[21];
  const int* recipe   = (const int*)d_in[22];
  const int* e_src = ei;
  const int* e_dst = ei + N_EDGES;
  float* out = (float*)d_out;

  char* p = (char*)d_ws;
  auto alloc = [&](size_t bytes) {
    char* r = p;
    p += (bytes + 255) & ~(size_t)255;
    return (void*)r;
  };
  int*   ecnt     = (int*)alloc((size_t)N_NODES * 4);
  float* dinv     = (float*)alloc((size_t)N_NODES * 4);
  int*   rowstart = (int*)alloc((size_t)N_NODES * 4);
  int*   cursor   = (int*)alloc((size_t)N_NODES * 4);
  int*   counter  = (int*)alloc(4);
  int*   gstart   = (int*)alloc((size_t)(N_GRAPHS + 1) * 4);
  float* stats    = (float*)alloc(256 * 4);   // [sum1|sq1|sum2|sq2]
  float* hgraph   = (float*)alloc((size_t)N_GRAPHS * 128 * 4);
  int*   cols     = (int*)alloc((size_t)N_EDGES * 4);
  float* h0       = (float*)alloc((size_t)N_NODES * 64 * 4);
  float* h1       = (float*)alloc((size_t)N_NODES * 64 * 4);

  hipMemsetAsync(ecnt, 0, (size_t)N_NODES * 4, stream);
  hipMemsetAsync(counter, 0, 4, stream);
  hipMemsetAsync(stats, 0, 256 * 4, stream);

  k_degree<<<(N_EDGES + 255) / 256, 256, 0, stream>>>(e_dst, ecnt);
  k_dinv_alloc<<<(N_NODES + 255) / 256, 256, 0, stream>>>(ecnt, dinv, rowstart, cursor, counter);
  k_fill<<<(N_EDGES + 255) / 256, 256, 0, stream>>>(e_src, e_dst, cursor, cols);
  k_xw1<<<2048, 256, 0, stream>>>(x, W1, dinv, h0);
  k_agg<<<(N_NODES + 3) / 4, 256, 0, stream>>>(h0, h1, rowstart, ecnt, cols, dinv);
  k_bnstats<<<512, 256, 0, stream>>>(h1, stats);
  k_l2<<<2048, 256, 0, stream>>>(h1, h0, W2, stats, gamma1, beta1, dinv);
  k_agg<<<(N_NODES + 3) / 4, 256, 0, stream>>>(h0, h1, rowstart, ecnt, cols, dinv);
  k_bnstats<<<512, 256, 0, stream>>>(h1, stats + 128);
  k_gstart<<<1, 576, 0, stream>>>(batch, gstart);
  k_pool<<<N_GRAPHS, 256, 0, stream>>>(h1, stats + 128, gamma2, beta2, gstart, hgraph);
  k_head<<<N_GRAPHS, 128, 0, stream>>>(hgraph, emb, recipe, conv_w, conv_b, fc_w, fc_b,
                                       m1_w, m1_b, m2_w, m2_b, m3_w, m3_b, out);
}

// Round 3
// 895.388 us; speedup vs baseline: 1.7710x; 1.7710x over previous
//
#include <hip/hip_runtime.h>

#define N_NODES 200000
#define N_EDGES 6400000
#define N_GRAPHS 512
#define RLEN 20
#define EMBED 8
#define EPS 1e-5f

#define NPB 1024                      // nodes per bucket
#define NBKT ((N_NODES + NPB - 1) / NPB)   // 196
#define CHUNK 4096                    // edges per k_bscatter block

// ---------------- bucketed CSR build ----------------

// bucket histogram: LDS hist + one global atomic per (block,bucket)
__global__ void k_bcount(const int* __restrict__ dst, int* __restrict__ bcnt) {
  __shared__ int hist[NBKT];
  for (int i = threadIdx.x; i < NBKT; i += blockDim.x) hist[i] = 0;
  __syncthreads();
  for (int e = blockIdx.x * blockDim.x + threadIdx.x; e < N_EDGES; e += gridDim.x * blockDim.x)
    atomicAdd(&hist[dst[e] >> 10], 1);
  __syncthreads();
  for (int i = threadIdx.x; i < NBKT; i += blockDim.x)
    if (hist[i]) atomicAdd(&bcnt[i], hist[i]);
}

// scan bucket counts -> bucket edge starts; init cursors; rowstart sentinel
__global__ void k_bscan(const int* __restrict__ bcnt, int* __restrict__ bstart,
                        int* __restrict__ bcursor, int* __restrict__ rowstart) {
  __shared__ int sb[256];
  int t = threadIdx.x;
  int v = (t < NBKT) ? bcnt[t] : 0;
  sb[t] = v;
  __syncthreads();
  for (int off = 1; off < 256; off <<= 1) {
    int u = (t >= off) ? sb[t - off] : 0;
    __syncthreads();
    sb[t] += u;
    __syncthreads();
  }
  if (t < NBKT) {
    int excl = sb[t] - v;
    bstart[t] = excl;
    bcursor[t] = excl;
  }
  if (t == 0) { bstart[NBKT] = N_EDGES; rowstart[N_NODES] = N_EDGES; }
}

// scatter edges into bucket-grouped packed array, coalesced via LDS staging
__global__ void __launch_bounds__(256) k_bscatter(const int* __restrict__ src,
                                                  const int* __restrict__ dst,
                                                  int* __restrict__ bcursor,
                                                  int* __restrict__ ebuf) {
  __shared__ int hist[256];     // bucket counts (padded)
  __shared__ int scanb[256];
  __shared__ int gbase[NBKT];
  __shared__ int staged[CHUNK];
  __shared__ int addrs[CHUNK];
  __shared__ int s_total;
  int t = threadIdx.x;
  int e0 = blockIdx.x * CHUNK;
  hist[t] = 0;
  __syncthreads();

  int pk[16], bk[16], rk[16];
  #pragma unroll
  for (int k = 0; k < 16; ++k) {
    int idx = e0 + t + k * 256;
    bk[k] = -1;
    if (idx < N_EDGES) {
      int s = src[idx], d = dst[idx];
      int b = d >> 10;
      pk[k] = s | ((d & (NPB - 1)) << 18);
      bk[k] = b;
      rk[k] = atomicAdd(&hist[b], 1);
    }
  }
  __syncthreads();
  int hv = hist[t];
  scanb[t] = hv;
  __syncthreads();
  for (int off = 1; off < 256; off <<= 1) {
    int u = (t >= off) ? scanb[t - off] : 0;
    __syncthreads();
    scanb[t] += u;
    __syncthreads();
  }
  int offt = scanb[t] - hv;           // exclusive
  if (t < NBKT && hv > 0) gbase[t] = atomicAdd(&bcursor[t], hv);
  if (t == 255) s_total = scanb[255];
  // reuse hist as offs
  __syncthreads();
  hist[t] = offt;
  __syncthreads();
  #pragma unroll
  for (int k = 0; k < 16; ++k) {
    if (bk[k] >= 0) {
      int slot = hist[bk[k]] + rk[k];
      staged[slot] = pk[k];
      addrs[slot] = gbase[bk[k]] + rk[k];
    }
  }
  __syncthreads();
  int total = s_total;
  for (int i = t; i < total; i += 256)
    ebuf[addrs[i]] = staged[i];
}

// per bucket: LDS degree hist -> rowstart/dinv, then local scatter of cols
__global__ void __launch_bounds__(256) k_bfill(const int* __restrict__ bstart,
                                               const int* __restrict__ ebuf,
                                               int* __restrict__ rowstart,
                                               float* __restrict__ dinv,
                                               int* __restrict__ cols) {
  __shared__ int deg[NPB];
  __shared__ int cur[NPB];
  __shared__ int wsum[4];
  int b = blockIdx.x;
  int t = threadIdx.x;
  int lane = t & 63, wid = t >> 6;
  int estart = bstart[b], eend = bstart[b + 1];
  for (int i = t; i < NPB; i += 256) deg[i] = 0;
  __syncthreads();
  for (int i = estart + t; i < eend; i += 256) {
    int p = ebuf[i];
    atomicAdd(&deg[((unsigned)p) >> 18], 1);
  }
  __syncthreads();
  // block exclusive scan over deg[1024]: 4 elems/thread
  int d0 = deg[t * 4], d1 = deg[t * 4 + 1], d2 = deg[t * 4 + 2], d3 = deg[t * 4 + 3];
  int tsum = d0 + d1 + d2 + d3;
  int incl = tsum;
  #pragma unroll
  for (int off = 1; off < 64; off <<= 1) {
    int u = __shfl_up(incl, off);
    if (lane >= off) incl += u;
  }
  if (lane == 63) wsum[wid] = incl;
  int wexcl = incl - tsum;
  __syncthreads();
  int wbase = 0;
  for (int w = 0; w < wid; ++w) wbase += wsum[w];
  int ebase = wbase + wexcl;
  cur[t * 4 + 0] = ebase;
  cur[t * 4 + 1] = ebase + d0;
  cur[t * 4 + 2] = ebase + d0 + d1;
  cur[t * 4 + 3] = ebase + d0 + d1 + d2;
  __syncthreads();
  // emit rowstart / dinv
  #pragma unroll
  for (int k = 0; k < 4; ++k) {
    int dl = t * 4 + k;
    int n = b * NPB + dl;
    if (n < N_NODES) {
      rowstart[n] = estart + cur[dl];
      dinv[n] = rsqrtf((float)(deg[dl] + 1));
    }
  }
  __syncthreads();
  // local scatter (writes confined to this bucket's contiguous cols region)
  for (int i = estart + t; i < eend; i += 256) {
    int p = ebuf[i];
    int dl = ((unsigned)p) >> 18;
    int lpos = atomicAdd(&cur[dl], 1);
    cols[estart + lpos] = p & 0x3FFFF;
  }
}

// ---------------- node feature pipeline ----------------

// h0[n,f] = dinv[n] * (x[n,:] @ W1)[f]
__global__ void k_xw1(const float* __restrict__ x, const float* __restrict__ W1,
                      const float* __restrict__ dinv, float* __restrict__ h0) {
  __shared__ float w1s[3 * 64];
  if (threadIdx.x < 192) w1s[threadIdx.x] = W1[threadIdx.x];
  __syncthreads();
  int lane = threadIdx.x & 63;
  int wid = threadIdx.x >> 6;
  for (int n = blockIdx.x * 4 + wid; n < N_NODES; n += gridDim.x * 4) {
    float x0 = x[n * 3 + 0], x1 = x[n * 3 + 1], x2 = x[n * 3 + 2];
    float v = x0 * w1s[lane] + x1 * w1s[64 + lane] + x2 * w1s[128 + lane];
    h0[n * 64 + lane] = v * dinv[n];
  }
}

// out[d,f] = dinv[d] * ( hin[d,f] + sum_{s in N(d)} hin[s,f] )   (hin pre-scaled by dinv[s])
__global__ void k_agg(const float* __restrict__ hin, float* __restrict__ hout,
                      const int* __restrict__ rowstart,
                      const int* __restrict__ cols, const float* __restrict__ dinv) {
  int node = blockIdx.x * 4 + (threadIdx.x >> 6);
  int lane = threadIdx.x & 63;
  if (node >= N_NODES) return;
  float acc = hin[node * 64 + lane];  // self loop
  int base = rowstart[node];
  int len = rowstart[node + 1] - base;
  for (int c0 = 0; c0 < len; c0 += 64) {
    int rem = len - c0;
    int m = rem < 64 ? rem : 64;
    int cidx = (lane < m) ? cols[base + c0 + lane] : 0;
    int j = 0;
    for (; j + 4 <= m; j += 4) {  // 4 loads in flight
      int s0 = __shfl(cidx, j), s1 = __shfl(cidx, j + 1);
      int s2 = __shfl(cidx, j + 2), s3 = __shfl(cidx, j + 3);
      float v0 = hin[s0 * 64 + lane], v1 = hin[s1 * 64 + lane];
      float v2 = hin[s2 * 64 + lane], v3 = hin[s3 * 64 + lane];
      acc += (v0 + v1) + (v2 + v3);
    }
    for (; j < m; ++j) {
      int s = __shfl(cidx, j);
      acc += hin[s * 64 + lane];
    }
  }
  hout[node * 64 + lane] = acc * dinv[node];
}

// per-feature sum and sumsq over all nodes -> stats[0:64], stats[64:128]
__global__ void k_bnstats(const float* __restrict__ h, float* __restrict__ stats) {
  __shared__ float ls[4][64], ls2[4][64];
  int lane = threadIdx.x & 63, wid = threadIdx.x >> 6;
  float s = 0.f, s2 = 0.f;
  for (int r = blockIdx.x * 4 + wid; r < N_NODES; r += gridDim.x * 4) {
    float v = h[r * 64 + lane];
    s += v;
    s2 += v * v;
  }
  ls[wid][lane] = s;
  ls2[wid][lane] = s2;
  __syncthreads();
  if (wid == 0) {
    float a = ls[0][lane] + ls[1][lane] + ls[2][lane] + ls[3][lane];
    float b = ls2[0][lane] + ls2[1][lane] + ls2[2][lane] + ls2[3][lane];
    atomicAdd(&stats[lane], a);
    atomicAdd(&stats[64 + lane], b);
  }
}

// hout[n,f] = dinv[n] * ( relu(bn1(h1[n,:])) @ W2 )[f]
__global__ void k_l2(const float* __restrict__ h1, float* __restrict__ hout,
                     const float* __restrict__ W2, const float* __restrict__ stats,
                     const float* __restrict__ gamma, const float* __restrict__ beta,
                     const float* __restrict__ dinv) {
  __shared__ float w2s[64 * 64];
  for (int i = threadIdx.x; i < 64 * 64; i += blockDim.x) w2s[i] = W2[i];
  __syncthreads();
  int lane = threadIdx.x & 63, wid = threadIdx.x >> 6;
  float mu = stats[lane] * (1.0f / N_NODES);
  float var = stats[64 + lane] * (1.0f / N_NODES) - mu * mu;
  float sc = rsqrtf(var + EPS) * gamma[lane];
  float sh = beta[lane] - mu * sc;
  for (int n = blockIdx.x * 4 + wid; n < N_NODES; n += gridDim.x * 4) {
    float a = h1[n * 64 + lane] * sc + sh;
    a = a > 0.f ? a : 0.f;
    float acc = 0.f;
    #pragma unroll
    for (int k = 0; k < 64; ++k) {
      acc = fmaf(__shfl(a, k), w2s[k * 64 + lane], acc);
    }
    hout[n * 64 + lane] = acc * dinv[n];
  }
}

// ---------------- pooling + head ----------------

__global__ void k_gstart(const int* __restrict__ batch, int* __restrict__ gstart) {
  int g = blockIdx.x * blockDim.x + threadIdx.x;
  if (g > N_GRAPHS) return;
  int lo = 0, hi = N_NODES;
  while (lo < hi) {
    int mid = (lo + hi) >> 1;
    if (batch[mid] < g) lo = mid + 1; else hi = mid;
  }
  gstart[g] = lo;
}

__global__ void k_pool(const float* __restrict__ h2, const float* __restrict__ stats2,
                       const float* __restrict__ gamma, const float* __restrict__ beta,
                       const int* __restrict__ gstart, float* __restrict__ hgraph) {
  __shared__ float ssum[4][64], smax[4][64];
  int g = blockIdx.x;
  int lane = threadIdx.x & 63, wid = threadIdx.x >> 6;
  int s0 = gstart[g], s1 = gstart[g + 1];
  float mu = stats2[lane] * (1.0f / N_NODES);
  float var = stats2[64 + lane] * (1.0f / N_NODES) - mu * mu;
  float sc = rsqrtf(var + EPS) * gamma[lane];
  float sh = beta[lane] - mu * sc;
  float sum = 0.f, mx = 0.f;  // relu output >= 0 -> 0 is valid max identity (matches empty-graph guard)
  for (int r = s0 + wid; r < s1; r += 4) {
    float v = h2[r * 64 + lane] * sc + sh;
    v = v > 0.f ? v : 0.f;
    sum += v;
    mx = v > mx ? v : mx;
  }
  ssum[wid][lane] = sum;
  smax[wid][lane] = mx;
  __syncthreads();
  if (wid == 0) {
    float s = ssum[0][lane] + ssum[1][lane] + ssum[2][lane] + ssum[3][lane];
    float m = fmaxf(fmaxf(smax[0][lane], smax[1][lane]), fmaxf(smax[2][lane], smax[3][lane]));
    int cnt = s1 - s0;
    float inv = 1.0f / (float)(cnt > 0 ? cnt : 1);
    hgraph[g * 128 + lane] = s * inv;
    hgraph[g * 128 + 64 + lane] = m;
  }
}

__global__ void k_head(const float* __restrict__ hgraph,
                       const float* __restrict__ emb, const int* __restrict__ recipe,
                       const float* __restrict__ conv_w, const float* __restrict__ conv_b,
                       const float* __restrict__ fc_w, const float* __restrict__ fc_b,
                       const float* __restrict__ m1_w, const float* __restrict__ m1_b,
                       const float* __restrict__ m2_w, const float* __restrict__ m2_b,
                       const float* __restrict__ m3_w, const float* __restrict__ m3_b,
                       float* __restrict__ out) {
  __shared__ float r_s[RLEN][EMBED];
  __shared__ float convout[16 * RLEN];
  __shared__ float cvec[192];
  __shared__ float y1[128];
  __shared__ float y2[64];
  __shared__ int rec_s[RLEN];
  __shared__ float emb_s[80];
  int g = blockIdx.x;
  int t = threadIdx.x;
  if (t < 80) emb_s[t] = emb[t];
  if (t < RLEN) rec_s[t] = recipe[g * RLEN + t];
  __syncthreads();
  for (int idx = t; idx < RLEN * EMBED; idx += blockDim.x) {
    int pos = idx >> 3, e = idx & 7;
    r_s[pos][e] = emb_s[rec_s[pos] * EMBED + e];
  }
  if (t < 128) cvec[t] = hgraph[g * 128 + t];
  __syncthreads();
  for (int idx = t; idx < 16 * RLEN; idx += blockDim.x) {
    int c = idx / RLEN, pos = idx % RLEN;
    float acc = conv_b[c];
    #pragma unroll
    for (int k = 0; k < 3; ++k) {
      int p = pos + k - 1;
      if (p >= 0 && p < RLEN) {
        #pragma unroll
        for (int e = 0; e < EMBED; ++e)
          acc = fmaf(r_s[p][e], conv_w[(c * EMBED + e) * 3 + k], acc);
      }
    }
    convout[c * RLEN + pos] = acc > 0.f ? acc : 0.f;  // channel-major flatten
  }
  __syncthreads();
  if (t < 64) {
    float acc = fc_b[t];
    for (int i = 0; i < 320; ++i) acc = fmaf(convout[i], fc_w[i * 64 + t], acc);
    cvec[128 + t] = acc > 0.f ? acc : 0.f;
  }
  __syncthreads();
  if (t < 128) {
    float acc = m1_b[t];
    for (int i = 0; i < 192; ++i) acc = fmaf(cvec[i], m1_w[i * 128 + t], acc);
    y1[t] = acc > 0.f ? acc : 0.f;
  }
  __syncthreads();
  if (t < 64) {
    float acc = m2_b[t];
    for (int i = 0; i < 128; ++i) acc = fmaf(y1[i], m2_w[i * 64 + t], acc);
    y2[t] = acc > 0.f ? acc : 0.f;
  }
  __syncthreads();
  if (t < 3) {
    float acc = m3_b[t];
    for (int i = 0; i < 64; ++i) acc = fmaf(y2[i], m3_w[i * 3 + t], acc);
    out[g * 3 + t] = acc;
  }
}

extern "C" void kernel_launch(void* const* d_in, const int* in_sizes, int n_in,
                              void* d_out, int out_size, void* d_ws, size_t ws_size,
                              hipStream_t stream) {
  const float* x      = (const float*)d_in[0];
  const float* W1     = (const float*)d_in[1];
  // b1 (d_in[2]) cancels under BN
  const float* gamma1 = (const float*)d_in[3];
  const float* beta1  = (const float*)d_in[4];
  const float* W2     = (const float*)d_in[5];
  // b2 (d_in[6]) cancels under BN
  const float* gamma2 = (const float*)d_in[7];
  const float* beta2  = (const float*)d_in[8];
  const float* emb    = (const float*)d_in[9];
  const float* conv_w = (const float*)d_in[10];
  const float* conv_b = (const float*)d_in[11];
  const float* fc_w   = (const float*)d_in[12];
  const float* fc_b   = (const float*)d_in[13];
  const float* m1_w   = (const float*)d_in[14];
  const float* m1_b   = (const float*)d_in[15];
  const float* m2_w   = (const float*)d_in[16];
  const float* m2_b   = (const float*)d_in[17];
  const float* m3_w   = (const float*)d_in[18];
  const float* m3_b   = (const float*)d_in[19];
  const int* ei       = (const int*)d_in[20];
  const int* batch    = (const int*)d_in[21];
  const int* recipe   = (const int*)d_in[22];
  const int* e_src = ei;
  const int* e_dst = ei + N_EDGES;
  float* out = (float*)d_out;

  char* p = (char*)d_ws;
  auto alloc = [&](size_t bytes) {
    char* r = p;
    p += (bytes + 255) & ~(size_t)255;
    return (void*)r;
  };
  int*   bcnt     = (int*)alloc((size_t)NBKT * 4);
  int*   bstart   = (int*)alloc((size_t)(NBKT + 1) * 4);
  int*   bcursor  = (int*)alloc((size_t)NBKT * 4);
  float* dinv     = (float*)alloc((size_t)N_NODES * 4);
  int*   rowstart = (int*)alloc((size_t)(N_NODES + 1) * 4);
  int*   gstart   = (int*)alloc((size_t)(N_GRAPHS + 1) * 4);
  float* stats    = (float*)alloc(256 * 4);   // [sum1|sq1|sum2|sq2]
  float* hgraph   = (float*)alloc((size_t)N_GRAPHS * 128 * 4);
  int*   cols     = (int*)alloc((size_t)N_EDGES * 4);
  float* h0       = (float*)alloc((size_t)N_NODES * 64 * 4);
  float* h1       = (float*)alloc((size_t)N_NODES * 64 * 4);
  int*   ebuf     = (int*)h0;  // alias: ebuf dead before k_xw1 writes h0

  hipMemsetAsync(bcnt, 0, (size_t)NBKT * 4, stream);
  hipMemsetAsync(stats, 0, 256 * 4, stream);

  k_bcount<<<512, 256, 0, stream>>>(e_dst, bcnt);
  k_bscan<<<1, 256, 0, stream>>>(bcnt, bstart, bcursor, rowstart);
  k_bscatter<<<(N_EDGES + CHUNK - 1) / CHUNK, 256, 0, stream>>>(e_src, e_dst, bcursor, ebuf);
  k_bfill<<<NBKT, 256, 0, stream>>>(bstart, ebuf, rowstart, dinv, cols);
  k_xw1<<<2048, 256, 0, stream>>>(x, W1, dinv, h0);
  k_agg<<<(N_NODES + 3) / 4, 256, 0, stream>>>(h0, h1, rowstart, cols, dinv);
  k_bnstats<<<512, 256, 0, stream>>>(h1, stats);
  k_l2<<<2048, 256, 0, stream>>>(h1, h0, W2, stats, gamma1, beta1, dinv);
  k_agg<<<(N_NODES + 3) / 4, 256, 0, stream>>>(h0, h1, rowstart, cols, dinv);
  k_bnstats<<<512, 256, 0, stream>>>(h1, stats + 128);
  k_gstart<<<1, 576, 0, stream>>>(batch, gstart);
  k_pool<<<N_GRAPHS, 256, 0, stream>>>(h1, stats + 128, gamma2, beta2, gstart, hgraph);
  k_head<<<N_GRAPHS, 128, 0, stream>>>(hgraph, emb, recipe, conv_w, conv_b, fc_w, fc_b,
                                       m1_w, m1_b, m2_w, m2_b, m3_w, m3_b, out);
}

// Round 4
// 756.640 us; speedup vs baseline: 2.0958x; 1.1834x over previous
//
#include <hip/hip_runtime.h>

#define N_NODES 200000
#define N_EDGES 6400000
#define N_GRAPHS 512
#define RLEN 20
#define EMBED 8
#define EPS 1e-5f

#define NPB 1024                      // nodes per bucket
#define NBKT ((N_NODES + NPB - 1) / NPB)   // 196
#define CHUNK 4096                    // edges per k_bscatter block

typedef unsigned short ushort_t;

__device__ inline ushort_t f32_to_bf16(float f) {
  unsigned u = __float_as_uint(f);
  unsigned r = (u + 0x7fff + ((u >> 16) & 1)) >> 16;  // RNE
  return (ushort_t)r;
}
__device__ inline float bf16_to_f32(ushort_t us) {
  return __uint_as_float(((unsigned)us) << 16);
}

// ---------------- bucketed CSR build ----------------

__global__ void k_bcount(const int* __restrict__ dst, int* __restrict__ bcnt) {
  __shared__ int hist[NBKT];
  for (int i = threadIdx.x; i < NBKT; i += blockDim.x) hist[i] = 0;
  __syncthreads();
  for (int e = blockIdx.x * blockDim.x + threadIdx.x; e < N_EDGES; e += gridDim.x * blockDim.x)
    atomicAdd(&hist[dst[e] >> 10], 1);
  __syncthreads();
  for (int i = threadIdx.x; i < NBKT; i += blockDim.x)
    if (hist[i]) atomicAdd(&bcnt[i], hist[i]);
}

__global__ void k_bscan(const int* __restrict__ bcnt, int* __restrict__ bstart,
                        int* __restrict__ bcursor, int* __restrict__ rowstart) {
  __shared__ int sb[256];
  int t = threadIdx.x;
  int v = (t < NBKT) ? bcnt[t] : 0;
  sb[t] = v;
  __syncthreads();
  for (int off = 1; off < 256; off <<= 1) {
    int u = (t >= off) ? sb[t - off] : 0;
    __syncthreads();
    sb[t] += u;
    __syncthreads();
  }
  if (t < NBKT) {
    int excl = sb[t] - v;
    bstart[t] = excl;
    bcursor[t] = excl;
  }
  if (t == 0) { bstart[NBKT] = N_EDGES; rowstart[N_NODES] = N_EDGES; }
}

__global__ void __launch_bounds__(256) k_bscatter(const int* __restrict__ src,
                                                  const int* __restrict__ dst,
                                                  int* __restrict__ bcursor,
                                                  int* __restrict__ ebuf) {
  __shared__ int hist[256];
  __shared__ int scanb[256];
  __shared__ int gbase[NBKT];
  __shared__ int staged[CHUNK];
  __shared__ int addrs[CHUNK];
  __shared__ int s_total;
  int t = threadIdx.x;
  int e0 = blockIdx.x * CHUNK;
  hist[t] = 0;
  __syncthreads();

  int pk[16], bk[16], rk[16];
  #pragma unroll
  for (int k = 0; k < 16; ++k) {
    int idx = e0 + t + k * 256;
    bk[k] = -1;
    if (idx < N_EDGES) {
      int s = src[idx], d = dst[idx];
      int b = d >> 10;
      pk[k] = s | ((d & (NPB - 1)) << 18);
      bk[k] = b;
      rk[k] = atomicAdd(&hist[b], 1);
    }
  }
  __syncthreads();
  int hv = hist[t];
  scanb[t] = hv;
  __syncthreads();
  for (int off = 1; off < 256; off <<= 1) {
    int u = (t >= off) ? scanb[t - off] : 0;
    __syncthreads();
    scanb[t] += u;
    __syncthreads();
  }
  int offt = scanb[t] - hv;
  if (t < NBKT && hv > 0) gbase[t] = atomicAdd(&bcursor[t], hv);
  if (t == 255) s_total = scanb[255];
  __syncthreads();
  hist[t] = offt;
  __syncthreads();
  #pragma unroll
  for (int k = 0; k < 16; ++k) {
    if (bk[k] >= 0) {
      int slot = hist[bk[k]] + rk[k];
      staged[slot] = pk[k];
      addrs[slot] = gbase[bk[k]] + rk[k];
    }
  }
  __syncthreads();
  int total = s_total;
  for (int i = t; i < total; i += 256)
    ebuf[addrs[i]] = staged[i];
}

__global__ void __launch_bounds__(256) k_bfill(const int* __restrict__ bstart,
                                               const int* __restrict__ ebuf,
                                               int* __restrict__ rowstart,
                                               float* __restrict__ dinv,
                                               int* __restrict__ cols) {
  __shared__ int deg[NPB];
  __shared__ int cur[NPB];
  __shared__ int wsum[4];
  int b = blockIdx.x;
  int t = threadIdx.x;
  int lane = t & 63, wid = t >> 6;
  int estart = bstart[b], eend = bstart[b + 1];
  for (int i = t; i < NPB; i += 256) deg[i] = 0;
  __syncthreads();
  for (int i = estart + t; i < eend; i += 256) {
    int p = ebuf[i];
    atomicAdd(&deg[((unsigned)p) >> 18], 1);
  }
  __syncthreads();
  int d0 = deg[t * 4], d1 = deg[t * 4 + 1], d2 = deg[t * 4 + 2], d3 = deg[t * 4 + 3];
  int tsum = d0 + d1 + d2 + d3;
  int incl = tsum;
  #pragma unroll
  for (int off = 1; off < 64; off <<= 1) {
    int u = __shfl_up(incl, off);
    if (lane >= off) incl += u;
  }
  if (lane == 63) wsum[wid] = incl;
  int wexcl = incl - tsum;
  __syncthreads();
  int wbase = 0;
  for (int w = 0; w < wid; ++w) wbase += wsum[w];
  int ebase = wbase + wexcl;
  cur[t * 4 + 0] = ebase;
  cur[t * 4 + 1] = ebase + d0;
  cur[t * 4 + 2] = ebase + d0 + d1;
  cur[t * 4 + 3] = ebase + d0 + d1 + d2;
  __syncthreads();
  #pragma unroll
  for (int k = 0; k < 4; ++k) {
    int dl = t * 4 + k;
    int n = b * NPB + dl;
    if (n < N_NODES) {
      rowstart[n] = estart + cur[dl];
      dinv[n] = rsqrtf((float)(deg[dl] + 1));
    }
  }
  __syncthreads();
  for (int i = estart + t; i < eend; i += 256) {
    int p = ebuf[i];
    int dl = ((unsigned)p) >> 18;
    int lpos = atomicAdd(&cur[dl], 1);
    cols[estart + lpos] = p & 0x3FFFF;
  }
}

// ---------------- node feature pipeline ----------------

// h0[n,f] = dinv[n] * (x[n,:] @ W1)[f]; hb = bf16 copy for the gather
__global__ void k_xw1(const float* __restrict__ x, const float* __restrict__ W1,
                      const float* __restrict__ dinv, float* __restrict__ h0,
                      ushort_t* __restrict__ hb) {
  __shared__ float w1s[3 * 64];
  if (threadIdx.x < 192) w1s[threadIdx.x] = W1[threadIdx.x];
  __syncthreads();
  int lane = threadIdx.x & 63;
  int wid = threadIdx.x >> 6;
  for (int n = blockIdx.x * 4 + wid; n < N_NODES; n += gridDim.x * 4) {
    float x0 = x[n * 3 + 0], x1 = x[n * 3 + 1], x2 = x[n * 3 + 2];
    float v = x0 * w1s[lane] + x1 * w1s[64 + lane] + x2 * w1s[128 + lane];
    v *= dinv[n];
    h0[n * 64 + lane] = v;
    hb[n * 64 + lane] = f32_to_bf16(v);
  }
}

// out[d,f] = dinv[d] * ( hin_f32[d,f] + sum_{s in N(d)} bf16(hin)[s,f] )
__global__ void k_agg(const float* __restrict__ hin, const ushort_t* __restrict__ hb,
                      float* __restrict__ hout, const int* __restrict__ rowstart,
                      const int* __restrict__ cols, const float* __restrict__ dinv) {
  int node = blockIdx.x * 4 + (threadIdx.x >> 6);
  int lane = threadIdx.x & 63;
  if (node >= N_NODES) return;
  float acc = hin[node * 64 + lane];  // self loop, exact
  int base = rowstart[node];
  int len = rowstart[node + 1] - base;
  for (int c0 = 0; c0 < len; c0 += 64) {
    int rem = len - c0;
    int m = rem < 64 ? rem : 64;
    int cidx = (lane < m) ? cols[base + c0 + lane] : 0;
    int j = 0;
    for (; j + 4 <= m; j += 4) {  // 4 gather loads in flight
      int s0 = __shfl(cidx, j), s1 = __shfl(cidx, j + 1);
      int s2 = __shfl(cidx, j + 2), s3 = __shfl(cidx, j + 3);
      ushort_t u0 = hb[s0 * 64 + lane], u1 = hb[s1 * 64 + lane];
      ushort_t u2 = hb[s2 * 64 + lane], u3 = hb[s3 * 64 + lane];
      acc += (bf16_to_f32(u0) + bf16_to_f32(u1)) + (bf16_to_f32(u2) + bf16_to_f32(u3));
    }
    for (; j < m; ++j) {
      int s = __shfl(cidx, j);
      acc += bf16_to_f32(hb[s * 64 + lane]);
    }
  }
  hout[node * 64 + lane] = acc * dinv[node];
}

// per-feature sum and sumsq over all nodes -> stats[0:64], stats[64:128]
__global__ void k_bnstats(const float* __restrict__ h, float* __restrict__ stats) {
  __shared__ float ls[4][64], ls2[4][64];
  int lane = threadIdx.x & 63, wid = threadIdx.x >> 6;
  float s = 0.f, s2 = 0.f;
  for (int r = blockIdx.x * 4 + wid; r < N_NODES; r += gridDim.x * 4) {
    float v = h[r * 64 + lane];
    s += v;
    s2 += v * v;
  }
  ls[wid][lane] = s;
  ls2[wid][lane] = s2;
  __syncthreads();
  if (wid == 0) {
    float a = ls[0][lane] + ls[1][lane] + ls[2][lane] + ls[3][lane];
    float b = ls2[0][lane] + ls2[1][lane] + ls2[2][lane] + ls2[3][lane];
    atomicAdd(&stats[lane], a);
    atomicAdd(&stats[64 + lane], b);
  }
}

// hout[n,f] = dinv[n] * ( relu(bn1(h1[n,:])) @ W2 )[f]; hb = bf16 copy
__global__ void k_l2(const float* __restrict__ h1, float* __restrict__ hout,
                     ushort_t* __restrict__ hb,
                     const float* __restrict__ W2, const float* __restrict__ stats,
                     const float* __restrict__ gamma, const float* __restrict__ beta,
                     const float* __restrict__ dinv) {
  __shared__ float w2s[64 * 64];
  for (int i = threadIdx.x; i < 64 * 64; i += blockDim.x) w2s[i] = W2[i];
  __syncthreads();
  int lane = threadIdx.x & 63, wid = threadIdx.x >> 6;
  float mu = stats[lane] * (1.0f / N_NODES);
  float var = stats[64 + lane] * (1.0f / N_NODES) - mu * mu;
  float sc = rsqrtf(var + EPS) * gamma[lane];
  float sh = beta[lane] - mu * sc;
  for (int n = blockIdx.x * 4 + wid; n < N_NODES; n += gridDim.x * 4) {
    float a = h1[n * 64 + lane] * sc + sh;
    a = a > 0.f ? a : 0.f;
    float acc = 0.f;
    #pragma unroll
    for (int k = 0; k < 64; ++k) {
      acc = fmaf(__shfl(a, k), w2s[k * 64 + lane], acc);
    }
    acc *= dinv[n];
    hout[n * 64 + lane] = acc;
    hb[n * 64 + lane] = f32_to_bf16(acc);
  }
}

// ---------------- pooling + head ----------------

__global__ void k_gstart(const int* __restrict__ batch, int* __restrict__ gstart) {
  int g = blockIdx.x * blockDim.x + threadIdx.x;
  if (g > N_GRAPHS) return;
  int lo = 0, hi = N_NODES;
  while (lo < hi) {
    int mid = (lo + hi) >> 1;
    if (batch[mid] < g) lo = mid + 1; else hi = mid;
  }
  gstart[g] = lo;
}

__global__ void k_pool(const float* __restrict__ h2, const float* __restrict__ stats2,
                       const float* __restrict__ gamma, const float* __restrict__ beta,
                       const int* __restrict__ gstart, float* __restrict__ hgraph) {
  __shared__ float ssum[4][64], smax[4][64];
  int g = blockIdx.x;
  int lane = threadIdx.x & 63, wid = threadIdx.x >> 6;
  int s0 = gstart[g], s1 = gstart[g + 1];
  float mu = stats2[lane] * (1.0f / N_NODES);
  float var = stats2[64 + lane] * (1.0f / N_NODES) - mu * mu;
  float sc = rsqrtf(var + EPS) * gamma[lane];
  float sh = beta[lane] - mu * sc;
  float sum = 0.f, mx = 0.f;  // relu >= 0 -> 0 valid identity (matches empty-graph guard)
  for (int r = s0 + wid; r < s1; r += 4) {
    float v = h2[r * 64 + lane] * sc + sh;
    v = v > 0.f ? v : 0.f;
    sum += v;
    mx = v > mx ? v : mx;
  }
  ssum[wid][lane] = sum;
  smax[wid][lane] = mx;
  __syncthreads();
  if (wid == 0) {
    float s = ssum[0][lane] + ssum[1][lane] + ssum[2][lane] + ssum[3][lane];
    float m = fmaxf(fmaxf(smax[0][lane], smax[1][lane]), fmaxf(smax[2][lane], smax[3][lane]));
    int cnt = s1 - s0;
    float inv = 1.0f / (float)(cnt > 0 ? cnt : 1);
    hgraph[g * 128 + lane] = s * inv;
    hgraph[g * 128 + 64 + lane] = m;
  }
}

__global__ void k_head(const float* __restrict__ hgraph,
                       const float* __restrict__ emb, const int* __restrict__ recipe,
                       const float* __restrict__ conv_w, const float* __restrict__ conv_b,
                       const float* __restrict__ fc_w, const float* __restrict__ fc_b,
                       const float* __restrict__ m1_w, const float* __restrict__ m1_b,
                       const float* __restrict__ m2_w, const float* __restrict__ m2_b,
                       const float* __restrict__ m3_w, const float* __restrict__ m3_b,
                       float* __restrict__ out) {
  __shared__ float r_s[RLEN][EMBED];
  __shared__ float convout[16 * RLEN];
  __shared__ float cvec[192];
  __shared__ float y1[128];
  __shared__ float y2[64];
  __shared__ int rec_s[RLEN];
  __shared__ float emb_s[80];
  int g = blockIdx.x;
  int t = threadIdx.x;
  if (t < 80) emb_s[t] = emb[t];
  if (t < RLEN) rec_s[t] = recipe[g * RLEN + t];
  __syncthreads();
  for (int idx = t; idx < RLEN * EMBED; idx += blockDim.x) {
    int pos = idx >> 3, e = idx & 7;
    r_s[pos][e] = emb_s[rec_s[pos] * EMBED + e];
  }
  if (t < 128) cvec[t] = hgraph[g * 128 + t];
  __syncthreads();
  for (int idx = t; idx < 16 * RLEN; idx += blockDim.x) {
    int c = idx / RLEN, pos = idx % RLEN;
    float acc = conv_b[c];
    #pragma unroll
    for (int k = 0; k < 3; ++k) {
      int p = pos + k - 1;
      if (p >= 0 && p < RLEN) {
        #pragma unroll
        for (int e = 0; e < EMBED; ++e)
          acc = fmaf(r_s[p][e], conv_w[(c * EMBED + e) * 3 + k], acc);
      }
    }
    convout[c * RLEN + pos] = acc > 0.f ? acc : 0.f;  // channel-major flatten
  }
  __syncthreads();
  if (t < 64) {
    float acc = fc_b[t];
    for (int i = 0; i < 320; ++i) acc = fmaf(convout[i], fc_w[i * 64 + t], acc);
    cvec[128 + t] = acc > 0.f ? acc : 0.f;
  }
  __syncthreads();
  if (t < 128) {
    float acc = m1_b[t];
    for (int i = 0; i < 192; ++i) acc = fmaf(cvec[i], m1_w[i * 128 + t], acc);
    y1[t] = acc > 0.f ? acc : 0.f;
  }
  __syncthreads();
  if (t < 64) {
    float acc = m2_b[t];
    for (int i = 0; i < 128; ++i) acc = fmaf(y1[i], m2_w[i * 64 + t], acc);
    y2[t] = acc > 0.f ? acc : 0.f;
  }
  __syncthreads();
  if (t < 3) {
    float acc = m3_b[t];
    for (int i = 0; i < 64; ++i) acc = fmaf(y2[i], m3_w[i * 3 + t], acc);
    out[g * 3 + t] = acc;
  }
}

extern "C" void kernel_launch(void* const* d_in, const int* in_sizes, int n_in,
                              void* d_out, int out_size, void* d_ws, size_t ws_size,
                              hipStream_t stream) {
  const float* x      = (const float*)d_in[0];
  const float* W1     = (const float*)d_in[1];
  // b1 (d_in[2]) cancels under BN
  const float* gamma1 = (const float*)d_in[3];
  const float* beta1  = (const float*)d_in[4];
  const float* W2     = (const float*)d_in[5];
  // b2 (d_in[6]) cancels under BN
  const float* gamma2 = (const float*)d_in[7];
  const float* beta2  = (const float*)d_in[8];
  const float* emb    = (const float*)d_in[9];
  const float* conv_w = (const float*)d_in[10];
  const float* conv_b = (const float*)d_in[11];
  const float* fc_w   = (const float*)d_in[12];
  const float* fc_b   = (const float*)d_in[13];
  const float* m1_w   = (const float*)d_in[14];
  const float* m1_b   = (const float*)d_in[15];
  const float* m2_w   = (const float*)d_in[16];
  const float* m2_b   = (const float*)d_in[17];
  const float* m3_w   = (const float*)d_in[18];
  const float* m3_b   = (const float*)d_in[19];
  const int* ei       = (const int*)d_in[20];
  const int* batch    = (const int*)d_in[21];
  const int* recipe   = (const int*)d_in[22];
  const int* e_src = ei;
  const int* e_dst = ei + N_EDGES;
  float* out = (float*)d_out;

  char* p = (char*)d_ws;
  auto alloc = [&](size_t bytes) {
    char* r = p;
    p += (bytes + 255) & ~(size_t)255;
    return (void*)r;
  };
  int*   bcnt     = (int*)alloc((size_t)NBKT * 4);
  int*   bstart   = (int*)alloc((size_t)(NBKT + 1) * 4);
  int*   bcursor  = (int*)alloc((size_t)NBKT * 4);
  float* dinv     = (float*)alloc((size_t)N_NODES * 4);
  int*   rowstart = (int*)alloc((size_t)(N_NODES + 1) * 4);
  int*   gstart   = (int*)alloc((size_t)(N_GRAPHS + 1) * 4);
  float* stats    = (float*)alloc(256 * 4);   // [sum1|sq1|sum2|sq2]
  float* hgraph   = (float*)alloc((size_t)N_GRAPHS * 128 * 4);
  int*   cols     = (int*)alloc((size_t)N_EDGES * 4);
  float* h0       = (float*)alloc((size_t)N_NODES * 64 * 4);
  float* h1       = (float*)alloc((size_t)N_NODES * 64 * 4);
  ushort_t* hb    = (ushort_t*)alloc((size_t)N_NODES * 64 * 2);
  int*   ebuf     = (int*)h0;  // alias: ebuf dead before k_xw1 writes h0

  hipMemsetAsync(bcnt, 0, (size_t)NBKT * 4, stream);
  hipMemsetAsync(stats, 0, 256 * 4, stream);

  k_bcount<<<512, 256, 0, stream>>>(e_dst, bcnt);
  k_bscan<<<1, 256, 0, stream>>>(bcnt, bstart, bcursor, rowstart);
  k_bscatter<<<(N_EDGES + CHUNK - 1) / CHUNK, 256, 0, stream>>>(e_src, e_dst, bcursor, ebuf);
  k_bfill<<<NBKT, 256, 0, stream>>>(bstart, ebuf, rowstart, dinv, cols);
  k_xw1<<<2048, 256, 0, stream>>>(x, W1, dinv, h0, hb);
  k_agg<<<(N_NODES + 3) / 4, 256, 0, stream>>>(h0, hb, h1, rowstart, cols, dinv);
  k_bnstats<<<512, 256, 0, stream>>>(h1, stats);
  k_l2<<<2048, 256, 0, stream>>>(h1, h0, hb, W2, stats, gamma1, beta1, dinv);
  k_agg<<<(N_NODES + 3) / 4, 256, 0, stream>>>(h0, hb, h1, rowstart, cols, dinv);
  k_bnstats<<<512, 256, 0, stream>>>(h1, stats + 128);
  k_gstart<<<1, 576, 0, stream>>>(batch, gstart);
  k_pool<<<N_GRAPHS, 256, 0, stream>>>(h1, stats + 128, gamma2, beta2, gstart, hgraph);
  k_head<<<N_GRAPHS, 128, 0, stream>>>(hgraph, emb, recipe, conv_w, conv_b, fc_w, fc_b,
                                       m1_w, m1_b, m2_w, m2_b, m3_w, m3_b, out);
}

// Round 5
// 590.241 us; speedup vs baseline: 2.6866x; 1.2819x over previous
//
#include <hip/hip_runtime.h>

#define N_NODES 200000
#define N_EDGES 6400000
#define N_GRAPHS 512
#define RLEN 20
#define EMBED 8
#define EPS 1e-5f

#define NPB 1024                      // nodes per bucket
#define NBKT ((N_NODES + NPB - 1) / NPB)   // 196
#define CHUNK 4096                    // edges per k_bscatter block

typedef unsigned short ushort_t;
typedef __attribute__((ext_vector_type(8))) short short8;
typedef __attribute__((ext_vector_type(4))) float f32x4;

__device__ inline ushort_t f32_to_bf16(float f) {
  unsigned u = __float_as_uint(f);
  unsigned r = (u + 0x7fff + ((u >> 16) & 1)) >> 16;  // RNE
  return (ushort_t)r;
}
__device__ inline float bf16_to_f32(ushort_t us) {
  return __uint_as_float(((unsigned)us) << 16);
}
__device__ inline float bfu_lo(unsigned u) { return __uint_as_float(u << 16); }
__device__ inline float bfu_hi(unsigned u) { return __uint_as_float(u & 0xFFFF0000u); }

// ---------------- bucketed CSR build ----------------

__global__ void k_bcount(const int* __restrict__ dst, int* __restrict__ bcnt) {
  __shared__ int hist[NBKT];
  for (int i = threadIdx.x; i < NBKT; i += blockDim.x) hist[i] = 0;
  __syncthreads();
  for (int e = blockIdx.x * blockDim.x + threadIdx.x; e < N_EDGES; e += gridDim.x * blockDim.x)
    atomicAdd(&hist[dst[e] >> 10], 1);
  __syncthreads();
  for (int i = threadIdx.x; i < NBKT; i += blockDim.x)
    if (hist[i]) atomicAdd(&bcnt[i], hist[i]);
}

__global__ void k_bscan(const int* __restrict__ bcnt, int* __restrict__ bstart,
                        int* __restrict__ bcursor, int* __restrict__ rowstart) {
  __shared__ int sb[256];
  int t = threadIdx.x;
  int v = (t < NBKT) ? bcnt[t] : 0;
  sb[t] = v;
  __syncthreads();
  for (int off = 1; off < 256; off <<= 1) {
    int u = (t >= off) ? sb[t - off] : 0;
    __syncthreads();
    sb[t] += u;
    __syncthreads();
  }
  if (t < NBKT) {
    int excl = sb[t] - v;
    bstart[t] = excl;
    bcursor[t] = excl;
  }
  if (t == 0) { bstart[NBKT] = N_EDGES; rowstart[N_NODES] = N_EDGES; }
}

__global__ void __launch_bounds__(256) k_bscatter(const int* __restrict__ src,
                                                  const int* __restrict__ dst,
                                                  int* __restrict__ bcursor,
                                                  int* __restrict__ ebuf) {
  __shared__ int hist[256];
  __shared__ int scanb[256];
  __shared__ int gbase[NBKT];
  __shared__ int staged[CHUNK];
  __shared__ int addrs[CHUNK];
  __shared__ int s_total;
  int t = threadIdx.x;
  int e0 = blockIdx.x * CHUNK;
  hist[t] = 0;
  __syncthreads();

  int pk[16], bk[16], rk[16];
  #pragma unroll
  for (int k = 0; k < 16; ++k) {
    int idx = e0 + t + k * 256;
    bk[k] = -1;
    if (idx < N_EDGES) {
      int s = src[idx], d = dst[idx];
      int b = d >> 10;
      pk[k] = s | ((d & (NPB - 1)) << 18);
      bk[k] = b;
      rk[k] = atomicAdd(&hist[b], 1);
    }
  }
  __syncthreads();
  int hv = hist[t];
  scanb[t] = hv;
  __syncthreads();
  for (int off = 1; off < 256; off <<= 1) {
    int u = (t >= off) ? scanb[t - off] : 0;
    __syncthreads();
    scanb[t] += u;
    __syncthreads();
  }
  int offt = scanb[t] - hv;
  if (t < NBKT && hv > 0) gbase[t] = atomicAdd(&bcursor[t], hv);
  if (t == 255) s_total = scanb[255];
  __syncthreads();
  hist[t] = offt;
  __syncthreads();
  #pragma unroll
  for (int k = 0; k < 16; ++k) {
    if (bk[k] >= 0) {
      int slot = hist[bk[k]] + rk[k];
      staged[slot] = pk[k];
      addrs[slot] = gbase[bk[k]] + rk[k];
    }
  }
  __syncthreads();
  int total = s_total;
  for (int i = t; i < total; i += 256)
    ebuf[addrs[i]] = staged[i];
}

__global__ void __launch_bounds__(256) k_bfill(const int* __restrict__ bstart,
                                               const int* __restrict__ ebuf,
                                               int* __restrict__ rowstart,
                                               float* __restrict__ dinv,
                                               int* __restrict__ cols) {
  __shared__ int deg[NPB];
  __shared__ int cur[NPB];
  __shared__ int wsum[4];
  int b = blockIdx.x;
  int t = threadIdx.x;
  int lane = t & 63, wid = t >> 6;
  int estart = bstart[b], eend = bstart[b + 1];
  for (int i = t; i < NPB; i += 256) deg[i] = 0;
  __syncthreads();
  for (int i = estart + t; i < eend; i += 256) {
    int p = ebuf[i];
    atomicAdd(&deg[((unsigned)p) >> 18], 1);
  }
  __syncthreads();
  int d0 = deg[t * 4], d1 = deg[t * 4 + 1], d2 = deg[t * 4 + 2], d3 = deg[t * 4 + 3];
  int tsum = d0 + d1 + d2 + d3;
  int incl = tsum;
  #pragma unroll
  for (int off = 1; off < 64; off <<= 1) {
    int u = __shfl_up(incl, off);
    if (lane >= off) incl += u;
  }
  if (lane == 63) wsum[wid] = incl;
  int wexcl = incl - tsum;
  __syncthreads();
  int wbase = 0;
  for (int w = 0; w < wid; ++w) wbase += wsum[w];
  int ebase = wbase + wexcl;
  cur[t * 4 + 0] = ebase;
  cur[t * 4 + 1] = ebase + d0;
  cur[t * 4 + 2] = ebase + d0 + d1;
  cur[t * 4 + 3] = ebase + d0 + d1 + d2;
  __syncthreads();
  #pragma unroll
  for (int k = 0; k < 4; ++k) {
    int dl = t * 4 + k;
    int n = b * NPB + dl;
    if (n < N_NODES) {
      rowstart[n] = estart + cur[dl];
      dinv[n] = rsqrtf((float)(deg[dl] + 1));
    }
  }
  __syncthreads();
  for (int i = estart + t; i < eend; i += 256) {
    int p = ebuf[i];
    int dl = ((unsigned)p) >> 18;
    int lpos = atomicAdd(&cur[dl], 1);
    cols[estart + lpos] = p & 0x3FFFF;
  }
}

// ---------------- node feature pipeline ----------------

// h0[n,f] = dinv[n] * (x[n,:] @ W1)[f]; hb = bf16 copy for the gather
__global__ void k_xw1(const float* __restrict__ x, const float* __restrict__ W1,
                      const float* __restrict__ dinv, float* __restrict__ h0,
                      ushort_t* __restrict__ hb) {
  __shared__ float w1s[3 * 64];
  if (threadIdx.x < 192) w1s[threadIdx.x] = W1[threadIdx.x];
  __syncthreads();
  int lane = threadIdx.x & 63;
  int wid = threadIdx.x >> 6;
  for (int n = blockIdx.x * 4 + wid; n < N_NODES; n += gridDim.x * 4) {
    float x0 = x[n * 3 + 0], x1 = x[n * 3 + 1], x2 = x[n * 3 + 2];
    float v = x0 * w1s[lane] + x1 * w1s[64 + lane] + x2 * w1s[128 + lane];
    v *= dinv[n];
    h0[n * 64 + lane] = v;
    hb[n * 64 + lane] = f32_to_bf16(v);
  }
}

// out[d,f] = dinv[d] * ( hin_f32[d,f] + sum_{s in N(d)} bf16(hin)[s,f] )
// dword gather: lane = (half, featpair); 2 neighbors per wave-step.
__global__ void k_agg(const float* __restrict__ hin, const ushort_t* __restrict__ hb,
                      float* __restrict__ hout, const int* __restrict__ rowstart,
                      const int* __restrict__ cols, const float* __restrict__ dinv) {
  int node = blockIdx.x * 4 + (threadIdx.x >> 6);
  int lane = threadIdx.x & 63;
  if (node >= N_NODES) return;
  int half = lane >> 5;
  int fl = lane & 31;
  const unsigned* hb32 = (const unsigned*)hb;      // hb32[s*32+fl] = feats {2fl, 2fl+1}
  const float2* hin2 = (const float2*)hin;
  float2 acc;
  if (half == 0) acc = hin2[node * 32 + fl];       // self loop (exact), half0 only
  else { acc.x = 0.f; acc.y = 0.f; }
  int base = rowstart[node];
  int len = rowstart[node + 1] - base;
  for (int c0 = 0; c0 < len; c0 += 64) {
    int rem = len - c0;
    int m = rem < 64 ? rem : 64;
    int cidx = (lane < m) ? cols[base + c0 + lane] : 0;
    int j = 0;
    for (; j + 8 <= m; j += 8) {   // 8 neighbors / iter, 4 dword loads in flight per lane
      int sA = __shfl(cidx, j + half);
      int sB = __shfl(cidx, j + 2 + half);
      int sC = __shfl(cidx, j + 4 + half);
      int sD = __shfl(cidx, j + 6 + half);
      unsigned uA = hb32[sA * 32 + fl], uB = hb32[sB * 32 + fl];
      unsigned uC = hb32[sC * 32 + fl], uD = hb32[sD * 32 + fl];
      acc.x += (bfu_lo(uA) + bfu_lo(uB)) + (bfu_lo(uC) + bfu_lo(uD));
      acc.y += (bfu_hi(uA) + bfu_hi(uB)) + (bfu_hi(uC) + bfu_hi(uD));
    }
    for (; j + 2 <= m; j += 2) {
      int s = __shfl(cidx, j + half);
      unsigned u = hb32[s * 32 + fl];
      acc.x += bfu_lo(u);
      acc.y += bfu_hi(u);
    }
    if (j < m) {                   // odd leftover: half0 only
      int s = __shfl(cidx, j);
      if (half == 0) {
        unsigned u = hb32[s * 32 + fl];
        acc.x += bfu_lo(u);
        acc.y += bfu_hi(u);
      }
    }
  }
  acc.x += __shfl_xor(acc.x, 32);
  acc.y += __shfl_xor(acc.y, 32);
  if (half == 0) {
    float dv = dinv[node];
    float2 o; o.x = acc.x * dv; o.y = acc.y * dv;
    ((float2*)hout)[node * 32 + fl] = o;
  }
}

// per-feature sum and sumsq over all nodes -> stats[0:64], stats[64:128]
__global__ void k_bnstats(const float* __restrict__ h, float* __restrict__ stats) {
  __shared__ float ls[4][64], ls2[4][64];
  int lane = threadIdx.x & 63, wid = threadIdx.x >> 6;
  float s = 0.f, s2 = 0.f;
  for (int r = blockIdx.x * 4 + wid; r < N_NODES; r += gridDim.x * 4) {
    float v = h[r * 64 + lane];
    s += v;
    s2 += v * v;
  }
  ls[wid][lane] = s;
  ls2[wid][lane] = s2;
  __syncthreads();
  if (wid == 0) {
    float a = ls[0][lane] + ls[1][lane] + ls[2][lane] + ls[3][lane];
    float b = ls2[0][lane] + ls2[1][lane] + ls2[2][lane] + ls2[3][lane];
    atomicAdd(&stats[lane], a);
    atomicAdd(&stats[64 + lane], b);
  }
}

// MFMA layer-2: hout[n,:] = dinv[n] * ( relu(bn1(h1[n,:])) @ W2 ), split-bf16 (3 products)
// N_NODES = 200000 = 3125 block-iters * 4 waves * 16 rows, exact.
__global__ void __launch_bounds__(256) k_l2m(const float* __restrict__ h1,
                                             float* __restrict__ hout,
                                             ushort_t* __restrict__ hb,
                                             const float* __restrict__ W2,
                                             const float* __restrict__ stats,
                                             const float* __restrict__ gamma,
                                             const float* __restrict__ beta,
                                             const float* __restrict__ dinv) {
  __shared__ ushort_t w2t_hi[64 * 64];   // [out_feat][k], bf16 hi
  __shared__ ushort_t w2t_lo[64 * 64];   // bf16 residual
  __shared__ ushort_t at_hi[4][16 * 64]; // per-wave A tile [row][k]
  __shared__ ushort_t at_lo[4][16 * 64];
  int t = threadIdx.x;
  int lane = t & 63, wid = t >> 6;

  // stage W2^T split-bf16: w2t[f][k] = bf16split(W2[k][f])
  for (int i = t; i < 64 * 64; i += 256) {
    int f = i >> 6, k = i & 63;
    float w = W2[k * 64 + f];
    ushort_t hi = f32_to_bf16(w);
    float res = w - bf16_to_f32(hi);
    w2t_hi[f * 64 + k] = hi;
    w2t_lo[f * 64 + k] = f32_to_bf16(res);
  }
  __syncthreads();

  int col = lane & 15, kb = lane >> 4;
  // preload B fragments: [nt][ks], each 8 bf16
  short8 bhi[4][2], blo[4][2];
  #pragma unroll
  for (int nt = 0; nt < 4; ++nt) {
    #pragma unroll
    for (int ks = 0; ks < 2; ++ks) {
      int base = (nt * 16 + col) * 64 + ks * 32 + kb * 8;
      bhi[nt][ks] = *reinterpret_cast<const short8*>(&w2t_hi[base]);
      blo[nt][ks] = *reinterpret_cast<const short8*>(&w2t_lo[base]);
    }
  }

  float mu = stats[lane] * (1.0f / N_NODES);
  float var = stats[64 + lane] * (1.0f / N_NODES) - mu * mu;
  float sc = rsqrtf(var + EPS) * gamma[lane];
  float sh = beta[lane] - mu * sc;

  for (int bt = blockIdx.x; bt < 3125; bt += gridDim.x) {
    int tile = bt * 4 + wid;
    int n0 = tile * 16;
    // build split-bf16 A tile: lane = feature, rows 0..15
    #pragma unroll 4
    for (int i = 0; i < 16; ++i) {
      float a = h1[(n0 + i) * 64 + lane] * sc + sh;
      a = a > 0.f ? a : 0.f;
      ushort_t hi = f32_to_bf16(a);
      float res = a - bf16_to_f32(hi);
      at_hi[wid][i * 64 + lane] = hi;
      at_lo[wid][i * 64 + lane] = f32_to_bf16(res);
    }
    __syncthreads();  // uniform across block (3125*4 exact); drains own ds_writes

    short8 ahi[2], alo[2];
    #pragma unroll
    for (int ks = 0; ks < 2; ++ks) {
      int base = col * 64 + ks * 32 + kb * 8;   // row=col(lane&15), k-block
      ahi[ks] = *reinterpret_cast<const short8*>(&at_hi[wid][base]);
      alo[ks] = *reinterpret_cast<const short8*>(&at_lo[wid][base]);
    }
    float dv[4];
    #pragma unroll
    for (int r = 0; r < 4; ++r) dv[r] = dinv[n0 + kb * 4 + r];

    #pragma unroll
    for (int nt = 0; nt < 4; ++nt) {
      f32x4 acc = {0.f, 0.f, 0.f, 0.f};
      #pragma unroll
      for (int ks = 0; ks < 2; ++ks) {
        acc = __builtin_amdgcn_mfma_f32_16x16x32_bf16(ahi[ks], bhi[nt][ks], acc, 0, 0, 0);
        acc = __builtin_amdgcn_mfma_f32_16x16x32_bf16(ahi[ks], blo[nt][ks], acc, 0, 0, 0);
        acc = __builtin_amdgcn_mfma_f32_16x16x32_bf16(alo[ks], bhi[nt][ks], acc, 0, 0, 0);
      }
      #pragma unroll
      for (int r = 0; r < 4; ++r) {
        int node = n0 + kb * 4 + r;      // C/D: row=(lane>>4)*4+r, col=lane&15
        int feat = nt * 16 + col;
        float val = acc[r] * dv[r];
        hout[node * 64 + feat] = val;
        hb[node * 64 + feat] = f32_to_bf16(val);
      }
    }
    __syncthreads();  // protect A tile before next overwrite
  }
}

// ---------------- pooling + head ----------------

__global__ void k_gstart(const int* __restrict__ batch, int* __restrict__ gstart) {
  int g = blockIdx.x * blockDim.x + threadIdx.x;
  if (g > N_GRAPHS) return;
  int lo = 0, hi = N_NODES;
  while (lo < hi) {
    int mid = (lo + hi) >> 1;
    if (batch[mid] < g) lo = mid + 1; else hi = mid;
  }
  gstart[g] = lo;
}

__global__ void k_pool(const float* __restrict__ h2, const float* __restrict__ stats2,
                       const float* __restrict__ gamma, const float* __restrict__ beta,
                       const int* __restrict__ gstart, float* __restrict__ hgraph) {
  __shared__ float ssum[4][64], smax[4][64];
  int g = blockIdx.x;
  int lane = threadIdx.x & 63, wid = threadIdx.x >> 6;
  int s0 = gstart[g], s1 = gstart[g + 1];
  float mu = stats2[lane] * (1.0f / N_NODES);
  float var = stats2[64 + lane] * (1.0f / N_NODES) - mu * mu;
  float sc = rsqrtf(var + EPS) * gamma[lane];
  float sh = beta[lane] - mu * sc;
  float sum = 0.f, mx = 0.f;
  for (int r = s0 + wid; r < s1; r += 4) {
    float v = h2[r * 64 + lane] * sc + sh;
    v = v > 0.f ? v : 0.f;
    sum += v;
    mx = v > mx ? v : mx;
  }
  ssum[wid][lane] = sum;
  smax[wid][lane] = mx;
  __syncthreads();
  if (wid == 0) {
    float s = ssum[0][lane] + ssum[1][lane] + ssum[2][lane] + ssum[3][lane];
    float m = fmaxf(fmaxf(smax[0][lane], smax[1][lane]), fmaxf(smax[2][lane], smax[3][lane]));
    int cnt = s1 - s0;
    float inv = 1.0f / (float)(cnt > 0 ? cnt : 1);
    hgraph[g * 128 + lane] = s * inv;
    hgraph[g * 128 + 64 + lane] = m;
  }
}

__global__ void k_head(const float* __restrict__ hgraph,
                       const float* __restrict__ emb, const int* __restrict__ recipe,
                       const float* __restrict__ conv_w, const float* __restrict__ conv_b,
                       const float* __restrict__ fc_w, const float* __restrict__ fc_b,
                       const float* __restrict__ m1_w, const float* __restrict__ m1_b,
                       const float* __restrict__ m2_w, const float* __restrict__ m2_b,
                       const float* __restrict__ m3_w, const float* __restrict__ m3_b,
                       float* __restrict__ out) {
  __shared__ float r_s[RLEN][EMBED];
  __shared__ float convout[16 * RLEN];
  __shared__ float cvec[192];
  __shared__ float y1[128];
  __shared__ float y2[64];
  __shared__ int rec_s[RLEN];
  __shared__ float emb_s[80];
  int g = blockIdx.x;
  int t = threadIdx.x;
  if (t < 80) emb_s[t] = emb[t];
  if (t < RLEN) rec_s[t] = recipe[g * RLEN + t];
  __syncthreads();
  for (int idx = t; idx < RLEN * EMBED; idx += blockDim.x) {
    int pos = idx >> 3, e = idx & 7;
    r_s[pos][e] = emb_s[rec_s[pos] * EMBED + e];
  }
  if (t < 128) cvec[t] = hgraph[g * 128 + t];
  __syncthreads();
  for (int idx = t; idx < 16 * RLEN; idx += blockDim.x) {
    int c = idx / RLEN, pos = idx % RLEN;
    float acc = conv_b[c];
    #pragma unroll
    for (int k = 0; k < 3; ++k) {
      int p = pos + k - 1;
      if (p >= 0 && p < RLEN) {
        #pragma unroll
        for (int e = 0; e < EMBED; ++e)
          acc = fmaf(r_s[p][e], conv_w[(c * EMBED + e) * 3 + k], acc);
      }
    }
    convout[c * RLEN + pos] = acc > 0.f ? acc : 0.f;
  }
  __syncthreads();
  if (t < 64) {
    float acc = fc_b[t];
    for (int i = 0; i < 320; ++i) acc = fmaf(convout[i], fc_w[i * 64 + t], acc);
    cvec[128 + t] = acc > 0.f ? acc : 0.f;
  }
  __syncthreads();
  if (t < 128) {
    float acc = m1_b[t];
    for (int i = 0; i < 192; ++i) acc = fmaf(cvec[i], m1_w[i * 128 + t], acc);
    y1[t] = acc > 0.f ? acc : 0.f;
  }
  __syncthreads();
  if (t < 64) {
    float acc = m2_b[t];
    for (int i = 0; i < 128; ++i) acc = fmaf(y1[i], m2_w[i * 64 + t], acc);
    y2[t] = acc > 0.f ? acc : 0.f;
  }
  __syncthreads();
  if (t < 3) {
    float acc = m3_b[t];
    for (int i = 0; i < 64; ++i) acc = fmaf(y2[i], m3_w[i * 3 + t], acc);
    out[g * 3 + t] = acc;
  }
}

extern "C" void kernel_launch(void* const* d_in, const int* in_sizes, int n_in,
                              void* d_out, int out_size, void* d_ws, size_t ws_size,
                              hipStream_t stream) {
  const float* x      = (const float*)d_in[0];
  const float* W1     = (const float*)d_in[1];
  // b1 (d_in[2]) cancels under BN
  const float* gamma1 = (const float*)d_in[3];
  const float* beta1  = (const float*)d_in[4];
  const float* W2     = (const float*)d_in[5];
  // b2 (d_in[6]) cancels under BN
  const float* gamma2 = (const float*)d_in[7];
  const float* beta2  = (const float*)d_in[8];
  const float* emb    = (const float*)d_in[9];
  const float* conv_w = (const float*)d_in[10];
  const float* conv_b = (const float*)d_in[11];
  const float* fc_w   = (const float*)d_in[12];
  const float* fc_b   = (const float*)d_in[13];
  const float* m1_w   = (const float*)d_in[14];
  const float* m1_b   = (const float*)d_in[15];
  const float* m2_w   = (const float*)d_in[16];
  const float* m2_b   = (const float*)d_in[17];
  const float* m3_w   = (const float*)d_in[18];
  const float* m3_b   = (const float*)d_in[19];
  const int* ei       = (const int*)d_in[20];
  const int* batch    = (const int*)d_in[21];
  const int* recipe   = (const int*)d_in[22];
  const int* e_src = ei;
  const int* e_dst = ei + N_EDGES;
  float* out = (float*)d_out;

  char* p = (char*)d_ws;
  auto alloc = [&](size_t bytes) {
    char* r = p;
    p += (bytes + 255) & ~(size_t)255;
    return (void*)r;
  };
  int*   bcnt     = (int*)alloc((size_t)NBKT * 4);
  int*   bstart   = (int*)alloc((size_t)(NBKT + 1) * 4);
  int*   bcursor  = (int*)alloc((size_t)NBKT * 4);
  float* dinv     = (float*)alloc((size_t)N_NODES * 4);
  int*   rowstart = (int*)alloc((size_t)(N_NODES + 1) * 4);
  int*   gstart   = (int*)alloc((size_t)(N_GRAPHS + 1) * 4);
  float* stats    = (float*)alloc(256 * 4);   // [sum1|sq1|sum2|sq2]
  float* hgraph   = (float*)alloc((size_t)N_GRAPHS * 128 * 4);
  int*   cols     = (int*)alloc((size_t)N_EDGES * 4);
  float* h0       = (float*)alloc((size_t)N_NODES * 64 * 4);
  float* h1       = (float*)alloc((size_t)N_NODES * 64 * 4);
  ushort_t* hb    = (ushort_t*)alloc((size_t)N_NODES * 64 * 2);
  int*   ebuf     = (int*)h0;  // alias: ebuf dead before k_xw1 writes h0

  hipMemsetAsync(bcnt, 0, (size_t)NBKT * 4, stream);
  hipMemsetAsync(stats, 0, 256 * 4, stream);

  k_bcount<<<512, 256, 0, stream>>>(e_dst, bcnt);
  k_bscan<<<1, 256, 0, stream>>>(bcnt, bstart, bcursor, rowstart);
  k_bscatter<<<(N_EDGES + CHUNK - 1) / CHUNK, 256, 0, stream>>>(e_src, e_dst, bcursor, ebuf);
  k_bfill<<<NBKT, 256, 0, stream>>>(bstart, ebuf, rowstart, dinv, cols);
  k_xw1<<<2048, 256, 0, stream>>>(x, W1, dinv, h0, hb);
  k_agg<<<(N_NODES + 3) / 4, 256, 0, stream>>>(h0, hb, h1, rowstart, cols, dinv);
  k_bnstats<<<512, 256, 0, stream>>>(h1, stats);
  k_l2m<<<625, 256, 0, stream>>>(h1, h0, hb, W2, stats, gamma1, beta1, dinv);
  k_agg<<<(N_NODES + 3) / 4, 256, 0, stream>>>(h0, hb, h1, rowstart, cols, dinv);
  k_bnstats<<<512, 256, 0, stream>>>(h1, stats + 128);
  k_gstart<<<1, 576, 0, stream>>>(batch, gstart);
  k_pool<<<N_GRAPHS, 256, 0, stream>>>(h1, stats + 128, gamma2, beta2, gstart, hgraph);
  k_head<<<N_GRAPHS, 128, 0, stream>>>(hgraph, emb, recipe, conv_w, conv_b, fc_w, fc_b,
                                       m1_w, m1_b, m2_w, m2_b, m3_w, m3_b, out);
}

// Round 6
// 485.908 us; speedup vs baseline: 3.2635x; 1.2147x over previous
//
#include <hip/hip_runtime.h>

#define N_NODES 200000
#define N_EDGES 6400000
#define N_GRAPHS 512
#define RLEN 20
#define EMBED 8
#define EPS 1e-5f

#define NPB 1024                      // nodes per bucket
#define NBKT ((N_NODES + NPB - 1) / NPB)   // 196
#define CHUNK 4096                    // edges per k_bscatter block

typedef unsigned short ushort_t;
typedef __attribute__((ext_vector_type(8))) short short8;
typedef __attribute__((ext_vector_type(4))) float f32x4;

__device__ inline ushort_t f32_to_bf16(float f) {
  unsigned u = __float_as_uint(f);
  unsigned r = (u + 0x7fff + ((u >> 16) & 1)) >> 16;  // RNE
  return (ushort_t)r;
}
__device__ inline float bf16_to_f32(ushort_t us) {
  return __uint_as_float(((unsigned)us) << 16);
}
__device__ inline float bfu_lo(unsigned u) { return __uint_as_float(u << 16); }
__device__ inline float bfu_hi(unsigned u) { return __uint_as_float(u & 0xFFFF0000u); }

// ---------------- bucketed CSR build ----------------

__global__ void k_bcount(const int* __restrict__ dst, int* __restrict__ bcnt) {
  __shared__ int hist[NBKT];
  for (int i = threadIdx.x; i < NBKT; i += blockDim.x) hist[i] = 0;
  __syncthreads();
  for (int e = blockIdx.x * blockDim.x + threadIdx.x; e < N_EDGES; e += gridDim.x * blockDim.x)
    atomicAdd(&hist[dst[e] >> 10], 1);
  __syncthreads();
  for (int i = threadIdx.x; i < NBKT; i += blockDim.x)
    if (hist[i]) atomicAdd(&bcnt[i], hist[i]);
}

__global__ void k_bscan(const int* __restrict__ bcnt, int* __restrict__ bstart,
                        int* __restrict__ bcursor, int* __restrict__ rowstart) {
  __shared__ int sb[256];
  int t = threadIdx.x;
  int v = (t < NBKT) ? bcnt[t] : 0;
  sb[t] = v;
  __syncthreads();
  for (int off = 1; off < 256; off <<= 1) {
    int u = (t >= off) ? sb[t - off] : 0;
    __syncthreads();
    sb[t] += u;
    __syncthreads();
  }
  if (t < NBKT) {
    int excl = sb[t] - v;
    bstart[t] = excl;
    bcursor[t] = excl;
  }
  if (t == 0) { bstart[NBKT] = N_EDGES; rowstart[N_NODES] = N_EDGES; }
}

__global__ void __launch_bounds__(256) k_bscatter(const int* __restrict__ src,
                                                  const int* __restrict__ dst,
                                                  int* __restrict__ bcursor,
                                                  int* __restrict__ ebuf) {
  __shared__ int hist[256];
  __shared__ int scanb[256];
  __shared__ int gbase[NBKT];
  __shared__ int staged[CHUNK];
  __shared__ int addrs[CHUNK];
  __shared__ int s_total;
  int t = threadIdx.x;
  int e0 = blockIdx.x * CHUNK;
  hist[t] = 0;
  __syncthreads();

  int pk[16], bk[16], rk[16];
  #pragma unroll
  for (int k = 0; k < 16; ++k) {
    int idx = e0 + t + k * 256;
    bk[k] = -1;
    if (idx < N_EDGES) {
      int s = src[idx], d = dst[idx];
      int b = d >> 10;
      pk[k] = s | ((d & (NPB - 1)) << 18);
      bk[k] = b;
      rk[k] = atomicAdd(&hist[b], 1);
    }
  }
  __syncthreads();
  int hv = hist[t];
  scanb[t] = hv;
  __syncthreads();
  for (int off = 1; off < 256; off <<= 1) {
    int u = (t >= off) ? scanb[t - off] : 0;
    __syncthreads();
    scanb[t] += u;
    __syncthreads();
  }
  int offt = scanb[t] - hv;
  if (t < NBKT && hv > 0) gbase[t] = atomicAdd(&bcursor[t], hv);
  if (t == 255) s_total = scanb[255];
  __syncthreads();
  hist[t] = offt;
  __syncthreads();
  #pragma unroll
  for (int k = 0; k < 16; ++k) {
    if (bk[k] >= 0) {
      int slot = hist[bk[k]] + rk[k];
      staged[slot] = pk[k];
      addrs[slot] = gbase[bk[k]] + rk[k];
    }
  }
  __syncthreads();
  int total = s_total;
  for (int i = t; i < total; i += 256)
    ebuf[addrs[i]] = staged[i];
}

// per bucket: degrees -> rowstart/dinv/xs, then local scatter of cols
__global__ void __launch_bounds__(256) k_bfill(const int* __restrict__ bstart,
                                               const int* __restrict__ ebuf,
                                               const float* __restrict__ x,
                                               int* __restrict__ rowstart,
                                               float* __restrict__ dinv,
                                               float4* __restrict__ xs,
                                               int* __restrict__ cols) {
  __shared__ int deg[NPB];
  __shared__ int cur[NPB];
  __shared__ int wsum[4];
  int b = blockIdx.x;
  int t = threadIdx.x;
  int lane = t & 63, wid = t >> 6;
  int estart = bstart[b], eend = bstart[b + 1];
  for (int i = t; i < NPB; i += 256) deg[i] = 0;
  __syncthreads();
  for (int i = estart + t; i < eend; i += 256) {
    int p = ebuf[i];
    atomicAdd(&deg[((unsigned)p) >> 18], 1);
  }
  __syncthreads();
  int d0 = deg[t * 4], d1 = deg[t * 4 + 1], d2 = deg[t * 4 + 2], d3 = deg[t * 4 + 3];
  int tsum = d0 + d1 + d2 + d3;
  int incl = tsum;
  #pragma unroll
  for (int off = 1; off < 64; off <<= 1) {
    int u = __shfl_up(incl, off);
    if (lane >= off) incl += u;
  }
  if (lane == 63) wsum[wid] = incl;
  int wexcl = incl - tsum;
  __syncthreads();
  int wbase = 0;
  for (int w = 0; w < wid; ++w) wbase += wsum[w];
  int ebase = wbase + wexcl;
  cur[t * 4 + 0] = ebase;
  cur[t * 4 + 1] = ebase + d0;
  cur[t * 4 + 2] = ebase + d0 + d1;
  cur[t * 4 + 3] = ebase + d0 + d1 + d2;
  __syncthreads();
  #pragma unroll
  for (int k = 0; k < 4; ++k) {
    int dl = t * 4 + k;
    int n = b * NPB + dl;
    if (n < N_NODES) {
      rowstart[n] = estart + cur[dl];
      float dv = rsqrtf((float)(deg[dl] + 1));
      dinv[n] = dv;
      float4 v;
      v.x = x[n * 3 + 0] * dv;
      v.y = x[n * 3 + 1] * dv;
      v.z = x[n * 3 + 2] * dv;
      v.w = 0.f;
      xs[n] = v;
    }
  }
  __syncthreads();
  for (int i = estart + t; i < eend; i += 256) {
    int p = ebuf[i];
    int dl = ((unsigned)p) >> 18;
    int lpos = atomicAdd(&cur[dl], 1);
    cols[estart + lpos] = p & 0x3FFFF;
  }
}

// ---------------- layer-1: aggregate 3-feature x (linearity of GCN) ----------------

// t[n] = dinv[n] * ( xs[n] + sum_{s in N(n)} xs[s] ),   xs = dinv * x  (L2-resident, 3.2 MB)
__global__ void k_agg1(const float4* __restrict__ xs, float4* __restrict__ t,
                       const int* __restrict__ rowstart, const int* __restrict__ cols,
                       const float* __restrict__ dinv) {
  int n = blockIdx.x * blockDim.x + threadIdx.x;
  if (n >= N_NODES) return;
  float4 self = xs[n];
  float a0 = self.x, a1 = self.y, a2 = self.z;
  float b0 = 0.f, b1 = 0.f, b2 = 0.f;
  float c0 = 0.f, c1 = 0.f, c2 = 0.f;
  float e0 = 0.f, e1 = 0.f, e2 = 0.f;
  int base = rowstart[n];
  int len = rowstart[n + 1] - base;
  int j = 0;
  for (; j + 4 <= len; j += 4) {   // 4 float4 loads in flight
    int s0 = cols[base + j], s1 = cols[base + j + 1];
    int s2 = cols[base + j + 2], s3 = cols[base + j + 3];
    float4 v0 = xs[s0], v1 = xs[s1], v2 = xs[s2], v3 = xs[s3];
    a0 += v0.x; a1 += v0.y; a2 += v0.z;
    b0 += v1.x; b1 += v1.y; b2 += v1.z;
    c0 += v2.x; c1 += v2.y; c2 += v2.z;
    e0 += v3.x; e1 += v3.y; e2 += v3.z;
  }
  for (; j < len; ++j) {
    float4 v = xs[cols[base + j]];
    a0 += v.x; a1 += v.y; a2 += v.z;
  }
  float dv = dinv[n];
  float4 o;
  o.x = dv * ((a0 + b0) + (c0 + e0));
  o.y = dv * ((a1 + b1) + (c1 + e1));
  o.z = dv * ((a2 + b2) + (c2 + e2));
  o.w = 0.f;
  t[n] = o;
}

// moments of t: mom[0..2] = sum t, mom[3..8] = sum {t0t0,t0t1,t0t2,t1t1,t1t2,t2t2}
__global__ void k_mom(const float4* __restrict__ t, float* __restrict__ mom) {
  float m[9] = {0.f, 0.f, 0.f, 0.f, 0.f, 0.f, 0.f, 0.f, 0.f};
  for (int n = blockIdx.x * blockDim.x + threadIdx.x; n < N_NODES; n += gridDim.x * blockDim.x) {
    float4 v = t[n];
    m[0] += v.x; m[1] += v.y; m[2] += v.z;
    m[3] += v.x * v.x; m[4] += v.x * v.y; m[5] += v.x * v.z;
    m[6] += v.y * v.y; m[7] += v.y * v.z; m[8] += v.z * v.z;
  }
  #pragma unroll
  for (int off = 32; off; off >>= 1) {
    #pragma unroll
    for (int i = 0; i < 9; ++i) m[i] += __shfl_xor(m[i], off);
  }
  __shared__ float ls[4][9];
  int lane = threadIdx.x & 63, wid = threadIdx.x >> 6;
  if (lane == 0) {
    #pragma unroll
    for (int i = 0; i < 9; ++i) ls[wid][i] = m[i];
  }
  __syncthreads();
  if (threadIdx.x < 9) {
    float s = ls[0][threadIdx.x] + ls[1][threadIdx.x] + ls[2][threadIdx.x] + ls[3][threadIdx.x];
    atomicAdd(&mom[threadIdx.x], s);
  }
}

// fused layer-2 front end: h1 = t @ W1 (in-register), BN1 (stats from moments),
// relu, @W2 via split-bf16 MFMA, scale by dinv -> hb (bf16 only)
__global__ void __launch_bounds__(256) k_l2m2(const float4* __restrict__ t,
                                              ushort_t* __restrict__ hb,
                                              const float* __restrict__ W1,
                                              const float* __restrict__ W2,
                                              const float* __restrict__ mom,
                                              const float* __restrict__ gamma,
                                              const float* __restrict__ beta,
                                              const float* __restrict__ dinv) {
  __shared__ float w1s[192];
  __shared__ ushort_t w2t_hi[64 * 64];   // [out_feat][k]
  __shared__ ushort_t w2t_lo[64 * 64];
  __shared__ float tt[4][16][4];
  __shared__ ushort_t at_hi[4][16 * 64];
  __shared__ ushort_t at_lo[4][16 * 64];
  int tix = threadIdx.x;
  int lane = tix & 63, wid = tix >> 6;
  if (tix < 192) w1s[tix] = W1[tix];
  for (int i = tix; i < 64 * 64; i += 256) {
    int f = i >> 6, k = i & 63;
    float w = W2[k * 64 + f];
    ushort_t hi = f32_to_bf16(w);
    w2t_hi[i] = hi;
    w2t_lo[i] = f32_to_bf16(w - bf16_to_f32(hi));
  }
  __syncthreads();

  int col = lane & 15, kb = lane >> 4;
  short8 bhi[4][2], blo[4][2];
  #pragma unroll
  for (int nt = 0; nt < 4; ++nt) {
    #pragma unroll
    for (int ks = 0; ks < 2; ++ks) {
      int base = (nt * 16 + col) * 64 + ks * 32 + kb * 8;
      bhi[nt][ks] = *reinterpret_cast<const short8*>(&w2t_hi[base]);
      blo[nt][ks] = *reinterpret_cast<const short8*>(&w2t_lo[base]);
    }
  }

  // BN1 constants from 3x3 moments: lane = feature
  float inv_n = 1.0f / N_NODES;
  float w0 = w1s[lane], w1 = w1s[64 + lane], w2 = w1s[128 + lane];
  float mu = (mom[0] * w0 + mom[1] * w1 + mom[2] * w2) * inv_n;
  float eh2 = (mom[3] * w0 * w0 + 2.f * mom[4] * w0 * w1 + 2.f * mom[5] * w0 * w2 +
               mom[6] * w1 * w1 + 2.f * mom[7] * w1 * w2 + mom[8] * w2 * w2) * inv_n;
  float var = eh2 - mu * mu;
  float sc = rsqrtf(var + EPS) * gamma[lane];
  float sh = beta[lane] - mu * sc;

  for (int bt = blockIdx.x; bt < 3125; bt += gridDim.x) {
    int n0 = (bt * 4 + wid) * 16;
    if (lane < 16) {
      float4 v = t[n0 + lane];
      tt[wid][lane][0] = v.x; tt[wid][lane][1] = v.y; tt[wid][lane][2] = v.z;
    }
    // per-wave LDS tiles: same-wave in-order LDS + compiler lgkmcnt waits suffice
    #pragma unroll 4
    for (int i = 0; i < 16; ++i) {
      float h = tt[wid][i][0] * w0 + tt[wid][i][1] * w1 + tt[wid][i][2] * w2;
      float a = h * sc + sh;
      a = a > 0.f ? a : 0.f;
      ushort_t hi = f32_to_bf16(a);
      at_hi[wid][i * 64 + lane] = hi;
      at_lo[wid][i * 64 + lane] = f32_to_bf16(a - bf16_to_f32(hi));
    }
    short8 ahi[2], alo[2];
    #pragma unroll
    for (int ks = 0; ks < 2; ++ks) {
      int base = col * 64 + ks * 32 + kb * 8;   // A: row=lane&15, k-block
      ahi[ks] = *reinterpret_cast<const short8*>(&at_hi[wid][base]);
      alo[ks] = *reinterpret_cast<const short8*>(&at_lo[wid][base]);
    }
    float dv[4];
    #pragma unroll
    for (int r = 0; r < 4; ++r) dv[r] = dinv[n0 + kb * 4 + r];

    #pragma unroll
    for (int nt = 0; nt < 4; ++nt) {
      f32x4 acc = {0.f, 0.f, 0.f, 0.f};
      #pragma unroll
      for (int ks = 0; ks < 2; ++ks) {
        acc = __builtin_amdgcn_mfma_f32_16x16x32_bf16(ahi[ks], bhi[nt][ks], acc, 0, 0, 0);
        acc = __builtin_amdgcn_mfma_f32_16x16x32_bf16(ahi[ks], blo[nt][ks], acc, 0, 0, 0);
        acc = __builtin_amdgcn_mfma_f32_16x16x32_bf16(alo[ks], bhi[nt][ks], acc, 0, 0, 0);
      }
      #pragma unroll
      for (int r = 0; r < 4; ++r) {
        int node = n0 + kb * 4 + r;      // C/D: row=(lane>>4)*4+r, col=lane&15
        int feat = nt * 16 + col;
        hb[node * 64 + feat] = f32_to_bf16(acc[r] * dv[r]);
      }
    }
  }
}

// layer-2 aggregation: h1[d,f] = dinv[d] * ( hb[d,f] + sum_{s} hb[s,f] )  (all bf16 reads)
__global__ void k_agg2(const ushort_t* __restrict__ hb, float* __restrict__ hout,
                       const int* __restrict__ rowstart, const int* __restrict__ cols,
                       const float* __restrict__ dinv) {
  int node = blockIdx.x * 4 + (threadIdx.x >> 6);
  int lane = threadIdx.x & 63;
  if (node >= N_NODES) return;
  int half = lane >> 5;
  int fl = lane & 31;
  const unsigned* hb32 = (const unsigned*)hb;      // hb32[s*32+fl] = feats {2fl, 2fl+1}
  float2 acc;
  if (half == 0) {                                  // self loop (bf16)
    unsigned u = hb32[node * 32 + fl];
    acc.x = bfu_lo(u); acc.y = bfu_hi(u);
  } else { acc.x = 0.f; acc.y = 0.f; }
  int base = rowstart[node];
  int len = rowstart[node + 1] - base;
  for (int c0 = 0; c0 < len; c0 += 64) {
    int rem = len - c0;
    int m = rem < 64 ? rem : 64;
    int cidx = (lane < m) ? cols[base + c0 + lane] : 0;
    int j = 0;
    for (; j + 8 <= m; j += 8) {   // 8 neighbors / iter, 4 dword loads in flight per lane
      int sA = __shfl(cidx, j + half);
      int sB = __shfl(cidx, j + 2 + half);
      int sC = __shfl(cidx, j + 4 + half);
      int sD = __shfl(cidx, j + 6 + half);
      unsigned uA = hb32[sA * 32 + fl], uB = hb32[sB * 32 + fl];
      unsigned uC = hb32[sC * 32 + fl], uD = hb32[sD * 32 + fl];
      acc.x += (bfu_lo(uA) + bfu_lo(uB)) + (bfu_lo(uC) + bfu_lo(uD));
      acc.y += (bfu_hi(uA) + bfu_hi(uB)) + (bfu_hi(uC) + bfu_hi(uD));
    }
    for (; j + 2 <= m; j += 2) {
      int s = __shfl(cidx, j + half);
      unsigned u = hb32[s * 32 + fl];
      acc.x += bfu_lo(u);
      acc.y += bfu_hi(u);
    }
    if (j < m) {                   // odd leftover: half0 only
      int s = __shfl(cidx, j);
      if (half == 0) {
        unsigned u = hb32[s * 32 + fl];
        acc.x += bfu_lo(u);
        acc.y += bfu_hi(u);
      }
    }
  }
  acc.x += __shfl_xor(acc.x, 32);
  acc.y += __shfl_xor(acc.y, 32);
  if (half == 0) {
    float dv = dinv[node];
    float2 o; o.x = acc.x * dv; o.y = acc.y * dv;
    ((float2*)hout)[node * 32 + fl] = o;
  }
}

// per-feature sum and sumsq over all nodes -> stats[0:64], stats[64:128]
__global__ void k_bnstats(const float* __restrict__ h, float* __restrict__ stats) {
  __shared__ float ls[4][64], ls2[4][64];
  int lane = threadIdx.x & 63, wid = threadIdx.x >> 6;
  float s = 0.f, s2 = 0.f;
  for (int r = blockIdx.x * 4 + wid; r < N_NODES; r += gridDim.x * 4) {
    float v = h[r * 64 + lane];
    s += v;
    s2 += v * v;
  }
  ls[wid][lane] = s;
  ls2[wid][lane] = s2;
  __syncthreads();
  if (wid == 0) {
    float a = ls[0][lane] + ls[1][lane] + ls[2][lane] + ls[3][lane];
    float b = ls2[0][lane] + ls2[1][lane] + ls2[2][lane] + ls2[3][lane];
    atomicAdd(&stats[lane], a);
    atomicAdd(&stats[64 + lane], b);
  }
}

// ---------------- pooling + head ----------------

__global__ void k_gstart(const int* __restrict__ batch, int* __restrict__ gstart) {
  int g = blockIdx.x * blockDim.x + threadIdx.x;
  if (g > N_GRAPHS) return;
  int lo = 0, hi = N_NODES;
  while (lo < hi) {
    int mid = (lo + hi) >> 1;
    if (batch[mid] < g) lo = mid + 1; else hi = mid;
  }
  gstart[g] = lo;
}

__global__ void k_pool(const float* __restrict__ h2, const float* __restrict__ stats2,
                       const float* __restrict__ gamma, const float* __restrict__ beta,
                       const int* __restrict__ gstart, float* __restrict__ hgraph) {
  __shared__ float ssum[4][64], smax[4][64];
  int g = blockIdx.x;
  int lane = threadIdx.x & 63, wid = threadIdx.x >> 6;
  int s0 = gstart[g], s1 = gstart[g + 1];
  float mu = stats2[lane] * (1.0f / N_NODES);
  float var = stats2[64 + lane] * (1.0f / N_NODES) - mu * mu;
  float sc = rsqrtf(var + EPS) * gamma[lane];
  float sh = beta[lane] - mu * sc;
  float sum = 0.f, mx = 0.f;
  for (int r = s0 + wid; r < s1; r += 4) {
    float v = h2[r * 64 + lane] * sc + sh;
    v = v > 0.f ? v : 0.f;
    sum += v;
    mx = v > mx ? v : mx;
  }
  ssum[wid][lane] = sum;
  smax[wid][lane] = mx;
  __syncthreads();
  if (wid == 0) {
    float s = ssum[0][lane] + ssum[1][lane] + ssum[2][lane] + ssum[3][lane];
    float m = fmaxf(fmaxf(smax[0][lane], smax[1][lane]), fmaxf(smax[2][lane], smax[3][lane]));
    int cnt = s1 - s0;
    float inv = 1.0f / (float)(cnt > 0 ? cnt : 1);
    hgraph[g * 128 + lane] = s * inv;
    hgraph[g * 128 + 64 + lane] = m;
  }
}

__global__ void k_head(const float* __restrict__ hgraph,
                       const float* __restrict__ emb, const int* __restrict__ recipe,
                       const float* __restrict__ conv_w, const float* __restrict__ conv_b,
                       const float* __restrict__ fc_w, const float* __restrict__ fc_b,
                       const float* __restrict__ m1_w, const float* __restrict__ m1_b,
                       const float* __restrict__ m2_w, const float* __restrict__ m2_b,
                       const float* __restrict__ m3_w, const float* __restrict__ m3_b,
                       float* __restrict__ out) {
  __shared__ float r_s[RLEN][EMBED];
  __shared__ float convout[16 * RLEN];
  __shared__ float cvec[192];
  __shared__ float y1[128];
  __shared__ float y2[64];
  __shared__ int rec_s[RLEN];
  __shared__ float emb_s[80];
  int g = blockIdx.x;
  int t = threadIdx.x;
  if (t < 80) emb_s[t] = emb[t];
  if (t < RLEN) rec_s[t] = recipe[g * RLEN + t];
  __syncthreads();
  for (int idx = t; idx < RLEN * EMBED; idx += blockDim.x) {
    int pos = idx >> 3, e = idx & 7;
    r_s[pos][e] = emb_s[rec_s[pos] * EMBED + e];
  }
  if (t < 128) cvec[t] = hgraph[g * 128 + t];
  __syncthreads();
  for (int idx = t; idx < 16 * RLEN; idx += blockDim.x) {
    int c = idx / RLEN, pos = idx % RLEN;
    float acc = conv_b[c];
    #pragma unroll
    for (int k = 0; k < 3; ++k) {
      int p = pos + k - 1;
      if (p >= 0 && p < RLEN) {
        #pragma unroll
        for (int e = 0; e < EMBED; ++e)
          acc = fmaf(r_s[p][e], conv_w[(c * EMBED + e) * 3 + k], acc);
      }
    }
    convout[c * RLEN + pos] = acc > 0.f ? acc : 0.f;
  }
  __syncthreads();
  if (t < 64) {
    float acc = fc_b[t];
    for (int i = 0; i < 320; ++i) acc = fmaf(convout[i], fc_w[i * 64 + t], acc);
    cvec[128 + t] = acc > 0.f ? acc : 0.f;
  }
  __syncthreads();
  if (t < 128) {
    float acc = m1_b[t];
    for (int i = 0; i < 192; ++i) acc = fmaf(cvec[i], m1_w[i * 128 + t], acc);
    y1[t] = acc > 0.f ? acc : 0.f;
  }
  __syncthreads();
  if (t < 64) {
    float acc = m2_b[t];
    for (int i = 0; i < 128; ++i) acc = fmaf(y1[i], m2_w[i * 64 + t], acc);
    y2[t] = acc > 0.f ? acc : 0.f;
  }
  __syncthreads();
  if (t < 3) {
    float acc = m3_b[t];
    for (int i = 0; i < 64; ++i) acc = fmaf(y2[i], m3_w[i * 3 + t], acc);
    out[g * 3 + t] = acc;
  }
}

extern "C" void kernel_launch(void* const* d_in, const int* in_sizes, int n_in,
                              void* d_out, int out_size, void* d_ws, size_t ws_size,
                              hipStream_t stream) {
  const float* x      = (const float*)d_in[0];
  const float* W1     = (const float*)d_in[1];
  // b1 (d_in[2]) cancels under BN
  const float* gamma1 = (const float*)d_in[3];
  const float* beta1  = (const float*)d_in[4];
  const float* W2     = (const float*)d_in[5];
  // b2 (d_in[6]) cancels under BN
  const float* gamma2 = (const float*)d_in[7];
  const float* beta2  = (const float*)d_in[8];
  const float* emb    = (const float*)d_in[9];
  const float* conv_w = (const float*)d_in[10];
  const float* conv_b = (const float*)d_in[11];
  const float* fc_w   = (const float*)d_in[12];
  const float* fc_b   = (const float*)d_in[13];
  const float* m1_w   = (const float*)d_in[14];
  const float* m1_b   = (const float*)d_in[15];
  const float* m2_w   = (const float*)d_in[16];
  const float* m2_b   = (const float*)d_in[17];
  const float* m3_w   = (const float*)d_in[18];
  const float* m3_b   = (const float*)d_in[19];
  const int* ei       = (const int*)d_in[20];
  const int* batch    = (const int*)d_in[21];
  const int* recipe   = (const int*)d_in[22];
  const int* e_src = ei;
  const int* e_dst = ei + N_EDGES;
  float* out = (float*)d_out;

  char* p = (char*)d_ws;
  auto alloc = [&](size_t bytes) {
    char* r = p;
    p += (bytes + 255) & ~(size_t)255;
    return (void*)r;
  };
  int*   bcnt     = (int*)alloc((size_t)NBKT * 4);
  int*   bstart   = (int*)alloc((size_t)(NBKT + 1) * 4);
  int*   bcursor  = (int*)alloc((size_t)NBKT * 4);
  float* dinv     = (float*)alloc((size_t)N_NODES * 4);
  int*   rowstart = (int*)alloc((size_t)(N_NODES + 1) * 4);
  int*   gstart   = (int*)alloc((size_t)(N_GRAPHS + 1) * 4);
  float* stats    = (float*)alloc(256 * 4);
  float* mom      = (float*)alloc(16 * 4);
  float* hgraph   = (float*)alloc((size_t)N_GRAPHS * 128 * 4);
  int*   cols     = (int*)alloc((size_t)N_EDGES * 4);
  float4* xs      = (float4*)alloc((size_t)N_NODES * 16);
  float4* tbuf    = (float4*)alloc((size_t)N_NODES * 16);
  float* h1       = (float*)alloc((size_t)N_NODES * 64 * 4);
  ushort_t* hb    = (ushort_t*)alloc((size_t)N_NODES * 64 * 2);
  int*   ebuf     = (int*)h1;  // alias: ebuf dead before k_agg2 writes h1

  hipMemsetAsync(bcnt, 0, (size_t)NBKT * 4, stream);
  hipMemsetAsync(stats, 0, 256 * 4, stream);
  hipMemsetAsync(mom, 0, 16 * 4, stream);

  k_bcount<<<512, 256, 0, stream>>>(e_dst, bcnt);
  k_bscan<<<1, 256, 0, stream>>>(bcnt, bstart, bcursor, rowstart);
  k_bscatter<<<(N_EDGES + CHUNK - 1) / CHUNK, 256, 0, stream>>>(e_src, e_dst, bcursor, ebuf);
  k_bfill<<<NBKT, 256, 0, stream>>>(bstart, ebuf, x, rowstart, dinv, xs, cols);
  k_agg1<<<(N_NODES + 255) / 256, 256, 0, stream>>>(xs, tbuf, rowstart, cols, dinv);
  k_mom<<<256, 256, 0, stream>>>(tbuf, mom);
  k_l2m2<<<625, 256, 0, stream>>>(tbuf, hb, W1, W2, mom, gamma1, beta1, dinv);
  k_agg2<<<(N_NODES + 3) / 4, 256, 0, stream>>>(hb, h1, rowstart, cols, dinv);
  k_bnstats<<<512, 256, 0, stream>>>(h1, stats);
  k_gstart<<<1, 576, 0, stream>>>(batch, gstart);
  k_pool<<<N_GRAPHS, 256, 0, stream>>>(h1, stats, gamma2, beta2, gstart, hgraph);
  k_head<<<N_GRAPHS, 128, 0, stream>>>(hgraph, emb, recipe, conv_w, conv_b, fc_w, fc_b,
                                       m1_w, m1_b, m2_w, m2_b, m3_w, m3_b, out);
}

// Round 7
// 464.198 us; speedup vs baseline: 3.4161x; 1.0468x over previous
//
#include <hip/hip_runtime.h>

#define N_NODES 200000
#define N_EDGES 6400000
#define N_GRAPHS 512
#define RLEN 20
#define EMBED 8
#define EPS 1e-5f

#define NPB 1024                      // nodes per bucket
#define NBKT ((N_NODES + NPB - 1) / NPB)   // 196
#define CHUNK 4096                    // edges per k_bscatter block

typedef unsigned short ushort_t;
typedef __attribute__((ext_vector_type(8))) short short8;
typedef __attribute__((ext_vector_type(4))) float f32x4;

__device__ inline ushort_t f32_to_bf16(float f) {
  unsigned u = __float_as_uint(f);
  unsigned r = (u + 0x7fff + ((u >> 16) & 1)) >> 16;  // RNE
  return (ushort_t)r;
}
__device__ inline float bf16_to_f32(ushort_t us) {
  return __uint_as_float(((unsigned)us) << 16);
}
__device__ inline float bfu_lo(unsigned u) { return __uint_as_float(u << 16); }
__device__ inline float bfu_hi(unsigned u) { return __uint_as_float(u & 0xFFFF0000u); }

// ---------------- bucketed CSR build ----------------

__global__ void k_bcount(const int* __restrict__ dst, int* __restrict__ bcnt) {
  __shared__ int hist[NBKT];
  for (int i = threadIdx.x; i < NBKT; i += blockDim.x) hist[i] = 0;
  __syncthreads();
  for (int e = blockIdx.x * blockDim.x + threadIdx.x; e < N_EDGES; e += gridDim.x * blockDim.x)
    atomicAdd(&hist[dst[e] >> 10], 1);
  __syncthreads();
  for (int i = threadIdx.x; i < NBKT; i += blockDim.x)
    if (hist[i]) atomicAdd(&bcnt[i], hist[i]);
}

__global__ void k_bscan(const int* __restrict__ bcnt, int* __restrict__ bstart,
                        int* __restrict__ bcursor, int* __restrict__ rowstart) {
  __shared__ int sb[256];
  int t = threadIdx.x;
  int v = (t < NBKT) ? bcnt[t] : 0;
  sb[t] = v;
  __syncthreads();
  for (int off = 1; off < 256; off <<= 1) {
    int u = (t >= off) ? sb[t - off] : 0;
    __syncthreads();
    sb[t] += u;
    __syncthreads();
  }
  if (t < NBKT) {
    int excl = sb[t] - v;
    bstart[t] = excl;
    bcursor[t] = excl;
  }
  if (t == 0) { bstart[NBKT] = N_EDGES; rowstart[N_NODES] = N_EDGES; }
}

__global__ void __launch_bounds__(256) k_bscatter(const int* __restrict__ src,
                                                  const int* __restrict__ dst,
                                                  int* __restrict__ bcursor,
                                                  int* __restrict__ ebuf) {
  __shared__ int hist[256];
  __shared__ int scanb[256];
  __shared__ int gbase[NBKT];
  __shared__ int staged[CHUNK];
  __shared__ int addrs[CHUNK];
  __shared__ int s_total;
  int t = threadIdx.x;
  int e0 = blockIdx.x * CHUNK;
  hist[t] = 0;
  __syncthreads();

  int pk[16], bk[16], rk[16];
  #pragma unroll
  for (int k = 0; k < 16; ++k) {
    int idx = e0 + t + k * 256;
    bk[k] = -1;
    if (idx < N_EDGES) {
      int s = src[idx], d = dst[idx];
      int b = d >> 10;
      pk[k] = s | ((d & (NPB - 1)) << 18);
      bk[k] = b;
      rk[k] = atomicAdd(&hist[b], 1);
    }
  }
  __syncthreads();
  int hv = hist[t];
  scanb[t] = hv;
  __syncthreads();
  for (int off = 1; off < 256; off <<= 1) {
    int u = (t >= off) ? scanb[t - off] : 0;
    __syncthreads();
    scanb[t] += u;
    __syncthreads();
  }
  int offt = scanb[t] - hv;
  if (t < NBKT && hv > 0) gbase[t] = atomicAdd(&bcursor[t], hv);
  if (t == 255) s_total = scanb[255];
  __syncthreads();
  hist[t] = offt;
  __syncthreads();
  #pragma unroll
  for (int k = 0; k < 16; ++k) {
    if (bk[k] >= 0) {
      int slot = hist[bk[k]] + rk[k];
      staged[slot] = pk[k];
      addrs[slot] = gbase[bk[k]] + rk[k];
    }
  }
  __syncthreads();
  int total = s_total;
  for (int i = t; i < total; i += 256)
    ebuf[addrs[i]] = staged[i];
}

// per bucket: degrees -> rowstart/dinv/xs, then local scatter of cols
__global__ void __launch_bounds__(256) k_bfill(const int* __restrict__ bstart,
                                               const int* __restrict__ ebuf,
                                               const float* __restrict__ x,
                                               int* __restrict__ rowstart,
                                               float* __restrict__ dinv,
                                               float4* __restrict__ xs,
                                               int* __restrict__ cols) {
  __shared__ int deg[NPB];
  __shared__ int cur[NPB];
  __shared__ int wsum[4];
  int b = blockIdx.x;
  int t = threadIdx.x;
  int lane = t & 63, wid = t >> 6;
  int estart = bstart[b], eend = bstart[b + 1];
  for (int i = t; i < NPB; i += 256) deg[i] = 0;
  __syncthreads();
  for (int i = estart + t; i < eend; i += 256) {
    int p = ebuf[i];
    atomicAdd(&deg[((unsigned)p) >> 18], 1);
  }
  __syncthreads();
  int d0 = deg[t * 4], d1 = deg[t * 4 + 1], d2 = deg[t * 4 + 2], d3 = deg[t * 4 + 3];
  int tsum = d0 + d1 + d2 + d3;
  int incl = tsum;
  #pragma unroll
  for (int off = 1; off < 64; off <<= 1) {
    int u = __shfl_up(incl, off);
    if (lane >= off) incl += u;
  }
  if (lane == 63) wsum[wid] = incl;
  int wexcl = incl - tsum;
  __syncthreads();
  int wbase = 0;
  for (int w = 0; w < wid; ++w) wbase += wsum[w];
  int ebase = wbase + wexcl;
  cur[t * 4 + 0] = ebase;
  cur[t * 4 + 1] = ebase + d0;
  cur[t * 4 + 2] = ebase + d0 + d1;
  cur[t * 4 + 3] = ebase + d0 + d1 + d2;
  __syncthreads();
  #pragma unroll
  for (int k = 0; k < 4; ++k) {
    int dl = t * 4 + k;
    int n = b * NPB + dl;
    if (n < N_NODES) {
      rowstart[n] = estart + cur[dl];
      float dv = rsqrtf((float)(deg[dl] + 1));
      dinv[n] = dv;
      float4 v;
      v.x = x[n * 3 + 0] * dv;
      v.y = x[n * 3 + 1] * dv;
      v.z = x[n * 3 + 2] * dv;
      v.w = 0.f;
      xs[n] = v;
    }
  }
  __syncthreads();
  for (int i = estart + t; i < eend; i += 256) {
    int p = ebuf[i];
    int dl = ((unsigned)p) >> 18;
    int lpos = atomicAdd(&cur[dl], 1);
    cols[estart + lpos] = p & 0x3FFFF;
  }
}

// ---------------- layer-1: aggregate 3-feature x + fused 3x3 moments ----------------

// t[n] = dinv[n] * ( xs[n] + sum_{s in N(n)} xs[s] );  mom += [sum t, sum t t^T]
__global__ void k_agg1(const float4* __restrict__ xs, float4* __restrict__ t,
                       const int* __restrict__ rowstart, const int* __restrict__ cols,
                       const float* __restrict__ dinv, float* __restrict__ mom) {
  int n = blockIdx.x * blockDim.x + threadIdx.x;
  float m9[9] = {0.f, 0.f, 0.f, 0.f, 0.f, 0.f, 0.f, 0.f, 0.f};
  if (n < N_NODES) {
    float4 self = xs[n];
    float a0 = self.x, a1 = self.y, a2 = self.z;
    float b0 = 0.f, b1 = 0.f, b2 = 0.f;
    float c0 = 0.f, c1 = 0.f, c2 = 0.f;
    float e0 = 0.f, e1 = 0.f, e2 = 0.f;
    int base = rowstart[n];
    int len = rowstart[n + 1] - base;
    int j = 0;
    for (; j + 8 <= len; j += 8) {   // 8 float4 loads in flight
      int s0 = cols[base + j],     s1 = cols[base + j + 1];
      int s2 = cols[base + j + 2], s3 = cols[base + j + 3];
      int s4 = cols[base + j + 4], s5 = cols[base + j + 5];
      int s6 = cols[base + j + 6], s7 = cols[base + j + 7];
      float4 v0 = xs[s0], v1 = xs[s1], v2 = xs[s2], v3 = xs[s3];
      float4 v4 = xs[s4], v5 = xs[s5], v6 = xs[s6], v7 = xs[s7];
      a0 += v0.x + v4.x; a1 += v0.y + v4.y; a2 += v0.z + v4.z;
      b0 += v1.x + v5.x; b1 += v1.y + v5.y; b2 += v1.z + v5.z;
      c0 += v2.x + v6.x; c1 += v2.y + v6.y; c2 += v2.z + v6.z;
      e0 += v3.x + v7.x; e1 += v3.y + v7.y; e2 += v3.z + v7.z;
    }
    for (; j + 4 <= len; j += 4) {
      int s0 = cols[base + j], s1 = cols[base + j + 1];
      int s2 = cols[base + j + 2], s3 = cols[base + j + 3];
      float4 v0 = xs[s0], v1 = xs[s1], v2 = xs[s2], v3 = xs[s3];
      a0 += v0.x; a1 += v0.y; a2 += v0.z;
      b0 += v1.x; b1 += v1.y; b2 += v1.z;
      c0 += v2.x; c1 += v2.y; c2 += v2.z;
      e0 += v3.x; e1 += v3.y; e2 += v3.z;
    }
    for (; j < len; ++j) {
      float4 v = xs[cols[base + j]];
      a0 += v.x; a1 += v.y; a2 += v.z;
    }
    float dv = dinv[n];
    float4 o;
    o.x = dv * ((a0 + b0) + (c0 + e0));
    o.y = dv * ((a1 + b1) + (c1 + e1));
    o.z = dv * ((a2 + b2) + (c2 + e2));
    o.w = 0.f;
    t[n] = o;
    m9[0] = o.x; m9[1] = o.y; m9[2] = o.z;
    m9[3] = o.x * o.x; m9[4] = o.x * o.y; m9[5] = o.x * o.z;
    m9[6] = o.y * o.y; m9[7] = o.y * o.z; m9[8] = o.z * o.z;
  }
  // block-reduce the 9 moments (all threads participate)
  #pragma unroll
  for (int off = 32; off; off >>= 1) {
    #pragma unroll
    for (int i = 0; i < 9; ++i) m9[i] += __shfl_xor(m9[i], off);
  }
  __shared__ float ls[4][9];
  int lane = threadIdx.x & 63, wid = threadIdx.x >> 6;
  if (lane == 0) {
    #pragma unroll
    for (int i = 0; i < 9; ++i) ls[wid][i] = m9[i];
  }
  __syncthreads();
  if (threadIdx.x < 9) {
    float s = ls[0][threadIdx.x] + ls[1][threadIdx.x] + ls[2][threadIdx.x] + ls[3][threadIdx.x];
    atomicAdd(&mom[threadIdx.x], s);
  }
}

// fused layer-2 front end: h1 = t @ W1 (in-register), BN1 (stats from moments),
// relu, @W2 via split-bf16 MFMA, scale by dinv -> hb (bf16 only)
__global__ void __launch_bounds__(256) k_l2m2(const float4* __restrict__ t,
                                              ushort_t* __restrict__ hb,
                                              const float* __restrict__ W1,
                                              const float* __restrict__ W2,
                                              const float* __restrict__ mom,
                                              const float* __restrict__ gamma,
                                              const float* __restrict__ beta,
                                              const float* __restrict__ dinv) {
  __shared__ float w1s[192];
  __shared__ ushort_t w2t_hi[64 * 64];   // [out_feat][k]
  __shared__ ushort_t w2t_lo[64 * 64];
  __shared__ float tt[4][16][4];
  __shared__ ushort_t at_hi[4][16 * 64];
  __shared__ ushort_t at_lo[4][16 * 64];
  int tix = threadIdx.x;
  int lane = tix & 63, wid = tix >> 6;
  if (tix < 192) w1s[tix] = W1[tix];
  for (int i = tix; i < 64 * 64; i += 256) {
    int f = i >> 6, k = i & 63;
    float w = W2[k * 64 + f];
    ushort_t hi = f32_to_bf16(w);
    w2t_hi[i] = hi;
    w2t_lo[i] = f32_to_bf16(w - bf16_to_f32(hi));
  }
  __syncthreads();

  int col = lane & 15, kb = lane >> 4;
  short8 bhi[4][2], blo[4][2];
  #pragma unroll
  for (int nt = 0; nt < 4; ++nt) {
    #pragma unroll
    for (int ks = 0; ks < 2; ++ks) {
      int base = (nt * 16 + col) * 64 + ks * 32 + kb * 8;
      bhi[nt][ks] = *reinterpret_cast<const short8*>(&w2t_hi[base]);
      blo[nt][ks] = *reinterpret_cast<const short8*>(&w2t_lo[base]);
    }
  }

  // BN1 constants from 3x3 moments: lane = feature
  float inv_n = 1.0f / N_NODES;
  float w0 = w1s[lane], w1 = w1s[64 + lane], w2 = w1s[128 + lane];
  float mu = (mom[0] * w0 + mom[1] * w1 + mom[2] * w2) * inv_n;
  float eh2 = (mom[3] * w0 * w0 + 2.f * mom[4] * w0 * w1 + 2.f * mom[5] * w0 * w2 +
               mom[6] * w1 * w1 + 2.f * mom[7] * w1 * w2 + mom[8] * w2 * w2) * inv_n;
  float var = eh2 - mu * mu;
  float sc = rsqrtf(var + EPS) * gamma[lane];
  float sh = beta[lane] - mu * sc;

  for (int bt = blockIdx.x; bt < 3125; bt += gridDim.x) {
    int n0 = (bt * 4 + wid) * 16;
    if (lane < 16) {
      float4 v = t[n0 + lane];
      tt[wid][lane][0] = v.x; tt[wid][lane][1] = v.y; tt[wid][lane][2] = v.z;
    }
    // per-wave LDS tiles: same-wave in-order LDS + compiler lgkmcnt waits suffice
    #pragma unroll 4
    for (int i = 0; i < 16; ++i) {
      float h = tt[wid][i][0] * w0 + tt[wid][i][1] * w1 + tt[wid][i][2] * w2;
      float a = h * sc + sh;
      a = a > 0.f ? a : 0.f;
      ushort_t hi = f32_to_bf16(a);
      at_hi[wid][i * 64 + lane] = hi;
      at_lo[wid][i * 64 + lane] = f32_to_bf16(a - bf16_to_f32(hi));
    }
    short8 ahi[2], alo[2];
    #pragma unroll
    for (int ks = 0; ks < 2; ++ks) {
      int base = col * 64 + ks * 32 + kb * 8;   // A: row=lane&15, k-block
      ahi[ks] = *reinterpret_cast<const short8*>(&at_hi[wid][base]);
      alo[ks] = *reinterpret_cast<const short8*>(&at_lo[wid][base]);
    }
    float dv[4];
    #pragma unroll
    for (int r = 0; r < 4; ++r) dv[r] = dinv[n0 + kb * 4 + r];

    #pragma unroll
    for (int nt = 0; nt < 4; ++nt) {
      f32x4 acc = {0.f, 0.f, 0.f, 0.f};
      #pragma unroll
      for (int ks = 0; ks < 2; ++ks) {
        acc = __builtin_amdgcn_mfma_f32_16x16x32_bf16(ahi[ks], bhi[nt][ks], acc, 0, 0, 0);
        acc = __builtin_amdgcn_mfma_f32_16x16x32_bf16(ahi[ks], blo[nt][ks], acc, 0, 0, 0);
        acc = __builtin_amdgcn_mfma_f32_16x16x32_bf16(alo[ks], bhi[nt][ks], acc, 0, 0, 0);
      }
      #pragma unroll
      for (int r = 0; r < 4; ++r) {
        int node = n0 + kb * 4 + r;      // C/D: row=(lane>>4)*4+r, col=lane&15
        int feat = nt * 16 + col;
        hb[node * 64 + feat] = f32_to_bf16(acc[r] * dv[r]);
      }
    }
  }
}

// layer-2 aggregation + fused BN2 stats; writes packed bf16 h1.
// grid-stride: 2048 blocks x 4 waves; 16-neighbor groups (8 loads in flight/lane).
__global__ void __launch_bounds__(256) k_agg2(const ushort_t* __restrict__ hb,
                       ushort_t* __restrict__ h1b,
                       const int* __restrict__ rowstart, const int* __restrict__ cols,
                       const float* __restrict__ dinv, float* __restrict__ stats) {
  int tid = threadIdx.x;
  int lane = tid & 63, wid = tid >> 6;
  int half = lane >> 5, fl = lane & 31;
  const unsigned* hb32 = (const unsigned*)hb;      // hb32[s*32+fl] = feats {2fl, 2fl+1}
  unsigned* h1b32 = (unsigned*)h1b;
  float s0 = 0.f, s1 = 0.f, q0 = 0.f, q1 = 0.f;
  for (int node = blockIdx.x * 4 + wid; node < N_NODES; node += gridDim.x * 4) {
    float2 acc;
    if (half == 0) {                                // self loop (bf16)
      unsigned u = hb32[node * 32 + fl];
      acc.x = bfu_lo(u); acc.y = bfu_hi(u);
    } else { acc.x = 0.f; acc.y = 0.f; }
    int base = rowstart[node];
    int len = rowstart[node + 1] - base;
    for (int c0 = 0; c0 < len; c0 += 64) {
      int rem = len - c0;
      int m = rem < 64 ? rem : 64;
      int cidx = (lane < m) ? cols[base + c0 + lane] : 0;
      int j = 0;
      for (; j + 16 <= m; j += 16) {   // 16 neighbors, 8 dword loads in flight per lane
        int sA = __shfl(cidx, j + half),      sB = __shfl(cidx, j + 2 + half);
        int sC = __shfl(cidx, j + 4 + half),  sD = __shfl(cidx, j + 6 + half);
        int sE = __shfl(cidx, j + 8 + half),  sF = __shfl(cidx, j + 10 + half);
        int sG = __shfl(cidx, j + 12 + half), sH = __shfl(cidx, j + 14 + half);
        unsigned uA = hb32[sA * 32 + fl], uB = hb32[sB * 32 + fl];
        unsigned uC = hb32[sC * 32 + fl], uD = hb32[sD * 32 + fl];
        unsigned uE = hb32[sE * 32 + fl], uF = hb32[sF * 32 + fl];
        unsigned uG = hb32[sG * 32 + fl], uH = hb32[sH * 32 + fl];
        acc.x += ((bfu_lo(uA) + bfu_lo(uB)) + (bfu_lo(uC) + bfu_lo(uD)))
               + ((bfu_lo(uE) + bfu_lo(uF)) + (bfu_lo(uG) + bfu_lo(uH)));
        acc.y += ((bfu_hi(uA) + bfu_hi(uB)) + (bfu_hi(uC) + bfu_hi(uD)))
               + ((bfu_hi(uE) + bfu_hi(uF)) + (bfu_hi(uG) + bfu_hi(uH)));
      }
      for (; j + 8 <= m; j += 8) {
        int sA = __shfl(cidx, j + half),     sB = __shfl(cidx, j + 2 + half);
        int sC = __shfl(cidx, j + 4 + half), sD = __shfl(cidx, j + 6 + half);
        unsigned uA = hb32[sA * 32 + fl], uB = hb32[sB * 32 + fl];
        unsigned uC = hb32[sC * 32 + fl], uD = hb32[sD * 32 + fl];
        acc.x += (bfu_lo(uA) + bfu_lo(uB)) + (bfu_lo(uC) + bfu_lo(uD));
        acc.y += (bfu_hi(uA) + bfu_hi(uB)) + (bfu_hi(uC) + bfu_hi(uD));
      }
      for (; j + 2 <= m; j += 2) {
        int s = __shfl(cidx, j + half);
        unsigned u = hb32[s * 32 + fl];
        acc.x += bfu_lo(u);
        acc.y += bfu_hi(u);
      }
      if (j < m) {                   // odd leftover: half0 only
        int s = __shfl(cidx, j);
        if (half == 0) {
          unsigned u = hb32[s * 32 + fl];
          acc.x += bfu_lo(u);
          acc.y += bfu_hi(u);
        }
      }
    }
    acc.x += __shfl_xor(acc.x, 32);
    acc.y += __shfl_xor(acc.y, 32);
    if (half == 0) {
      float dv = dinv[node];
      float ox = acc.x * dv, oy = acc.y * dv;
      h1b32[node * 32 + fl] = ((unsigned)f32_to_bf16(oy) << 16) | (unsigned)f32_to_bf16(ox);
      s0 += ox; s1 += oy;
      q0 += ox * ox; q1 += oy * oy;
    }
  }
  __shared__ float lsum[4][64], lsq[4][64];
  if (half == 0) {
    lsum[wid][2 * fl] = s0; lsum[wid][2 * fl + 1] = s1;
    lsq[wid][2 * fl] = q0;  lsq[wid][2 * fl + 1] = q1;
  }
  __syncthreads();
  if (tid < 64) {
    float a = lsum[0][tid] + lsum[1][tid] + lsum[2][tid] + lsum[3][tid];
    float b = lsq[0][tid] + lsq[1][tid] + lsq[2][tid] + lsq[3][tid];
    atomicAdd(&stats[tid], a);
    atomicAdd(&stats[64 + tid], b);
  }
}

// ---------------- pooling + head ----------------

__global__ void k_gstart(const int* __restrict__ batch, int* __restrict__ gstart) {
  int g = blockIdx.x * blockDim.x + threadIdx.x;
  if (g > N_GRAPHS) return;
  int lo = 0, hi = N_NODES;
  while (lo < hi) {
    int mid = (lo + hi) >> 1;
    if (batch[mid] < g) lo = mid + 1; else hi = mid;
  }
  gstart[g] = lo;
}

__global__ void k_pool(const ushort_t* __restrict__ h1b, const float* __restrict__ stats2,
                       const float* __restrict__ gamma, const float* __restrict__ beta,
                       const int* __restrict__ gstart, float* __restrict__ hgraph) {
  __shared__ float ssum[4][64], smax[4][64];
  int g = blockIdx.x;
  int lane = threadIdx.x & 63, wid = threadIdx.x >> 6;
  int s0 = gstart[g], s1 = gstart[g + 1];
  float mu = stats2[lane] * (1.0f / N_NODES);
  float var = stats2[64 + lane] * (1.0f / N_NODES) - mu * mu;
  float sc = rsqrtf(var + EPS) * gamma[lane];
  float sh = beta[lane] - mu * sc;
  float sum = 0.f, mx = 0.f;
  for (int r = s0 + wid; r < s1; r += 4) {
    float v = bf16_to_f32(h1b[r * 64 + lane]) * sc + sh;
    v = v > 0.f ? v : 0.f;
    sum += v;
    mx = v > mx ? v : mx;
  }
  ssum[wid][lane] = sum;
  smax[wid][lane] = mx;
  __syncthreads();
  if (wid == 0) {
    float s = ssum[0][lane] + ssum[1][lane] + ssum[2][lane] + ssum[3][lane];
    float m = fmaxf(fmaxf(smax[0][lane], smax[1][lane]), fmaxf(smax[2][lane], smax[3][lane]));
    int cnt = s1 - s0;
    float inv = 1.0f / (float)(cnt > 0 ? cnt : 1);
    hgraph[g * 128 + lane] = s * inv;
    hgraph[g * 128 + 64 + lane] = m;
  }
}

__global__ void k_head(const float* __restrict__ hgraph,
                       const float* __restrict__ emb, const int* __restrict__ recipe,
                       const float* __restrict__ conv_w, const float* __restrict__ conv_b,
                       const float* __restrict__ fc_w, const float* __restrict__ fc_b,
                       const float* __restrict__ m1_w, const float* __restrict__ m1_b,
                       const float* __restrict__ m2_w, const float* __restrict__ m2_b,
                       const float* __restrict__ m3_w, const float* __restrict__ m3_b,
                       float* __restrict__ out) {
  __shared__ float r_s[RLEN][EMBED];
  __shared__ float convout[16 * RLEN];
  __shared__ float cvec[192];
  __shared__ float y1[128];
  __shared__ float y2[64];
  __shared__ int rec_s[RLEN];
  __shared__ float emb_s[80];
  int g = blockIdx.x;
  int t = threadIdx.x;
  if (t < 80) emb_s[t] = emb[t];
  if (t < RLEN) rec_s[t] = recipe[g * RLEN + t];
  __syncthreads();
  for (int idx = t; idx < RLEN * EMBED; idx += blockDim.x) {
    int pos = idx >> 3, e = idx & 7;
    r_s[pos][e] = emb_s[rec_s[pos] * EMBED + e];
  }
  if (t < 128) cvec[t] = hgraph[g * 128 + t];
  __syncthreads();
  for (int idx = t; idx < 16 * RLEN; idx += blockDim.x) {
    int c = idx / RLEN, pos = idx % RLEN;
    float acc = conv_b[c];
    #pragma unroll
    for (int k = 0; k < 3; ++k) {
      int p = pos + k - 1;
      if (p >= 0 && p < RLEN) {
        #pragma unroll
        for (int e = 0; e < EMBED; ++e)
          acc = fmaf(r_s[p][e], conv_w[(c * EMBED + e) * 3 + k], acc);
      }
    }
    convout[c * RLEN + pos] = acc > 0.f ? acc : 0.f;
  }
  __syncthreads();
  if (t < 64) {
    float acc = fc_b[t];
    for (int i = 0; i < 320; ++i) acc = fmaf(convout[i], fc_w[i * 64 + t], acc);
    cvec[128 + t] = acc > 0.f ? acc : 0.f;
  }
  __syncthreads();
  if (t < 128) {
    float acc = m1_b[t];
    for (int i = 0; i < 192; ++i) acc = fmaf(cvec[i], m1_w[i * 128 + t], acc);
    y1[t] = acc > 0.f ? acc : 0.f;
  }
  __syncthreads();
  if (t < 64) {
    float acc = m2_b[t];
    for (int i = 0; i < 128; ++i) acc = fmaf(y1[i], m2_w[i * 64 + t], acc);
    y2[t] = acc > 0.f ? acc : 0.f;
  }
  __syncthreads();
  if (t < 3) {
    float acc = m3_b[t];
    for (int i = 0; i < 64; ++i) acc = fmaf(y2[i], m3_w[i * 3 + t], acc);
    out[g * 3 + t] = acc;
  }
}

extern "C" void kernel_launch(void* const* d_in, const int* in_sizes, int n_in,
                              void* d_out, int out_size, void* d_ws, size_t ws_size,
                              hipStream_t stream) {
  const float* x      = (const float*)d_in[0];
  const float* W1     = (const float*)d_in[1];
  // b1 (d_in[2]) cancels under BN
  const float* gamma1 = (const float*)d_in[3];
  const float* beta1  = (const float*)d_in[4];
  const float* W2     = (const float*)d_in[5];
  // b2 (d_in[6]) cancels under BN
  const float* gamma2 = (const float*)d_in[7];
  const float* beta2  = (const float*)d_in[8];
  const float* emb    = (const float*)d_in[9];
  const float* conv_w = (const float*)d_in[10];
  const float* conv_b = (const float*)d_in[11];
  const float* fc_w   = (const float*)d_in[12];
  const float* fc_b   = (const float*)d_in[13];
  const float* m1_w   = (const float*)d_in[14];
  const float* m1_b   = (const float*)d_in[15];
  const float* m2_w   = (const float*)d_in[16];
  const float* m2_b   = (const float*)d_in[17];
  const float* m3_w   = (const float*)d_in[18];
  const float* m3_b   = (const float*)d_in[19];
  const int* ei       = (const int*)d_in[20];
  const int* batch    = (const int*)d_in[21];
  const int* recipe   = (const int*)d_in[22];
  const int* e_src = ei;
  const int* e_dst = ei + N_EDGES;
  float* out = (float*)d_out;

  char* p = (char*)d_ws;
  auto alloc = [&](size_t bytes) {
    char* r = p;
    p += (bytes + 255) & ~(size_t)255;
    return (void*)r;
  };
  int*   bcnt     = (int*)alloc((size_t)NBKT * 4);
  int*   bstart   = (int*)alloc((size_t)(NBKT + 1) * 4);
  int*   bcursor  = (int*)alloc((size_t)NBKT * 4);
  float* dinv     = (float*)alloc((size_t)N_NODES * 4);
  int*   rowstart = (int*)alloc((size_t)(N_NODES + 1) * 4);
  int*   gstart   = (int*)alloc((size_t)(N_GRAPHS + 1) * 4);
  float* stats    = (float*)alloc(256 * 4);
  float* mom      = (float*)alloc(16 * 4);
  float* hgraph   = (float*)alloc((size_t)N_GRAPHS * 128 * 4);
  int*   cols     = (int*)alloc((size_t)N_EDGES * 4);
  float4* xs      = (float4*)alloc((size_t)N_NODES * 16);
  float4* tbuf    = (float4*)alloc((size_t)N_NODES * 16);
  ushort_t* h1b   = (ushort_t*)alloc((size_t)N_NODES * 64 * 2);
  ushort_t* hb    = (ushort_t*)alloc((size_t)N_NODES * 64 * 2);
  int*   ebuf     = (int*)h1b;  // alias: ebuf dead before k_agg2 writes h1b

  hipMemsetAsync(bcnt, 0, (size_t)NBKT * 4, stream);
  hipMemsetAsync(stats, 0, 256 * 4, stream);
  hipMemsetAsync(mom, 0, 16 * 4, stream);

  k_bcount<<<512, 256, 0, stream>>>(e_dst, bcnt);
  k_bscan<<<1, 256, 0, stream>>>(bcnt, bstart, bcursor, rowstart);
  k_bscatter<<<(N_EDGES + CHUNK - 1) / CHUNK, 256, 0, stream>>>(e_src, e_dst, bcursor, ebuf);
  k_bfill<<<NBKT, 256, 0, stream>>>(bstart, ebuf, x, rowstart, dinv, xs, cols);
  k_agg1<<<(N_NODES + 255) / 256, 256, 0, stream>>>(xs, tbuf, rowstart, cols, dinv, mom);
  k_l2m2<<<625, 256, 0, stream>>>(tbuf, hb, W1, W2, mom, gamma1, beta1, dinv);
  k_agg2<<<2048, 256, 0, stream>>>(hb, h1b, rowstart, cols, dinv, stats);
  k_gstart<<<1, 576, 0, stream>>>(batch, gstart);
  k_pool<<<N_GRAPHS, 256, 0, stream>>>(h1b, stats, gamma2, beta2, gstart, hgraph);
  k_head<<<N_GRAPHS, 128, 0, stream>>>(hgraph, emb, recipe, conv_w, conv_b, fc_w, fc_b,
                                       m1_w, m1_b, m2_w, m2_b, m3_w, m3_b, out);
}

// Round 8
// 439.099 us; speedup vs baseline: 3.6114x; 1.0572x over previous
//
#include <hip/hip_runtime.h>

#define N_NODES 200000
#define N_EDGES 6400000
#define N_GRAPHS 512
#define RLEN 20
#define EMBED 8
#define EPS 1e-5f

#define NPB 1024                           // nodes per bucket
#define NBKT ((N_NODES + NPB - 1) / NPB)   // 196
#define CHUNK 4096                         // edges per k_bscatter block
#define CAP 36864                          // padded bucket capacity (mean 32653 + 23 sigma)

typedef unsigned short ushort_t;
typedef __attribute__((ext_vector_type(8))) short short8;
typedef __attribute__((ext_vector_type(4))) float f32x4;

__device__ inline ushort_t f32_to_bf16(float f) {
  unsigned u = __float_as_uint(f);
  unsigned r = (u + 0x7fff + ((u >> 16) & 1)) >> 16;  // RNE
  return (ushort_t)r;
}
__device__ inline float bf16_to_f32(ushort_t us) {
  return __uint_as_float(((unsigned)us) << 16);
}
__device__ inline float bfu_lo(unsigned u) { return __uint_as_float(u << 16); }
__device__ inline float bfu_hi(unsigned u) { return __uint_as_float(u & 0xFFFF0000u); }

// ---------------- bucketed CSR build (padded buckets, no count/scan pass) ----------------

__global__ void k_binit(int* __restrict__ bcursor) {
  int b = threadIdx.x;
  if (b < NBKT) bcursor[b] = b * CAP;
}

__global__ void __launch_bounds__(256) k_bscatter(const int* __restrict__ src,
                                                  const int* __restrict__ dst,
                                                  int* __restrict__ bcursor,
                                                  int* __restrict__ ebuf) {
  __shared__ int hist[256];
  __shared__ int scanb[256];
  __shared__ int gbase[NBKT];
  __shared__ int staged[CHUNK];
  __shared__ int addrs[CHUNK];
  __shared__ int s_total;
  int t = threadIdx.x;
  int e0 = blockIdx.x * CHUNK;
  hist[t] = 0;
  __syncthreads();

  int pk[16], bk[16], rk[16];
  #pragma unroll
  for (int k = 0; k < 16; ++k) {
    int idx = e0 + t + k * 256;
    bk[k] = -1;
    if (idx < N_EDGES) {
      int s = src[idx], d = dst[idx];
      int b = d >> 10;
      pk[k] = s | ((d & (NPB - 1)) << 18);
      bk[k] = b;
      rk[k] = atomicAdd(&hist[b], 1);
    }
  }
  __syncthreads();
  int hv = hist[t];
  scanb[t] = hv;
  __syncthreads();
  for (int off = 1; off < 256; off <<= 1) {
    int u = (t >= off) ? scanb[t - off] : 0;
    __syncthreads();
    scanb[t] += u;
    __syncthreads();
  }
  int offt = scanb[t] - hv;
  if (t < NBKT && hv > 0) gbase[t] = atomicAdd(&bcursor[t], hv);
  if (t == 255) s_total = scanb[255];
  __syncthreads();
  hist[t] = offt;
  __syncthreads();
  #pragma unroll
  for (int k = 0; k < 16; ++k) {
    if (bk[k] >= 0) {
      int slot = hist[bk[k]] + rk[k];
      staged[slot] = pk[k];
      addrs[slot] = gbase[bk[k]] + rk[k];
    }
  }
  __syncthreads();
  int total = s_total;
  for (int i = t; i < total; i += 256)
    ebuf[addrs[i]] = staged[i];
}

// per bucket: degrees -> rowstart/rowlen/dinv/xs, then local scatter of cols
__global__ void __launch_bounds__(256) k_bfill(const int* __restrict__ bcursor,
                                               const int* __restrict__ ebuf,
                                               const float* __restrict__ x,
                                               int* __restrict__ rowstart,
                                               int* __restrict__ rowlen,
                                               float* __restrict__ dinv,
                                               float4* __restrict__ xs,
                                               int* __restrict__ cols) {
  __shared__ int deg[NPB];
  __shared__ int cur[NPB];
  __shared__ int wsum[4];
  int b = blockIdx.x;
  int t = threadIdx.x;
  int lane = t & 63, wid = t >> 6;
  int estart = b * CAP;
  int eend = bcursor[b];           // estart + count
  for (int i = t; i < NPB; i += 256) deg[i] = 0;
  __syncthreads();
  for (int i = estart + t; i < eend; i += 256) {
    int p = ebuf[i];
    atomicAdd(&deg[((unsigned)p) >> 18], 1);
  }
  __syncthreads();
  int d0 = deg[t * 4], d1 = deg[t * 4 + 1], d2 = deg[t * 4 + 2], d3 = deg[t * 4 + 3];
  int tsum = d0 + d1 + d2 + d3;
  int incl = tsum;
  #pragma unroll
  for (int off = 1; off < 64; off <<= 1) {
    int u = __shfl_up(incl, off);
    if (lane >= off) incl += u;
  }
  if (lane == 63) wsum[wid] = incl;
  int wexcl = incl - tsum;
  __syncthreads();
  int wbase = 0;
  for (int w = 0; w < wid; ++w) wbase += wsum[w];
  int ebase = wbase + wexcl;
  cur[t * 4 + 0] = ebase;
  cur[t * 4 + 1] = ebase + d0;
  cur[t * 4 + 2] = ebase + d0 + d1;
  cur[t * 4 + 3] = ebase + d0 + d1 + d2;
  __syncthreads();
  #pragma unroll
  for (int k = 0; k < 4; ++k) {
    int dl = t * 4 + k;
    int n = b * NPB + dl;
    if (n < N_NODES) {
      rowstart[n] = estart + cur[dl];
      rowlen[n] = deg[dl];
      float dv = rsqrtf((float)(deg[dl] + 1));
      dinv[n] = dv;
      float4 v;
      v.x = x[n * 3 + 0] * dv;
      v.y = x[n * 3 + 1] * dv;
      v.z = x[n * 3 + 2] * dv;
      v.w = 0.f;
      xs[n] = v;
    }
  }
  __syncthreads();
  for (int i = estart + t; i < eend; i += 256) {
    int p = ebuf[i];
    int dl = ((unsigned)p) >> 18;
    int lpos = atomicAdd(&cur[dl], 1);
    cols[estart + lpos] = p & 0x3FFFF;
  }
}

// ---------------- layer-1: aggregate 3-feature x + fused 3x3 moments ----------------

__global__ void k_agg1(const float4* __restrict__ xs, float4* __restrict__ t,
                       const int* __restrict__ rowstart, const int* __restrict__ rowlen,
                       const int* __restrict__ cols,
                       const float* __restrict__ dinv, float* __restrict__ mom) {
  int n = blockIdx.x * blockDim.x + threadIdx.x;
  float m9[9] = {0.f, 0.f, 0.f, 0.f, 0.f, 0.f, 0.f, 0.f, 0.f};
  if (n < N_NODES) {
    float4 self = xs[n];
    float a0 = self.x, a1 = self.y, a2 = self.z;
    float b0 = 0.f, b1 = 0.f, b2 = 0.f;
    float c0 = 0.f, c1 = 0.f, c2 = 0.f;
    float e0 = 0.f, e1 = 0.f, e2 = 0.f;
    int base = rowstart[n];
    int len = rowlen[n];
    int j = 0;
    for (; j + 8 <= len; j += 8) {   // 8 float4 loads in flight
      int s0 = cols[base + j],     s1 = cols[base + j + 1];
      int s2 = cols[base + j + 2], s3 = cols[base + j + 3];
      int s4 = cols[base + j + 4], s5 = cols[base + j + 5];
      int s6 = cols[base + j + 6], s7 = cols[base + j + 7];
      float4 v0 = xs[s0], v1 = xs[s1], v2 = xs[s2], v3 = xs[s3];
      float4 v4 = xs[s4], v5 = xs[s5], v6 = xs[s6], v7 = xs[s7];
      a0 += v0.x + v4.x; a1 += v0.y + v4.y; a2 += v0.z + v4.z;
      b0 += v1.x + v5.x; b1 += v1.y + v5.y; b2 += v1.z + v5.z;
      c0 += v2.x + v6.x; c1 += v2.y + v6.y; c2 += v2.z + v6.z;
      e0 += v3.x + v7.x; e1 += v3.y + v7.y; e2 += v3.z + v7.z;
    }
    for (; j + 4 <= len; j += 4) {
      int s0 = cols[base + j], s1 = cols[base + j + 1];
      int s2 = cols[base + j + 2], s3 = cols[base + j + 3];
      float4 v0 = xs[s0], v1 = xs[s1], v2 = xs[s2], v3 = xs[s3];
      a0 += v0.x; a1 += v0.y; a2 += v0.z;
      b0 += v1.x; b1 += v1.y; b2 += v1.z;
      c0 += v2.x; c1 += v2.y; c2 += v2.z;
      e0 += v3.x; e1 += v3.y; e2 += v3.z;
    }
    for (; j < len; ++j) {
      float4 v = xs[cols[base + j]];
      a0 += v.x; a1 += v.y; a2 += v.z;
    }
    float dv = dinv[n];
    float4 o;
    o.x = dv * ((a0 + b0) + (c0 + e0));
    o.y = dv * ((a1 + b1) + (c1 + e1));
    o.z = dv * ((a2 + b2) + (c2 + e2));
    o.w = 0.f;
    t[n] = o;
    m9[0] = o.x; m9[1] = o.y; m9[2] = o.z;
    m9[3] = o.x * o.x; m9[4] = o.x * o.y; m9[5] = o.x * o.z;
    m9[6] = o.y * o.y; m9[7] = o.y * o.z; m9[8] = o.z * o.z;
  }
  #pragma unroll
  for (int off = 32; off; off >>= 1) {
    #pragma unroll
    for (int i = 0; i < 9; ++i) m9[i] += __shfl_xor(m9[i], off);
  }
  __shared__ float ls[4][9];
  int lane = threadIdx.x & 63, wid = threadIdx.x >> 6;
  if (lane == 0) {
    #pragma unroll
    for (int i = 0; i < 9; ++i) ls[wid][i] = m9[i];
  }
  __syncthreads();
  if (threadIdx.x < 9) {
    float s = ls[0][threadIdx.x] + ls[1][threadIdx.x] + ls[2][threadIdx.x] + ls[3][threadIdx.x];
    atomicAdd(&mom[threadIdx.x], s);
  }
}

// fused layer-2 front end: h1 = t @ W1 (in-register), BN1 (stats from moments),
// relu, @W2 via split-bf16 MFMA, scale by dinv -> hb (bf16 only)
__global__ void __launch_bounds__(256) k_l2m2(const float4* __restrict__ t,
                                              ushort_t* __restrict__ hb,
                                              const float* __restrict__ W1,
                                              const float* __restrict__ W2,
                                              const float* __restrict__ mom,
                                              const float* __restrict__ gamma,
                                              const float* __restrict__ beta,
                                              const float* __restrict__ dinv) {
  __shared__ float w1s[192];
  __shared__ ushort_t w2t_hi[64 * 64];   // [out_feat][k]
  __shared__ ushort_t w2t_lo[64 * 64];
  __shared__ float tt[4][16][4];
  __shared__ ushort_t at_hi[4][16 * 64];
  __shared__ ushort_t at_lo[4][16 * 64];
  int tix = threadIdx.x;
  int lane = tix & 63, wid = tix >> 6;
  if (tix < 192) w1s[tix] = W1[tix];
  for (int i = tix; i < 64 * 64; i += 256) {
    int f = i >> 6, k = i & 63;
    float w = W2[k * 64 + f];
    ushort_t hi = f32_to_bf16(w);
    w2t_hi[i] = hi;
    w2t_lo[i] = f32_to_bf16(w - bf16_to_f32(hi));
  }
  __syncthreads();

  int col = lane & 15, kb = lane >> 4;
  short8 bhi[4][2], blo[4][2];
  #pragma unroll
  for (int nt = 0; nt < 4; ++nt) {
    #pragma unroll
    for (int ks = 0; ks < 2; ++ks) {
      int base = (nt * 16 + col) * 64 + ks * 32 + kb * 8;
      bhi[nt][ks] = *reinterpret_cast<const short8*>(&w2t_hi[base]);
      blo[nt][ks] = *reinterpret_cast<const short8*>(&w2t_lo[base]);
    }
  }

  float inv_n = 1.0f / N_NODES;
  float w0 = w1s[lane], w1 = w1s[64 + lane], w2 = w1s[128 + lane];
  float mu = (mom[0] * w0 + mom[1] * w1 + mom[2] * w2) * inv_n;
  float eh2 = (mom[3] * w0 * w0 + 2.f * mom[4] * w0 * w1 + 2.f * mom[5] * w0 * w2 +
               mom[6] * w1 * w1 + 2.f * mom[7] * w1 * w2 + mom[8] * w2 * w2) * inv_n;
  float var = eh2 - mu * mu;
  float sc = rsqrtf(var + EPS) * gamma[lane];
  float sh = beta[lane] - mu * sc;

  for (int bt = blockIdx.x; bt < 3125; bt += gridDim.x) {
    int n0 = (bt * 4 + wid) * 16;
    if (lane < 16) {
      float4 v = t[n0 + lane];
      tt[wid][lane][0] = v.x; tt[wid][lane][1] = v.y; tt[wid][lane][2] = v.z;
    }
    #pragma unroll 4
    for (int i = 0; i < 16; ++i) {
      float h = tt[wid][i][0] * w0 + tt[wid][i][1] * w1 + tt[wid][i][2] * w2;
      float a = h * sc + sh;
      a = a > 0.f ? a : 0.f;
      ushort_t hi = f32_to_bf16(a);
      at_hi[wid][i * 64 + lane] = hi;
      at_lo[wid][i * 64 + lane] = f32_to_bf16(a - bf16_to_f32(hi));
    }
    short8 ahi[2], alo[2];
    #pragma unroll
    for (int ks = 0; ks < 2; ++ks) {
      int base = col * 64 + ks * 32 + kb * 8;   // A: row=lane&15, k-block
      ahi[ks] = *reinterpret_cast<const short8*>(&at_hi[wid][base]);
      alo[ks] = *reinterpret_cast<const short8*>(&at_lo[wid][base]);
    }
    float dv[4];
    #pragma unroll
    for (int r = 0; r < 4; ++r) dv[r] = dinv[n0 + kb * 4 + r];

    #pragma unroll
    for (int nt = 0; nt < 4; ++nt) {
      f32x4 acc = {0.f, 0.f, 0.f, 0.f};
      #pragma unroll
      for (int ks = 0; ks < 2; ++ks) {
        acc = __builtin_amdgcn_mfma_f32_16x16x32_bf16(ahi[ks], bhi[nt][ks], acc, 0, 0, 0);
        acc = __builtin_amdgcn_mfma_f32_16x16x32_bf16(ahi[ks], blo[nt][ks], acc, 0, 0, 0);
        acc = __builtin_amdgcn_mfma_f32_16x16x32_bf16(alo[ks], bhi[nt][ks], acc, 0, 0, 0);
      }
      #pragma unroll
      for (int r = 0; r < 4; ++r) {
        int node = n0 + kb * 4 + r;      // C/D: row=(lane>>4)*4+r, col=lane&15
        int feat = nt * 16 + col;
        hb[node * 64 + feat] = f32_to_bf16(acc[r] * dv[r]);
      }
    }
  }
}

// layer-2 aggregation (round-6 proven shape): one node per wave, 8-neighbor groups.
// Writes packed bf16 h1.
__global__ void k_agg2(const ushort_t* __restrict__ hb, ushort_t* __restrict__ h1b,
                       const int* __restrict__ rowstart, const int* __restrict__ rowlen,
                       const int* __restrict__ cols, const float* __restrict__ dinv) {
  int node = blockIdx.x * 4 + (threadIdx.x >> 6);
  int lane = threadIdx.x & 63;
  if (node >= N_NODES) return;
  int half = lane >> 5;
  int fl = lane & 31;
  const unsigned* hb32 = (const unsigned*)hb;      // hb32[s*32+fl] = feats {2fl, 2fl+1}
  unsigned* o32 = (unsigned*)h1b;
  float2 acc;
  if (half == 0) {                                  // self loop (bf16)
    unsigned u = hb32[node * 32 + fl];
    acc.x = bfu_lo(u); acc.y = bfu_hi(u);
  } else { acc.x = 0.f; acc.y = 0.f; }
  int base = rowstart[node];
  int len = rowlen[node];
  for (int c0 = 0; c0 < len; c0 += 64) {
    int rem = len - c0;
    int m = rem < 64 ? rem : 64;
    int cidx = (lane < m) ? cols[base + c0 + lane] : 0;
    int j = 0;
    for (; j + 8 <= m; j += 8) {   // 8 neighbors / iter, 4 dword loads in flight per lane
      int sA = __shfl(cidx, j + half);
      int sB = __shfl(cidx, j + 2 + half);
      int sC = __shfl(cidx, j + 4 + half);
      int sD = __shfl(cidx, j + 6 + half);
      unsigned uA = hb32[sA * 32 + fl], uB = hb32[sB * 32 + fl];
      unsigned uC = hb32[sC * 32 + fl], uD = hb32[sD * 32 + fl];
      acc.x += (bfu_lo(uA) + bfu_lo(uB)) + (bfu_lo(uC) + bfu_lo(uD));
      acc.y += (bfu_hi(uA) + bfu_hi(uB)) + (bfu_hi(uC) + bfu_hi(uD));
    }
    for (; j + 2 <= m; j += 2) {
      int s = __shfl(cidx, j + half);
      unsigned u = hb32[s * 32 + fl];
      acc.x += bfu_lo(u);
      acc.y += bfu_hi(u);
    }
    if (j < m) {                   // odd leftover: half0 only
      int s = __shfl(cidx, j);
      if (half == 0) {
        unsigned u = hb32[s * 32 + fl];
        acc.x += bfu_lo(u);
        acc.y += bfu_hi(u);
      }
    }
  }
  acc.x += __shfl_xor(acc.x, 32);
  acc.y += __shfl_xor(acc.y, 32);
  if (half == 0) {
    float dv = dinv[node];
    float ox = acc.x * dv, oy = acc.y * dv;
    o32[node * 32 + fl] = ((unsigned)f32_to_bf16(oy) << 16) | (unsigned)f32_to_bf16(ox);
  }
}

// BN2 stats from packed bf16 h1 -> stats[0:64], stats[64:128]
__global__ void k_bnstats_b(const ushort_t* __restrict__ h1b, float* __restrict__ stats) {
  const unsigned* h32 = (const unsigned*)h1b;
  int tid = threadIdx.x;
  int lane = tid & 63, wid = tid >> 6;
  int fl = lane & 31, rsel = lane >> 5;
  float s0 = 0.f, s1 = 0.f, q0 = 0.f, q1 = 0.f;
  for (int r = blockIdx.x * 8 + wid * 2 + rsel; r < N_NODES; r += gridDim.x * 8) {
    unsigned u = h32[r * 32 + fl];
    float a = bfu_lo(u), b = bfu_hi(u);
    s0 += a; s1 += b; q0 += a * a; q1 += b * b;
  }
  s0 += __shfl_xor(s0, 32); s1 += __shfl_xor(s1, 32);
  q0 += __shfl_xor(q0, 32); q1 += __shfl_xor(q1, 32);
  __shared__ float ls[4][64], lq[4][64];
  if (rsel == 0) {
    ls[wid][2 * fl] = s0; ls[wid][2 * fl + 1] = s1;
    lq[wid][2 * fl] = q0; lq[wid][2 * fl + 1] = q1;
  }
  __syncthreads();
  if (tid < 64) {
    float a = ls[0][tid] + ls[1][tid] + ls[2][tid] + ls[3][tid];
    float b = lq[0][tid] + lq[1][tid] + lq[2][tid] + lq[3][tid];
    atomicAdd(&stats[tid], a);
    atomicAdd(&stats[64 + tid], b);
  }
}

// ---------------- pooling + head ----------------

__global__ void k_gstart(const int* __restrict__ batch, int* __restrict__ gstart) {
  int g = blockIdx.x * blockDim.x + threadIdx.x;
  if (g > N_GRAPHS) return;
  int lo = 0, hi = N_NODES;
  while (lo < hi) {
    int mid = (lo + hi) >> 1;
    if (batch[mid] < g) lo = mid + 1; else hi = mid;
  }
  gstart[g] = lo;
}

__global__ void k_pool(const ushort_t* __restrict__ h1b, const float* __restrict__ stats2,
                       const float* __restrict__ gamma, const float* __restrict__ beta,
                       const int* __restrict__ gstart, float* __restrict__ hgraph) {
  __shared__ float ssum[4][64], smax[4][64];
  int g = blockIdx.x;
  int lane = threadIdx.x & 63, wid = threadIdx.x >> 6;
  int s0 = gstart[g], s1 = gstart[g + 1];
  float mu = stats2[lane] * (1.0f / N_NODES);
  float var = stats2[64 + lane] * (1.0f / N_NODES) - mu * mu;
  float sc = rsqrtf(var + EPS) * gamma[lane];
  float sh = beta[lane] - mu * sc;
  float sum = 0.f, mx = 0.f;
  for (int r = s0 + wid; r < s1; r += 4) {
    float v = bf16_to_f32(h1b[r * 64 + lane]) * sc + sh;
    v = v > 0.f ? v : 0.f;
    sum += v;
    mx = v > mx ? v : mx;
  }
  ssum[wid][lane] = sum;
  smax[wid][lane] = mx;
  __syncthreads();
  if (wid == 0) {
    float s = ssum[0][lane] + ssum[1][lane] + ssum[2][lane] + ssum[3][lane];
    float m = fmaxf(fmaxf(smax[0][lane], smax[1][lane]), fmaxf(smax[2][lane], smax[3][lane]));
    int cnt = s1 - s0;
    float inv = 1.0f / (float)(cnt > 0 ? cnt : 1);
    hgraph[g * 128 + lane] = s * inv;
    hgraph[g * 128 + 64 + lane] = m;
  }
}

__global__ void k_head(const float* __restrict__ hgraph,
                       const float* __restrict__ emb, const int* __restrict__ recipe,
                       const float* __restrict__ conv_w, const float* __restrict__ conv_b,
                       const float* __restrict__ fc_w, const float* __restrict__ fc_b,
                       const float* __restrict__ m1_w, const float* __restrict__ m1_b,
                       const float* __restrict__ m2_w, const float* __restrict__ m2_b,
                       const float* __restrict__ m3_w, const float* __restrict__ m3_b,
                       float* __restrict__ out) {
  __shared__ float r_s[RLEN][EMBED];
  __shared__ float convout[16 * RLEN];
  __shared__ float cvec[192];
  __shared__ float y1[128];
  __shared__ float y2[64];
  __shared__ int rec_s[RLEN];
  __shared__ float emb_s[80];
  int g = blockIdx.x;
  int t = threadIdx.x;
  if (t < 80) emb_s[t] = emb[t];
  if (t < RLEN) rec_s[t] = recipe[g * RLEN + t];
  __syncthreads();
  for (int idx = t; idx < RLEN * EMBED; idx += blockDim.x) {
    int pos = idx >> 3, e = idx & 7;
    r_s[pos][e] = emb_s[rec_s[pos] * EMBED + e];
  }
  if (t < 128) cvec[t] = hgraph[g * 128 + t];
  __syncthreads();
  for (int idx = t; idx < 16 * RLEN; idx += blockDim.x) {
    int c = idx / RLEN, pos = idx % RLEN;
    float acc = conv_b[c];
    #pragma unroll
    for (int k = 0; k < 3; ++k) {
      int p = pos + k - 1;
      if (p >= 0 && p < RLEN) {
        #pragma unroll
        for (int e = 0; e < EMBED; ++e)
          acc = fmaf(r_s[p][e], conv_w[(c * EMBED + e) * 3 + k], acc);
      }
    }
    convout[c * RLEN + pos] = acc > 0.f ? acc : 0.f;
  }
  __syncthreads();
  if (t < 64) {
    float acc = fc_b[t];
    for (int i = 0; i < 320; ++i) acc = fmaf(convout[i], fc_w[i * 64 + t], acc);
    cvec[128 + t] = acc > 0.f ? acc : 0.f;
  }
  __syncthreads();
  if (t < 128) {
    float acc = m1_b[t];
    for (int i = 0; i < 192; ++i) acc = fmaf(cvec[i], m1_w[i * 128 + t], acc);
    y1[t] = acc > 0.f ? acc : 0.f;
  }
  __syncthreads();
  if (t < 64) {
    float acc = m2_b[t];
    for (int i = 0; i < 128; ++i) acc = fmaf(y1[i], m2_w[i * 64 + t], acc);
    y2[t] = acc > 0.f ? acc : 0.f;
  }
  __syncthreads();
  if (t < 3) {
    float acc = m3_b[t];
    for (int i = 0; i < 64; ++i) acc = fmaf(y2[i], m3_w[i * 3 + t], acc);
    out[g * 3 + t] = acc;
  }
}

extern "C" void kernel_launch(void* const* d_in, const int* in_sizes, int n_in,
                              void* d_out, int out_size, void* d_ws, size_t ws_size,
                              hipStream_t stream) {
  const float* x      = (const float*)d_in[0];
  const float* W1     = (const float*)d_in[1];
  // b1 (d_in[2]) cancels under BN
  const float* gamma1 = (const float*)d_in[3];
  const float* beta1  = (const float*)d_in[4];
  const float* W2     = (const float*)d_in[5];
  // b2 (d_in[6]) cancels under BN
  const float* gamma2 = (const float*)d_in[7];
  const float* beta2  = (const float*)d_in[8];
  const float* emb    = (const float*)d_in[9];
  const float* conv_w = (const float*)d_in[10];
  const float* conv_b = (const float*)d_in[11];
  const float* fc_w   = (const float*)d_in[12];
  const float* fc_b   = (const float*)d_in[13];
  const float* m1_w   = (const float*)d_in[14];
  const float* m1_b   = (const float*)d_in[15];
  const float* m2_w   = (const float*)d_in[16];
  const float* m2_b   = (const float*)d_in[17];
  const float* m3_w   = (const float*)d_in[18];
  const float* m3_b   = (const float*)d_in[19];
  const int* ei       = (const int*)d_in[20];
  const int* batch    = (const int*)d_in[21];
  const int* recipe   = (const int*)d_in[22];
  const int* e_src = ei;
  const int* e_dst = ei + N_EDGES;
  float* out = (float*)d_out;

  char* p = (char*)d_ws;
  auto alloc = [&](size_t bytes) {
    char* r = p;
    p += (bytes + 255) & ~(size_t)255;
    return (void*)r;
  };
  int*   bcursor  = (int*)alloc((size_t)NBKT * 4);
  float* dinv     = (float*)alloc((size_t)N_NODES * 4);
  int*   rowstart = (int*)alloc((size_t)N_NODES * 4);
  int*   rowlen   = (int*)alloc((size_t)N_NODES * 4);
  int*   gstart   = (int*)alloc((size_t)(N_GRAPHS + 1) * 4);
  float* stats    = (float*)alloc(256 * 4);
  float* mom      = (float*)alloc(16 * 4);
  float* hgraph   = (float*)alloc((size_t)N_GRAPHS * 128 * 4);
  int*   cols     = (int*)alloc((size_t)NBKT * CAP * 4);
  float4* xs      = (float4*)alloc((size_t)N_NODES * 16);
  float4* tbuf    = (float4*)alloc((size_t)N_NODES * 16);
  int*   ebuf     = (int*)alloc((size_t)NBKT * CAP * 4);
  ushort_t* hb    = (ushort_t*)alloc((size_t)N_NODES * 64 * 2);
  ushort_t* h1b   = (ushort_t*)ebuf;  // alias: ebuf dead before k_agg2 writes h1b

  hipMemsetAsync(stats, 0, 256 * 4, stream);
  hipMemsetAsync(mom, 0, 16 * 4, stream);

  k_binit<<<1, 256, 0, stream>>>(bcursor);
  k_bscatter<<<(N_EDGES + CHUNK - 1) / CHUNK, 256, 0, stream>>>(e_src, e_dst, bcursor, ebuf);
  k_bfill<<<NBKT, 256, 0, stream>>>(bcursor, ebuf, x, rowstart, rowlen, dinv, xs, cols);
  k_agg1<<<(N_NODES + 255) / 256, 256, 0, stream>>>(xs, tbuf, rowstart, rowlen, cols, dinv, mom);
  k_l2m2<<<625, 256, 0, stream>>>(tbuf, hb, W1, W2, mom, gamma1, beta1, dinv);
  k_agg2<<<(N_NODES + 3) / 4, 256, 0, stream>>>(hb, h1b, rowstart, rowlen, cols, dinv);
  k_bnstats_b<<<512, 256, 0, stream>>>(h1b, stats);
  k_gstart<<<1, 576, 0, stream>>>(batch, gstart);
  k_pool<<<N_GRAPHS, 256, 0, stream>>>(h1b, stats, gamma2, beta2, gstart, hgraph);
  k_head<<<N_GRAPHS, 128, 0, stream>>>(hgraph, emb, recipe, conv_w, conv_b, fc_w, fc_b,
                                       m1_w, m1_b, m2_w, m2_b, m3_w, m3_b, out);
}

// Round 9
// 428.149 us; speedup vs baseline: 3.7037x; 1.0256x over previous
//
#include <hip/hip_runtime.h>

#define N_NODES 200000
#define N_EDGES 6400000
#define N_GRAPHS 512
#define RLEN 20
#define EMBED 8
#define EPS 1e-5f

#define NPB 1024                           // nodes per bucket
#define NBKT ((N_NODES + NPB - 1) / NPB)   // 196
#define CHUNK 4096                         // edges per k_bscatter block
#define CAP 36864                          // padded bucket capacity (mean 32653 + 23 sigma)

typedef unsigned short ushort_t;
typedef __attribute__((ext_vector_type(8))) short short8;
typedef __attribute__((ext_vector_type(4))) float f32x4;

__device__ inline ushort_t f32_to_bf16(float f) {
  unsigned u = __float_as_uint(f);
  unsigned r = (u + 0x7fff + ((u >> 16) & 1)) >> 16;  // RNE
  return (ushort_t)r;
}
__device__ inline float bf16_to_f32(ushort_t us) {
  return __uint_as_float(((unsigned)us) << 16);
}
__device__ inline float bfu_lo(unsigned u) { return __uint_as_float(u << 16); }
__device__ inline float bfu_hi(unsigned u) { return __uint_as_float(u & 0xFFFF0000u); }

// ---------------- bucketed CSR build (padded buckets; direct-write scatter) ----------------

__global__ void k_binit(int* __restrict__ bcursor) {
  int b = threadIdx.x;
  if (b < NBKT) bcursor[b] = b * CAP;
}

// direct-write scatter: per edge 1 LDS atomic (rank) + 1 global store.
// Writes cluster into <=196 short contiguous runs per block -> L2 merges them.
__global__ void __launch_bounds__(256) k_bscatter(const int* __restrict__ src,
                                                  const int* __restrict__ dst,
                                                  int* __restrict__ bcursor,
                                                  int* __restrict__ ebuf) {
  __shared__ int hist[256];
  __shared__ int gbase[256];
  int t = threadIdx.x;
  hist[t] = 0;
  __syncthreads();

  const int4* src4 = (const int4*)(src + blockIdx.x * CHUNK);
  const int4* dst4 = (const int4*)(dst + blockIdx.x * CHUNK);
  // grid sized so blockIdx.x*CHUNK+CHUNK <= N_EDGES except possibly last block
  int e0 = blockIdx.x * CHUNK;
  int nrem = N_EDGES - e0;
  int nv = (nrem >= CHUNK ? CHUNK : nrem) >> 2;     // int4 groups (N_EDGES%4==0)

  int pk[16], bk[16], rk[16];
  #pragma unroll
  for (int g = 0; g < 4; ++g) {
    int vi = g * 256 + t;
    if (vi < nv) {
      int4 s4 = src4[vi];
      int4 d4 = dst4[vi];
      #pragma unroll
      for (int c = 0; c < 4; ++c) {
        int s = (&s4.x)[c], d = (&d4.x)[c];
        int b = d >> 10;
        pk[g * 4 + c] = s | ((d & (NPB - 1)) << 18);
        bk[g * 4 + c] = b;
        rk[g * 4 + c] = atomicAdd(&hist[b], 1);
      }
    } else {
      #pragma unroll
      for (int c = 0; c < 4; ++c) bk[g * 4 + c] = -1;
    }
  }
  __syncthreads();
  if (t < NBKT && hist[t] > 0) gbase[t] = atomicAdd(&bcursor[t], hist[t]);
  __syncthreads();
  #pragma unroll
  for (int k = 0; k < 16; ++k) {
    if (bk[k] >= 0) ebuf[gbase[bk[k]] + rk[k]] = pk[k];
  }
}

// per bucket: degrees -> rowstart/rowlen/dinv/xs, then local scatter of cols
__global__ void __launch_bounds__(256) k_bfill(const int* __restrict__ bcursor,
                                               const int* __restrict__ ebuf,
                                               const float* __restrict__ x,
                                               int* __restrict__ rowstart,
                                               int* __restrict__ rowlen,
                                               float* __restrict__ dinv,
                                               float4* __restrict__ xs,
                                               int* __restrict__ cols) {
  __shared__ int deg[NPB];
  __shared__ int cur[NPB];
  __shared__ int wsum[4];
  int b = blockIdx.x;
  int t = threadIdx.x;
  int lane = t & 63, wid = t >> 6;
  int estart = b * CAP;
  int eend = bcursor[b];           // estart + count
  int cnt = eend - estart;
  int nv = cnt >> 2;
  const int4* eb4 = (const int4*)(ebuf + estart);   // estart*4 % 16 == 0
  for (int i = t; i < NPB; i += 256) deg[i] = 0;
  __syncthreads();
  for (int i = t; i < nv; i += 256) {
    int4 p4 = eb4[i];
    atomicAdd(&deg[((unsigned)p4.x) >> 18], 1);
    atomicAdd(&deg[((unsigned)p4.y) >> 18], 1);
    atomicAdd(&deg[((unsigned)p4.z) >> 18], 1);
    atomicAdd(&deg[((unsigned)p4.w) >> 18], 1);
  }
  for (int i = estart + (nv << 2) + t; i < eend; i += 256) {
    int p = ebuf[i];
    atomicAdd(&deg[((unsigned)p) >> 18], 1);
  }
  __syncthreads();
  int d0 = deg[t * 4], d1 = deg[t * 4 + 1], d2 = deg[t * 4 + 2], d3 = deg[t * 4 + 3];
  int tsum = d0 + d1 + d2 + d3;
  int incl = tsum;
  #pragma unroll
  for (int off = 1; off < 64; off <<= 1) {
    int u = __shfl_up(incl, off);
    if (lane >= off) incl += u;
  }
  if (lane == 63) wsum[wid] = incl;
  int wexcl = incl - tsum;
  __syncthreads();
  int wbase = 0;
  for (int w = 0; w < wid; ++w) wbase += wsum[w];
  int ebase = wbase + wexcl;
  cur[t * 4 + 0] = ebase;
  cur[t * 4 + 1] = ebase + d0;
  cur[t * 4 + 2] = ebase + d0 + d1;
  cur[t * 4 + 3] = ebase + d0 + d1 + d2;
  __syncthreads();
  #pragma unroll
  for (int k = 0; k < 4; ++k) {
    int dl = t * 4 + k;
    int n = b * NPB + dl;
    if (n < N_NODES) {
      rowstart[n] = estart + cur[dl];
      rowlen[n] = deg[dl];
      float dv = rsqrtf((float)(deg[dl] + 1));
      dinv[n] = dv;
      float4 v;
      v.x = x[n * 3 + 0] * dv;
      v.y = x[n * 3 + 1] * dv;
      v.z = x[n * 3 + 2] * dv;
      v.w = 0.f;
      xs[n] = v;
    }
  }
  __syncthreads();
  for (int i = t; i < nv; i += 256) {
    int4 p4 = eb4[i];
    #pragma unroll
    for (int c = 0; c < 4; ++c) {
      int p = (&p4.x)[c];
      int dl = ((unsigned)p) >> 18;
      int lpos = atomicAdd(&cur[dl], 1);
      cols[estart + lpos] = p & 0x3FFFF;
    }
  }
  for (int i = estart + (nv << 2) + t; i < eend; i += 256) {
    int p = ebuf[i];
    int dl = ((unsigned)p) >> 18;
    int lpos = atomicAdd(&cur[dl], 1);
    cols[estart + lpos] = p & 0x3FFFF;
  }
}

// ---------------- layer-1: aggregate 3-feature x + fused 3x3 moments ----------------

__global__ void k_agg1(const float4* __restrict__ xs, float4* __restrict__ t,
                       const int* __restrict__ rowstart, const int* __restrict__ rowlen,
                       const int* __restrict__ cols,
                       const float* __restrict__ dinv, float* __restrict__ mom) {
  int n = blockIdx.x * blockDim.x + threadIdx.x;
  float m9[9] = {0.f, 0.f, 0.f, 0.f, 0.f, 0.f, 0.f, 0.f, 0.f};
  if (n < N_NODES) {
    float4 self = xs[n];
    float a0 = self.x, a1 = self.y, a2 = self.z;
    float b0 = 0.f, b1 = 0.f, b2 = 0.f;
    float c0 = 0.f, c1 = 0.f, c2 = 0.f;
    float e0 = 0.f, e1 = 0.f, e2 = 0.f;
    int base = rowstart[n];
    int len = rowlen[n];
    int j = 0;
    for (; j + 8 <= len; j += 8) {   // 8 float4 loads in flight
      int s0 = cols[base + j],     s1 = cols[base + j + 1];
      int s2 = cols[base + j + 2], s3 = cols[base + j + 3];
      int s4 = cols[base + j + 4], s5 = cols[base + j + 5];
      int s6 = cols[base + j + 6], s7 = cols[base + j + 7];
      float4 v0 = xs[s0], v1 = xs[s1], v2 = xs[s2], v3 = xs[s3];
      float4 v4 = xs[s4], v5 = xs[s5], v6 = xs[s6], v7 = xs[s7];
      a0 += v0.x + v4.x; a1 += v0.y + v4.y; a2 += v0.z + v4.z;
      b0 += v1.x + v5.x; b1 += v1.y + v5.y; b2 += v1.z + v5.z;
      c0 += v2.x + v6.x; c1 += v2.y + v6.y; c2 += v2.z + v6.z;
      e0 += v3.x + v7.x; e1 += v3.y + v7.y; e2 += v3.z + v7.z;
    }
    for (; j + 4 <= len; j += 4) {
      int s0 = cols[base + j], s1 = cols[base + j + 1];
      int s2 = cols[base + j + 2], s3 = cols[base + j + 3];
      float4 v0 = xs[s0], v1 = xs[s1], v2 = xs[s2], v3 = xs[s3];
      a0 += v0.x; a1 += v0.y; a2 += v0.z;
      b0 += v1.x; b1 += v1.y; b2 += v1.z;
      c0 += v2.x; c1 += v2.y; c2 += v2.z;
      e0 += v3.x; e1 += v3.y; e2 += v3.z;
    }
    for (; j < len; ++j) {
      float4 v = xs[cols[base + j]];
      a0 += v.x; a1 += v.y; a2 += v.z;
    }
    float dv = dinv[n];
    float4 o;
    o.x = dv * ((a0 + b0) + (c0 + e0));
    o.y = dv * ((a1 + b1) + (c1 + e1));
    o.z = dv * ((a2 + b2) + (c2 + e2));
    o.w = 0.f;
    t[n] = o;
    m9[0] = o.x; m9[1] = o.y; m9[2] = o.z;
    m9[3] = o.x * o.x; m9[4] = o.x * o.y; m9[5] = o.x * o.z;
    m9[6] = o.y * o.y; m9[7] = o.y * o.z; m9[8] = o.z * o.z;
  }
  #pragma unroll
  for (int off = 32; off; off >>= 1) {
    #pragma unroll
    for (int i = 0; i < 9; ++i) m9[i] += __shfl_xor(m9[i], off);
  }
  __shared__ float ls[4][9];
  int lane = threadIdx.x & 63, wid = threadIdx.x >> 6;
  if (lane == 0) {
    #pragma unroll
    for (int i = 0; i < 9; ++i) ls[wid][i] = m9[i];
  }
  __syncthreads();
  if (threadIdx.x < 9) {
    float s = ls[0][threadIdx.x] + ls[1][threadIdx.x] + ls[2][threadIdx.x] + ls[3][threadIdx.x];
    atomicAdd(&mom[threadIdx.x], s);
  }
}

// fused layer-2 front end: h1 = t @ W1 (in-register), BN1 (stats from moments),
// relu, @W2 via split-bf16 MFMA, scale by dinv -> hb (bf16 only)
__global__ void __launch_bounds__(256) k_l2m2(const float4* __restrict__ t,
                                              ushort_t* __restrict__ hb,
                                              const float* __restrict__ W1,
                                              const float* __restrict__ W2,
                                              const float* __restrict__ mom,
                                              const float* __restrict__ gamma,
                                              const float* __restrict__ beta,
                                              const float* __restrict__ dinv) {
  __shared__ float w1s[192];
  __shared__ ushort_t w2t_hi[64 * 64];   // [out_feat][k]
  __shared__ ushort_t w2t_lo[64 * 64];
  __shared__ float tt[4][16][4];
  __shared__ ushort_t at_hi[4][16 * 64];
  __shared__ ushort_t at_lo[4][16 * 64];
  int tix = threadIdx.x;
  int lane = tix & 63, wid = tix >> 6;
  if (tix < 192) w1s[tix] = W1[tix];
  for (int i = tix; i < 64 * 64; i += 256) {
    int f = i >> 6, k = i & 63;
    float w = W2[k * 64 + f];
    ushort_t hi = f32_to_bf16(w);
    w2t_hi[i] = hi;
    w2t_lo[i] = f32_to_bf16(w - bf16_to_f32(hi));
  }
  __syncthreads();

  int col = lane & 15, kb = lane >> 4;
  short8 bhi[4][2], blo[4][2];
  #pragma unroll
  for (int nt = 0; nt < 4; ++nt) {
    #pragma unroll
    for (int ks = 0; ks < 2; ++ks) {
      int base = (nt * 16 + col) * 64 + ks * 32 + kb * 8;
      bhi[nt][ks] = *reinterpret_cast<const short8*>(&w2t_hi[base]);
      blo[nt][ks] = *reinterpret_cast<const short8*>(&w2t_lo[base]);
    }
  }

  float inv_n = 1.0f / N_NODES;
  float w0 = w1s[lane], w1 = w1s[64 + lane], w2 = w1s[128 + lane];
  float mu = (mom[0] * w0 + mom[1] * w1 + mom[2] * w2) * inv_n;
  float eh2 = (mom[3] * w0 * w0 + 2.f * mom[4] * w0 * w1 + 2.f * mom[5] * w0 * w2 +
               mom[6] * w1 * w1 + 2.f * mom[7] * w1 * w2 + mom[8] * w2 * w2) * inv_n;
  float var = eh2 - mu * mu;
  float sc = rsqrtf(var + EPS) * gamma[lane];
  float sh = beta[lane] - mu * sc;

  for (int bt = blockIdx.x; bt < 3125; bt += gridDim.x) {
    int n0 = (bt * 4 + wid) * 16;
    if (lane < 16) {
      float4 v = t[n0 + lane];
      tt[wid][lane][0] = v.x; tt[wid][lane][1] = v.y; tt[wid][lane][2] = v.z;
    }
    #pragma unroll 4
    for (int i = 0; i < 16; ++i) {
      float h = tt[wid][i][0] * w0 + tt[wid][i][1] * w1 + tt[wid][i][2] * w2;
      float a = h * sc + sh;
      a = a > 0.f ? a : 0.f;
      ushort_t hi = f32_to_bf16(a);
      at_hi[wid][i * 64 + lane] = hi;
      at_lo[wid][i * 64 + lane] = f32_to_bf16(a - bf16_to_f32(hi));
    }
    short8 ahi[2], alo[2];
    #pragma unroll
    for (int ks = 0; ks < 2; ++ks) {
      int base = col * 64 + ks * 32 + kb * 8;   // A: row=lane&15, k-block
      ahi[ks] = *reinterpret_cast<const short8*>(&at_hi[wid][base]);
      alo[ks] = *reinterpret_cast<const short8*>(&at_lo[wid][base]);
    }
    float dv[4];
    #pragma unroll
    for (int r = 0; r < 4; ++r) dv[r] = dinv[n0 + kb * 4 + r];

    #pragma unroll
    for (int nt = 0; nt < 4; ++nt) {
      f32x4 acc = {0.f, 0.f, 0.f, 0.f};
      #pragma unroll
      for (int ks = 0; ks < 2; ++ks) {
        acc = __builtin_amdgcn_mfma_f32_16x16x32_bf16(ahi[ks], bhi[nt][ks], acc, 0, 0, 0);
        acc = __builtin_amdgcn_mfma_f32_16x16x32_bf16(ahi[ks], blo[nt][ks], acc, 0, 0, 0);
        acc = __builtin_amdgcn_mfma_f32_16x16x32_bf16(alo[ks], bhi[nt][ks], acc, 0, 0, 0);
      }
      #pragma unroll
      for (int r = 0; r < 4; ++r) {
        int node = n0 + kb * 4 + r;      // C/D: row=(lane>>4)*4+r, col=lane&15
        int feat = nt * 16 + col;
        hb[node * 64 + feat] = f32_to_bf16(acc[r] * dv[r]);
      }
    }
  }
}

// layer-2 aggregation: one node per wave, 8-neighbor groups. Writes packed bf16 h1.
__global__ void k_agg2(const ushort_t* __restrict__ hb, ushort_t* __restrict__ h1b,
                       const int* __restrict__ rowstart, const int* __restrict__ rowlen,
                       const int* __restrict__ cols, const float* __restrict__ dinv) {
  int node = blockIdx.x * 4 + (threadIdx.x >> 6);
  int lane = threadIdx.x & 63;
  if (node >= N_NODES) return;
  int half = lane >> 5;
  int fl = lane & 31;
  const unsigned* hb32 = (const unsigned*)hb;      // hb32[s*32+fl] = feats {2fl, 2fl+1}
  unsigned* o32 = (unsigned*)h1b;
  float2 acc;
  if (half == 0) {                                  // self loop (bf16)
    unsigned u = hb32[node * 32 + fl];
    acc.x = bfu_lo(u); acc.y = bfu_hi(u);
  } else { acc.x = 0.f; acc.y = 0.f; }
  int base = rowstart[node];
  int len = rowlen[node];
  for (int c0 = 0; c0 < len; c0 += 64) {
    int rem = len - c0;
    int m = rem < 64 ? rem : 64;
    int cidx = (lane < m) ? cols[base + c0 + lane] : 0;
    int j = 0;
    for (; j + 8 <= m; j += 8) {   // 8 neighbors / iter, 4 dword loads in flight per lane
      int sA = __shfl(cidx, j + half);
      int sB = __shfl(cidx, j + 2 + half);
      int sC = __shfl(cidx, j + 4 + half);
      int sD = __shfl(cidx, j + 6 + half);
      unsigned uA = hb32[sA * 32 + fl], uB = hb32[sB * 32 + fl];
      unsigned uC = hb32[sC * 32 + fl], uD = hb32[sD * 32 + fl];
      acc.x += (bfu_lo(uA) + bfu_lo(uB)) + (bfu_lo(uC) + bfu_lo(uD));
      acc.y += (bfu_hi(uA) + bfu_hi(uB)) + (bfu_hi(uC) + bfu_hi(uD));
    }
    for (; j + 2 <= m; j += 2) {
      int s = __shfl(cidx, j + half);
      unsigned u = hb32[s * 32 + fl];
      acc.x += bfu_lo(u);
      acc.y += bfu_hi(u);
    }
    if (j < m) {                   // odd leftover: half0 only
      int s = __shfl(cidx, j);
      if (half == 0) {
        unsigned u = hb32[s * 32 + fl];
        acc.x += bfu_lo(u);
        acc.y += bfu_hi(u);
      }
    }
  }
  acc.x += __shfl_xor(acc.x, 32);
  acc.y += __shfl_xor(acc.y, 32);
  if (half == 0) {
    float dv = dinv[node];
    float ox = acc.x * dv, oy = acc.y * dv;
    o32[node * 32 + fl] = ((unsigned)f32_to_bf16(oy) << 16) | (unsigned)f32_to_bf16(ox);
  }
}

// BN2 stats from packed bf16 h1 -> stats[0:64], stats[64:128]
__global__ void k_bnstats_b(const ushort_t* __restrict__ h1b, float* __restrict__ stats) {
  const unsigned* h32 = (const unsigned*)h1b;
  int tid = threadIdx.x;
  int lane = tid & 63, wid = tid >> 6;
  int fl = lane & 31, rsel = lane >> 5;
  float s0 = 0.f, s1 = 0.f, q0 = 0.f, q1 = 0.f;
  for (int r = blockIdx.x * 8 + wid * 2 + rsel; r < N_NODES; r += gridDim.x * 8) {
    unsigned u = h32[r * 32 + fl];
    float a = bfu_lo(u), b = bfu_hi(u);
    s0 += a; s1 += b; q0 += a * a; q1 += b * b;
  }
  s0 += __shfl_xor(s0, 32); s1 += __shfl_xor(s1, 32);
  q0 += __shfl_xor(q0, 32); q1 += __shfl_xor(q1, 32);
  __shared__ float ls[4][64], lq[4][64];
  if (rsel == 0) {
    ls[wid][2 * fl] = s0; ls[wid][2 * fl + 1] = s1;
    lq[wid][2 * fl] = q0; lq[wid][2 * fl + 1] = q1;
  }
  __syncthreads();
  if (tid < 64) {
    float a = ls[0][tid] + ls[1][tid] + ls[2][tid] + ls[3][tid];
    float b = lq[0][tid] + lq[1][tid] + lq[2][tid] + lq[3][tid];
    atomicAdd(&stats[tid], a);
    atomicAdd(&stats[64 + tid], b);
  }
}

// ---------------- pooling + head ----------------

__global__ void k_gstart(const int* __restrict__ batch, int* __restrict__ gstart) {
  int g = blockIdx.x * blockDim.x + threadIdx.x;
  if (g > N_GRAPHS) return;
  int lo = 0, hi = N_NODES;
  while (lo < hi) {
    int mid = (lo + hi) >> 1;
    if (batch[mid] < g) lo = mid + 1; else hi = mid;
  }
  gstart[g] = lo;
}

__global__ void k_pool(const ushort_t* __restrict__ h1b, const float* __restrict__ stats2,
                       const float* __restrict__ gamma, const float* __restrict__ beta,
                       const int* __restrict__ gstart, float* __restrict__ hgraph) {
  __shared__ float ssum[4][64], smax[4][64];
  int g = blockIdx.x;
  int lane = threadIdx.x & 63, wid = threadIdx.x >> 6;
  int s0 = gstart[g], s1 = gstart[g + 1];
  float mu = stats2[lane] * (1.0f / N_NODES);
  float var = stats2[64 + lane] * (1.0f / N_NODES) - mu * mu;
  float sc = rsqrtf(var + EPS) * gamma[lane];
  float sh = beta[lane] - mu * sc;
  float sum = 0.f, mx = 0.f;
  for (int r = s0 + wid; r < s1; r += 4) {
    float v = bf16_to_f32(h1b[r * 64 + lane]) * sc + sh;
    v = v > 0.f ? v : 0.f;
    sum += v;
    mx = v > mx ? v : mx;
  }
  ssum[wid][lane] = sum;
  smax[wid][lane] = mx;
  __syncthreads();
  if (wid == 0) {
    float s = ssum[0][lane] + ssum[1][lane] + ssum[2][lane] + ssum[3][lane];
    float m = fmaxf(fmaxf(smax[0][lane], smax[1][lane]), fmaxf(smax[2][lane], smax[3][lane]));
    int cnt = s1 - s0;
    float inv = 1.0f / (float)(cnt > 0 ? cnt : 1);
    hgraph[g * 128 + lane] = s * inv;
    hgraph[g * 128 + 64 + lane] = m;
  }
}

__global__ void k_head(const float* __restrict__ hgraph,
                       const float* __restrict__ emb, const int* __restrict__ recipe,
                       const float* __restrict__ conv_w, const float* __restrict__ conv_b,
                       const float* __restrict__ fc_w, const float* __restrict__ fc_b,
                       const float* __restrict__ m1_w, const float* __restrict__ m1_b,
                       const float* __restrict__ m2_w, const float* __restrict__ m2_b,
                       const float* __restrict__ m3_w, const float* __restrict__ m3_b,
                       float* __restrict__ out) {
  __shared__ float r_s[RLEN][EMBED];
  __shared__ float convout[16 * RLEN];
  __shared__ float cvec[192];
  __shared__ float y1[128];
  __shared__ float y2[64];
  __shared__ int rec_s[RLEN];
  __shared__ float emb_s[80];
  int g = blockIdx.x;
  int t = threadIdx.x;
  if (t < 80) emb_s[t] = emb[t];
  if (t < RLEN) rec_s[t] = recipe[g * RLEN + t];
  __syncthreads();
  for (int idx = t; idx < RLEN * EMBED; idx += blockDim.x) {
    int pos = idx >> 3, e = idx & 7;
    r_s[pos][e] = emb_s[rec_s[pos] * EMBED + e];
  }
  if (t < 128) cvec[t] = hgraph[g * 128 + t];
  __syncthreads();
  for (int idx = t; idx < 16 * RLEN; idx += blockDim.x) {
    int c = idx / RLEN, pos = idx % RLEN;
    float acc = conv_b[c];
    #pragma unroll
    for (int k = 0; k < 3; ++k) {
      int p = pos + k - 1;
      if (p >= 0 && p < RLEN) {
        #pragma unroll
        for (int e = 0; e < EMBED; ++e)
          acc = fmaf(r_s[p][e], conv_w[(c * EMBED + e) * 3 + k], acc);
      }
    }
    convout[c * RLEN + pos] = acc > 0.f ? acc : 0.f;
  }
  __syncthreads();
  if (t < 64) {
    float acc = fc_b[t];
    for (int i = 0; i < 320; ++i) acc = fmaf(convout[i], fc_w[i * 64 + t], acc);
    cvec[128 + t] = acc > 0.f ? acc : 0.f;
  }
  __syncthreads();
  if (t < 128) {
    float acc = m1_b[t];
    for (int i = 0; i < 192; ++i) acc = fmaf(cvec[i], m1_w[i * 128 + t], acc);
    y1[t] = acc > 0.f ? acc : 0.f;
  }
  __syncthreads();
  if (t < 64) {
    float acc = m2_b[t];
    for (int i = 0; i < 128; ++i) acc = fmaf(y1[i], m2_w[i * 64 + t], acc);
    y2[t] = acc > 0.f ? acc : 0.f;
  }
  __syncthreads();
  if (t < 3) {
    float acc = m3_b[t];
    for (int i = 0; i < 64; ++i) acc = fmaf(y2[i], m3_w[i * 3 + t], acc);
    out[g * 3 + t] = acc;
  }
}

extern "C" void kernel_launch(void* const* d_in, const int* in_sizes, int n_in,
                              void* d_out, int out_size, void* d_ws, size_t ws_size,
                              hipStream_t stream) {
  const float* x      = (const float*)d_in[0];
  const float* W1     = (const float*)d_in[1];
  // b1 (d_in[2]) cancels under BN
  const float* gamma1 = (const float*)d_in[3];
  const float* beta1  = (const float*)d_in[4];
  const float* W2     = (const float*)d_in[5];
  // b2 (d_in[6]) cancels under BN
  const float* gamma2 = (const float*)d_in[7];
  const float* beta2  = (const float*)d_in[8];
  const float* emb    = (const float*)d_in[9];
  const float* conv_w = (const float*)d_in[10];
  const float* conv_b = (const float*)d_in[11];
  const float* fc_w   = (const float*)d_in[12];
  const float* fc_b   = (const float*)d_in[13];
  const float* m1_w   = (const float*)d_in[14];
  const float* m1_b   = (const float*)d_in[15];
  const float* m2_w   = (const float*)d_in[16];
  const float* m2_b   = (const float*)d_in[17];
  const float* m3_w   = (const float*)d_in[18];
  const float* m3_b   = (const float*)d_in[19];
  const int* ei       = (const int*)d_in[20];
  const int* batch    = (const int*)d_in[21];
  const int* recipe   = (const int*)d_in[22];
  const int* e_src = ei;
  const int* e_dst = ei + N_EDGES;
  float* out = (float*)d_out;

  char* p = (char*)d_ws;
  auto alloc = [&](size_t bytes) {
    char* r = p;
    p += (bytes + 255) & ~(size_t)255;
    return (void*)r;
  };
  int*   bcursor  = (int*)alloc((size_t)NBKT * 4);
  float* dinv     = (float*)alloc((size_t)N_NODES * 4);
  int*   rowstart = (int*)alloc((size_t)N_NODES * 4);
  int*   rowlen   = (int*)alloc((size_t)N_NODES * 4);
  int*   gstart   = (int*)alloc((size_t)(N_GRAPHS + 1) * 4);
  float* stats    = (float*)alloc(256 * 4);
  float* mom      = (float*)alloc(16 * 4);
  float* hgraph   = (float*)alloc((size_t)N_GRAPHS * 128 * 4);
  int*   cols     = (int*)alloc((size_t)NBKT * CAP * 4);
  float4* xs      = (float4*)alloc((size_t)N_NODES * 16);
  float4* tbuf    = (float4*)alloc((size_t)N_NODES * 16);
  int*   ebuf     = (int*)alloc((size_t)NBKT * CAP * 4);
  ushort_t* hb    = (ushort_t*)alloc((size_t)N_NODES * 64 * 2);
  ushort_t* h1b   = (ushort_t*)ebuf;  // alias: ebuf dead before k_agg2 writes h1b

  hipMemsetAsync(stats, 0, 256 * 4, stream);
  hipMemsetAsync(mom, 0, 16 * 4, stream);

  k_binit<<<1, 256, 0, stream>>>(bcursor);
  k_bscatter<<<(N_EDGES + CHUNK - 1) / CHUNK, 256, 0, stream>>>(e_src, e_dst, bcursor, ebuf);
  k_bfill<<<NBKT, 256, 0, stream>>>(bcursor, ebuf, x, rowstart, rowlen, dinv, xs, cols);
  k_agg1<<<(N_NODES + 255) / 256, 256, 0, stream>>>(xs, tbuf, rowstart, rowlen, cols, dinv, mom);
  k_l2m2<<<625, 256, 0, stream>>>(tbuf, hb, W1, W2, mom, gamma1, beta1, dinv);
  k_agg2<<<(N_NODES + 3) / 4, 256, 0, stream>>>(hb, h1b, rowstart, rowlen, cols, dinv);
  k_bnstats_b<<<512, 256, 0, stream>>>(h1b, stats);
  k_gstart<<<1, 576, 0, stream>>>(batch, gstart);
  k_pool<<<N_GRAPHS, 256, 0, stream>>>(h1b, stats, gamma2, beta2, gstart, hgraph);
  k_head<<<N_GRAPHS, 128, 0, stream>>>(hgraph, emb, recipe, conv_w, conv_b, fc_w, fc_b,
                                       m1_w, m1_b, m2_w, m2_b, m3_w, m3_b, out);
}